// Round 3
// baseline (7498.277 us; speedup 1.0000x reference)
//
#include <hip/hip_runtime.h>
#include <hip/hip_bf16.h>
#include <stdint.h>

#define B_ 2
#define L_ 2046
#define H_ 16
#define NW_ 682
#define LP_ 2048
#define NWP_ 704
#define M_ (B_*L_)
#define SCALE_ 0.125f

// ---------------- q = x @ Wq^T + bq  (f32, tiled) ----------------
__global__ __launch_bounds__(256) void qgemm32(const float* __restrict__ X,
                                               const float* __restrict__ W,
                                               const float* __restrict__ bq,
                                               float* __restrict__ Q) {
  __shared__ float xs[64][17];
  __shared__ float wsm[64][17];
  int t = threadIdx.x;
  int tx = t & 15, ty = t >> 4;
  int m0 = blockIdx.x * 64, n0 = blockIdx.y * 64;
  float acc[4][4];
#pragma unroll
  for (int i = 0; i < 4; ++i)
#pragma unroll
    for (int j = 0; j < 4; ++j) acc[i][j] = 0.f;
  for (int kt = 0; kt < 1024; kt += 16) {
    for (int i = t; i < 1024; i += 256) {
      int r = i >> 4, c = i & 15;
      int row = m0 + r;
      xs[r][c] = (row < M_) ? X[(size_t)row * 1024 + kt + c] : 0.f;
      wsm[r][c] = W[(size_t)(n0 + r) * 1024 + kt + c];
    }
    __syncthreads();
#pragma unroll
    for (int kk = 0; kk < 16; ++kk) {
      float a[4], bv[4];
#pragma unroll
      for (int i = 0; i < 4; ++i) a[i] = xs[ty * 4 + i][kk];
#pragma unroll
      for (int j = 0; j < 4; ++j) bv[j] = wsm[tx * 4 + j][kk];
#pragma unroll
      for (int i = 0; i < 4; ++i)
#pragma unroll
        for (int j = 0; j < 4; ++j) acc[i][j] = fmaf(a[i], bv[j], acc[i][j]);
    }
    __syncthreads();
  }
#pragma unroll
  for (int i = 0; i < 4; ++i) {
    int row = m0 + ty * 4 + i;
    if (row < M_) {
#pragma unroll
      for (int j = 0; j < 4; ++j) {
        int col = n0 + tx * 4 + j;
        Q[(size_t)row * 1024 + col] = acc[i][j] + bq[col];
      }
    }
  }
}

// ---------------- global-head K/V projections (f32, row-major out) ----------------
__global__ __launch_bounds__(256) void proj_g32(const float* __restrict__ x,
    const float* __restrict__ Wk, const float* __restrict__ bk,
    const float* __restrict__ Wv, const float* __restrict__ bv,
    float* __restrict__ KGP, float* __restrict__ VGP) {
  __shared__ float xs[64][64];
  __shared__ float wks[64][65];
  __shared__ float wvs[64][65];
  int t = threadIdx.x;
  int lb = blockIdx.x, bh = blockIdx.y;
  int b = bh >> 3, h = bh & 7;
  int l0 = lb * 64;
  for (int idx = t; idx < 4096; idx += 256) {
    int r = idx >> 6, c = idx & 63;
    int l = l0 + r;
    xs[r][c] = (l < L_) ? x[((size_t)b * L_ + l) * 1024 + h * 64 + c] : 0.0f;
    wks[r][c] = Wk[(size_t)h * 4096 + idx];
    wvs[r][c] = Wv[(size_t)h * 4096 + idx];
  }
  __syncthreads();
  int o = t & 63, lg = t >> 6;
  float kbias = bk[h * 64 + o], vbias = bv[h * 64 + o];
  const size_t outb = (size_t)bh * LP_ * 64;
  for (int ls = 0; ls < 16; ++ls) {
    int l = lg * 16 + ls;
    float ka = kbias, va = vbias;
#pragma unroll
    for (int i = 0; i < 64; ++i) {
      float xv = xs[l][i];
      ka = fmaf(xv, wks[o][i], ka);
      va = fmaf(xv, wvs[o][i], va);
    }
    KGP[outb + (size_t)(l0 + l) * 64 + o] = ka;
    VGP[outb + (size_t)(l0 + l) * 64 + o] = va;
  }
}

// ---------------- local-head window-avg + K/V projections (f32) ----------------
__global__ __launch_bounds__(256) void proj_l32(const float* __restrict__ x,
    const float* __restrict__ Wk, const float* __restrict__ bk,
    const float* __restrict__ Wv, const float* __restrict__ bv,
    float* __restrict__ KLP, float* __restrict__ VLP) {
  __shared__ float xs[64][64];
  __shared__ float wks[64][65];
  __shared__ float wvs[64][65];
  int t = threadIdx.x;
  int nb = blockIdx.x, bh = blockIdx.y;
  int b = bh >> 3, h = bh & 7;
  int n0 = nb * 64;
  int hh = 8 + h;
  for (int idx = t; idx < 4096; idx += 256) {
    int r = idx >> 6, c = idx & 63;
    int n = n0 + r;
    float v = 0.0f;
    if (n < NW_) {
      size_t base = ((size_t)b * L_ + 3 * n) * 1024 + hh * 64 + c;
      v = (x[base] + x[base + 1024] + x[base + 2048]) * (1.0f / 3.0f);
    }
    xs[r][c] = v;
    wks[r][c] = Wk[(size_t)hh * 4096 + idx];
    wvs[r][c] = Wv[(size_t)hh * 4096 + idx];
  }
  __syncthreads();
  int o = t & 63, lg = t >> 6;
  float kbias = bk[hh * 64 + o], vbias = bv[hh * 64 + o];
  const size_t outb = (size_t)bh * NWP_ * 64;
  for (int ls = 0; ls < 16; ++ls) {
    int l = lg * 16 + ls;
    float ka = kbias, va = vbias;
#pragma unroll
    for (int i = 0; i < 64; ++i) {
      float xv = xs[l][i];
      ka = fmaf(xv, wks[o][i], ka);
      va = fmaf(xv, wvs[o][i], va);
    }
    KLP[outb + (size_t)(n0 + l) * 64 + o] = ka;
    VLP[outb + (size_t)(n0 + l) * 64 + o] = va;
  }
}

// ---------------- mask precompute: bit-packed (1 = masked) ----------------
__global__ __launch_bounds__(256) void maskprep(const float* __restrict__ mask,
                                                uint64_t* __restrict__ gm,
                                                uint64_t* __restrict__ wm) {
  int row = blockIdx.x * 4 + (threadIdx.x >> 6);  // b*L + l
  int lane = threadIdx.x & 63;
  if (row >= B_ * L_) return;
  int b = row / L_, l = row % L_;
  const float* mr = mask + (size_t)b * L_ * L_ + (size_t)l * L_;
  for (int w = 0; w < 32; ++w) {
    int m = w * 64 + lane;
    bool masked = (m >= L_) ? true : (mr[m] == 0.0f);
    uint64_t bal = __ballot(masked);
    if (lane == 0) gm[(size_t)row * 32 + w] = bal;
  }
  for (int w = 0; w < 11; ++w) {
    int n = w * 64 + lane;
    bool lmask = true;
    if (n < NW_) {
      float s = mr[3 * n] + mr[3 * n + 1] + mr[3 * n + 2];
      lmask = !(s >= 2.0f);
    }
    uint64_t bal = __ballot(lmask);
    if (lane == 0) wm[(size_t)row * 11 + w] = bal;
  }
}

// ---------------- global attention, pure f32 VALU ----------------
// block: 16 q-rows (r = t>>4), 16 key-slots (sl = t&15). grid (128, 16)
__global__ __launch_bounds__(256) void attn_g32(const float* __restrict__ Q,
    const float* __restrict__ K, const float* __restrict__ V,
    const uint64_t* __restrict__ GM,
    float* __restrict__ OV, float* __restrict__ OP) {
  __shared__ float sums[16];
  int t = threadIdx.x;
  int r = t >> 4, sl = t & 15;
  int q0 = blockIdx.x * 16;
  int bh = blockIdx.y;
  int b = bh >> 3, h = bh & 7;
  int qr = q0 + r;
  bool qv = (qr < L_);
  int qs = qv ? qr : 0;
  float qreg[64];
  {
    const float* qrow = Q + ((size_t)(b * L_ + qs)) * 1024 + h * 64;
#pragma unroll
    for (int d = 0; d < 64; d += 4) {
      float4 v = *reinterpret_cast<const float4*>(qrow + d);
      qreg[d] = v.x; qreg[d + 1] = v.y; qreg[d + 2] = v.z; qreg[d + 3] = v.w;
    }
  }
  const float* kb = K + (size_t)bh * LP_ * 64;
  const float* vb = V + (size_t)bh * LP_ * 64;
  const uint64_t* gmr = GM + (size_t)(b * L_ + qs) * 32;

  // pass A: row sum of exp
  float ps = 0.f;
  for (int m = sl; m < L_; m += 16) {
    const float* krow = kb + (size_t)m * 64;
    float dot = 0.f;
#pragma unroll
    for (int d = 0; d < 64; ++d) dot = fmaf(qreg[d], krow[d], dot);
    uint64_t w = gmr[m >> 6];
    if (!((w >> (m & 63)) & 1)) ps += __expf(dot * SCALE_);
  }
#pragma unroll
  for (int off = 8; off >= 1; off >>= 1) ps += __shfl_xor(ps, off, 64);
  if (sl == 0) sums[r] = ps;
  __syncthreads();
  float s = sums[r];
  float inv = (s > 0.f) ? 1.0f / s : 0.0f;

  // pass B: write normalized pg, accumulate PV
  float oacc[64];
#pragma unroll
  for (int d = 0; d < 64; ++d) oacc[d] = 0.f;
  const size_t oprow = ((size_t)bh * L_ + qs) * (size_t)L_;
  for (int m = sl; m < L_; m += 16) {
    const float* krow = kb + (size_t)m * 64;
    float dot = 0.f;
#pragma unroll
    for (int d = 0; d < 64; ++d) dot = fmaf(qreg[d], krow[d], dot);
    uint64_t w = gmr[m >> 6];
    float pv = ((w >> (m & 63)) & 1) ? 0.f : __expf(dot * SCALE_);
    float pn = pv * inv;
    if (qv) OP[oprow + m] = pn;
    const float* vrow = vb + (size_t)m * 64;
#pragma unroll
    for (int d = 0; d < 64; ++d) oacc[d] = fmaf(pn, vrow[d], oacc[d]);
  }
#pragma unroll
  for (int off = 8; off >= 1; off >>= 1)
#pragma unroll
    for (int d = 0; d < 64; ++d) oacc[d] += __shfl_xor(oacc[d], off, 64);
  if (sl == 0 && qv) {
    float* orow = OV + (((size_t)b * 16 + h) * L_ + qr) * 64;
#pragma unroll
    for (int d = 0; d < 64; ++d) orow[d] = oacc[d];
  }
}

// ---------------- local attention, pure f32 VALU ----------------
__global__ __launch_bounds__(256) void attn_l32(const float* __restrict__ Q,
    const float* __restrict__ K, const float* __restrict__ V,
    const uint64_t* __restrict__ WM,
    float* __restrict__ OV, float* __restrict__ OP) {
  __shared__ float sums[16];
  int t = threadIdx.x;
  int r = t >> 4, sl = t & 15;
  int q0 = blockIdx.x * 16;
  int bh = blockIdx.y;
  int b = bh >> 3, h = bh & 7;
  int qr = q0 + r;
  bool qv = (qr < L_);
  int qs = qv ? qr : 0;
  float qreg[64];
  {
    const float* qrow = Q + ((size_t)(b * L_ + qs)) * 1024 + (8 + h) * 64;
#pragma unroll
    for (int d = 0; d < 64; d += 4) {
      float4 v = *reinterpret_cast<const float4*>(qrow + d);
      qreg[d] = v.x; qreg[d + 1] = v.y; qreg[d + 2] = v.z; qreg[d + 3] = v.w;
    }
  }
  const float* kb = K + (size_t)bh * NWP_ * 64;
  const float* vb = V + (size_t)bh * NWP_ * 64;
  const uint64_t* wmr = WM + (size_t)(b * L_ + qs) * 11;

  float ps = 0.f;
  for (int m = sl; m < NW_; m += 16) {
    const float* krow = kb + (size_t)m * 64;
    float dot = 0.f;
#pragma unroll
    for (int d = 0; d < 64; ++d) dot = fmaf(qreg[d], krow[d], dot);
    uint64_t w = wmr[m >> 6];
    if (!((w >> (m & 63)) & 1)) ps += __expf(dot * SCALE_);
  }
#pragma unroll
  for (int off = 8; off >= 1; off >>= 1) ps += __shfl_xor(ps, off, 64);
  if (sl == 0) sums[r] = ps;
  __syncthreads();
  float s = sums[r];
  float inv = (s > 0.f) ? 1.0f / s : 0.0f;

  float oacc[64];
#pragma unroll
  for (int d = 0; d < 64; ++d) oacc[d] = 0.f;
  const size_t oprow = ((size_t)bh * L_ + qs) * (size_t)NW_;
  for (int m = sl; m < NW_; m += 16) {
    const float* krow = kb + (size_t)m * 64;
    float dot = 0.f;
#pragma unroll
    for (int d = 0; d < 64; ++d) dot = fmaf(qreg[d], krow[d], dot);
    uint64_t w = wmr[m >> 6];
    float pv = ((w >> (m & 63)) & 1) ? 0.f : __expf(dot * SCALE_);
    float pn = pv * inv;
    if (qv) OP[oprow + m] = pn;
    const float* vrow = vb + (size_t)m * 64;
#pragma unroll
    for (int d = 0; d < 64; ++d) oacc[d] = fmaf(pn, vrow[d], oacc[d]);
  }
#pragma unroll
  for (int off = 8; off >= 1; off >>= 1)
#pragma unroll
    for (int d = 0; d < 64; ++d) oacc[d] += __shfl_xor(oacc[d], off, 64);
  if (sl == 0 && qv) {
    float* orow = OV + (((size_t)b * 16 + 8 + h) * L_ + qr) * 64;
#pragma unroll
    for (int d = 0; d < 64; ++d) orow[d] = oacc[d];
  }
}

extern "C" void kernel_launch(void* const* d_in, const int* in_sizes, int n_in,
                              void* d_out, int out_size, void* d_ws, size_t ws_size,
                              hipStream_t stream) {
  (void)in_sizes; (void)n_in; (void)out_size; (void)ws_size;
  const float* x    = (const float*)d_in[0];
  const float* mask = (const float*)d_in[1];
  const float* Wq   = (const float*)d_in[2];
  const float* bq   = (const float*)d_in[3];
  const float* Wk   = (const float*)d_in[4];
  const float* bk   = (const float*)d_in[5];
  const float* Wv   = (const float*)d_in[6];
  const float* bv   = (const float*)d_in[7];

  char* ws = (char*)d_ws;
  float* q32     = (float*)(ws + 0);            // 4092*1024*4 = 16,760,832
  float* kgp32   = (float*)(ws + 16760832);     // 16*2048*64*4 = 8,388,608
  float* vgp32   = (float*)(ws + 25149440);     // 8,388,608
  float* klp32   = (float*)(ws + 33538048);     // 16*704*64*4 = 2,883,584
  float* vlp32   = (float*)(ws + 36421632);     // 2,883,584
  uint64_t* gm   = (uint64_t*)(ws + 39305216);  // 2*2046*32*8 = 1,047,552
  uint64_t* wm   = (uint64_t*)(ws + 40352768);  // 2*2046*11*8 = 360,096

  float* out    = (float*)d_out;
  float* o_vall = out;                 // (2,16,2046,64)
  float* o_pg   = out + 4190208;       // (2,8,2046,2046)
  float* o_pl   = out + 71168064;      // (2,8,2046,682)

  qgemm32<<<dim3(64, 16), 256, 0, stream>>>(x, Wq, bq, q32);
  proj_g32<<<dim3(32, 16), 256, 0, stream>>>(x, Wk, bk, Wv, bv, kgp32, vgp32);
  proj_l32<<<dim3(11, 16), 256, 0, stream>>>(x, Wk, bk, Wv, bv, klp32, vlp32);
  maskprep<<<1023, 256, 0, stream>>>(mask, gm, wm);

  attn_g32<<<dim3(128, 16), 256, 0, stream>>>(q32, kgp32, vgp32, gm, o_vall, o_pg);
  attn_l32<<<dim3(128, 16), 256, 0, stream>>>(q32, klp32, vlp32, wm, o_vall, o_pl);
}

// Round 5
// 2197.221 us; speedup vs baseline: 3.4126x; 3.4126x over previous
//
#include <hip/hip_runtime.h>
#include <hip/hip_bf16.h>
#include <stdint.h>

typedef __bf16 bf16;
typedef bf16 bf16x8 __attribute__((ext_vector_type(8)));
typedef float f32x4 __attribute__((ext_vector_type(4)));

#define B_ 2
#define L_ 2046
#define H_ 16
#define NW_ 682
#define LP_ 2048
#define NWP_ 704
#define M_ (B_*L_)
#define SCALE_ 0.125f

__device__ inline bf16x8 zf8() {
  bf16x8 v;
#pragma unroll
  for (int e = 0; e < 8; ++e) v[e] = (bf16)0.0f;
  return v;
}

// ---------------- q = x @ Wq^T + bq  (f32 math, bf16 out) — R3-verified ----------------
__global__ __launch_bounds__(256) void qgemm32(const float* __restrict__ X,
                                               const float* __restrict__ W,
                                               const float* __restrict__ bq,
                                               bf16* __restrict__ Q) {
  __shared__ float xs[64][17];
  __shared__ float wsm[64][17];
  int t = threadIdx.x;
  int tx = t & 15, ty = t >> 4;
  int m0 = blockIdx.x * 64, n0 = blockIdx.y * 64;
  float acc[4][4];
#pragma unroll
  for (int i = 0; i < 4; ++i)
#pragma unroll
    for (int j = 0; j < 4; ++j) acc[i][j] = 0.f;
  for (int kt = 0; kt < 1024; kt += 16) {
    for (int i = t; i < 1024; i += 256) {
      int r = i >> 4, c = i & 15;
      int row = m0 + r;
      xs[r][c] = (row < M_) ? X[(size_t)row * 1024 + kt + c] : 0.f;
      wsm[r][c] = W[(size_t)(n0 + r) * 1024 + kt + c];
    }
    __syncthreads();
#pragma unroll
    for (int kk = 0; kk < 16; ++kk) {
      float a[4], bv[4];
#pragma unroll
      for (int i = 0; i < 4; ++i) a[i] = xs[ty * 4 + i][kk];
#pragma unroll
      for (int j = 0; j < 4; ++j) bv[j] = wsm[tx * 4 + j][kk];
#pragma unroll
      for (int i = 0; i < 4; ++i)
#pragma unroll
        for (int j = 0; j < 4; ++j) acc[i][j] = fmaf(a[i], bv[j], acc[i][j]);
    }
    __syncthreads();
  }
#pragma unroll
  for (int i = 0; i < 4; ++i) {
    int row = m0 + ty * 4 + i;
    if (row < M_) {
#pragma unroll
      for (int j = 0; j < 4; ++j) {
        int col = n0 + tx * 4 + j;
        Q[(size_t)row * 1024 + col] = (bf16)(acc[i][j] + bq[col]);
      }
    }
  }
}

// ---------------- global-head K/V projections (f32 math, bf16 row-major out) ----------------
__global__ __launch_bounds__(256) void proj_g32(const float* __restrict__ x,
    const float* __restrict__ Wk, const float* __restrict__ bk,
    const float* __restrict__ Wv, const float* __restrict__ bv,
    bf16* __restrict__ KGP, bf16* __restrict__ VGP) {
  __shared__ float xs[64][64];
  __shared__ float wks[64][65];
  __shared__ float wvs[64][65];
  int t = threadIdx.x;
  int lb = blockIdx.x, bh = blockIdx.y;
  int b = bh >> 3, h = bh & 7;
  int l0 = lb * 64;
  for (int idx = t; idx < 4096; idx += 256) {
    int r = idx >> 6, c = idx & 63;
    int l = l0 + r;
    xs[r][c] = (l < L_) ? x[((size_t)b * L_ + l) * 1024 + h * 64 + c] : 0.0f;
    wks[r][c] = Wk[(size_t)h * 4096 + idx];
    wvs[r][c] = Wv[(size_t)h * 4096 + idx];
  }
  __syncthreads();
  int o = t & 63, lg = t >> 6;
  float kbias = bk[h * 64 + o], vbias = bv[h * 64 + o];
  const size_t outb = (size_t)bh * LP_ * 64;
  for (int ls = 0; ls < 16; ++ls) {
    int l = lg * 16 + ls;
    float ka = kbias, va = vbias;
#pragma unroll
    for (int i = 0; i < 64; ++i) {
      float xv = xs[l][i];
      ka = fmaf(xv, wks[o][i], ka);
      va = fmaf(xv, wvs[o][i], va);
    }
    KGP[outb + (size_t)(l0 + l) * 64 + o] = (bf16)ka;
    VGP[outb + (size_t)(l0 + l) * 64 + o] = (bf16)va;
  }
}

// ---------------- local-head window-avg + K/V projections (f32 math, bf16 out) ----------------
__global__ __launch_bounds__(256) void proj_l32(const float* __restrict__ x,
    const float* __restrict__ Wk, const float* __restrict__ bk,
    const float* __restrict__ Wv, const float* __restrict__ bv,
    bf16* __restrict__ KLP, bf16* __restrict__ VLP) {
  __shared__ float xs[64][64];
  __shared__ float wks[64][65];
  __shared__ float wvs[64][65];
  int t = threadIdx.x;
  int nb = blockIdx.x, bh = blockIdx.y;
  int b = bh >> 3, h = bh & 7;
  int n0 = nb * 64;
  int hh = 8 + h;
  for (int idx = t; idx < 4096; idx += 256) {
    int r = idx >> 6, c = idx & 63;
    int n = n0 + r;
    float v = 0.0f;
    if (n < NW_) {
      size_t base = ((size_t)b * L_ + 3 * n) * 1024 + hh * 64 + c;
      v = (x[base] + x[base + 1024] + x[base + 2048]) * (1.0f / 3.0f);
    }
    xs[r][c] = v;
    wks[r][c] = Wk[(size_t)hh * 4096 + idx];
    wvs[r][c] = Wv[(size_t)hh * 4096 + idx];
  }
  __syncthreads();
  int o = t & 63, lg = t >> 6;
  float kbias = bk[hh * 64 + o], vbias = bv[hh * 64 + o];
  const size_t outb = (size_t)bh * NWP_ * 64;
  for (int ls = 0; ls < 16; ++ls) {
    int l = lg * 16 + ls;
    float ka = kbias, va = vbias;
#pragma unroll
    for (int i = 0; i < 64; ++i) {
      float xv = xs[l][i];
      ka = fmaf(xv, wks[o][i], ka);
      va = fmaf(xv, wvs[o][i], va);
    }
    KLP[outb + (size_t)(n0 + l) * 64 + o] = (bf16)ka;
    VLP[outb + (size_t)(n0 + l) * 64 + o] = (bf16)va;
  }
}

// ---------------- mask precompute: bit-packed (1 = masked) — R3-verified ----------------
__global__ __launch_bounds__(256) void maskprep(const float* __restrict__ mask,
                                                uint64_t* __restrict__ gm,
                                                uint64_t* __restrict__ wm) {
  int row = blockIdx.x * 4 + (threadIdx.x >> 6);  // b*L + l
  int lane = threadIdx.x & 63;
  if (row >= B_ * L_) return;
  int b = row / L_, l = row % L_;
  const float* mr = mask + (size_t)b * L_ * L_ + (size_t)l * L_;
  for (int w = 0; w < 32; ++w) {
    int m = w * 64 + lane;
    bool masked = (m >= L_) ? true : (mr[m] == 0.0f);
    uint64_t bal = __ballot(masked);
    if (lane == 0) gm[(size_t)row * 32 + w] = bal;
  }
  for (int w = 0; w < 11; ++w) {
    int n = w * 64 + lane;
    bool lmask = true;
    if (n < NW_) {
      float s = mr[3 * n] + mr[3 * n + 1] + mr[3 * n + 2];
      lmask = !(s >= 2.0f);
    }
    uint64_t bal = __ballot(lmask);
    if (lane == 0) wm[(size_t)row * 11 + w] = bal;
  }
}

// ---------------- global scores: MFMA QK^T two-pass -> normalized pg only ----------------
__global__ __launch_bounds__(256) void attn_gs(const bf16* __restrict__ Q,
    const bf16* __restrict__ K, const uint64_t* __restrict__ GM,
    float* __restrict__ OP) {
  __shared__ float sums[64];
  int lane = threadIdx.x & 63, wave = threadIdx.x >> 6;
  int lid = lane & 15, g = lane >> 4;
  int q0 = blockIdx.x * 16;
  int bh = blockIdx.y;
  int b = bh >> 3, h = bh & 7;
  const bf16* qb = Q + (size_t)b * L_ * 1024 + h * 64;
  const bf16* kb = K + (size_t)bh * LP_ * 64;
  const uint64_t* gmb = GM + (size_t)b * L_ * 32;

  bf16x8 aq0 = zf8(), aq1 = zf8();
  {
    int qr = q0 + lid;
    if (qr < L_) {
      aq0 = *reinterpret_cast<const bf16x8*>(qb + (size_t)qr * 1024 + g * 8);
      aq1 = *reinterpret_cast<const bf16x8*>(qb + (size_t)qr * 1024 + 32 + g * 8);
    }
  }
  // pass A: row sums
  float rs[4] = {0.f, 0.f, 0.f, 0.f};
  for (int p = wave; p < 64; p += 4) {
#pragma unroll
    for (int tt = 0; tt < 2; ++tt) {
      int col = p * 32 + tt * 16 + lid;
      bf16x8 bk0 = *reinterpret_cast<const bf16x8*>(kb + (size_t)col * 64 + g * 8);
      bf16x8 bk1 = *reinterpret_cast<const bf16x8*>(kb + (size_t)col * 64 + 32 + g * 8);
      f32x4 acc = {0.f, 0.f, 0.f, 0.f};
      acc = __builtin_amdgcn_mfma_f32_16x16x32_bf16(aq0, bk0, acc, 0, 0, 0);
      acc = __builtin_amdgcn_mfma_f32_16x16x32_bf16(aq1, bk1, acc, 0, 0, 0);
      int wi = col >> 6, bit = col & 63;
#pragma unroll
      for (int r = 0; r < 4; ++r) {
        int qr = q0 + g * 4 + r;
        uint64_t w = (qr < L_) ? gmb[(size_t)qr * 32 + wi] : ~0ull;
        rs[r] += ((w >> bit) & 1) ? 0.0f : __expf(acc[r] * SCALE_);
      }
    }
  }
#pragma unroll
  for (int off = 8; off >= 1; off >>= 1)
#pragma unroll
    for (int r = 0; r < 4; ++r) rs[r] += __shfl_xor(rs[r], off, 64);
  if (lid == 0) {
#pragma unroll
    for (int r = 0; r < 4; ++r) sums[wave * 16 + g * 4 + r] = rs[r];
  }
  __syncthreads();
  float invr[4];
#pragma unroll
  for (int r = 0; r < 4; ++r) {
    int row = g * 4 + r;
    float s = sums[row] + sums[16 + row] + sums[32 + row] + sums[48 + row];
    invr[r] = (s > 0.f) ? 1.0f / s : 0.0f;
  }
  // pass B: recompute, write normalized pg
  const size_t pgbase = (size_t)bh * L_ * L_;
  for (int p = wave; p < 64; p += 4) {
#pragma unroll
    for (int tt = 0; tt < 2; ++tt) {
      int col = p * 32 + tt * 16 + lid;
      bf16x8 bk0 = *reinterpret_cast<const bf16x8*>(kb + (size_t)col * 64 + g * 8);
      bf16x8 bk1 = *reinterpret_cast<const bf16x8*>(kb + (size_t)col * 64 + 32 + g * 8);
      f32x4 acc = {0.f, 0.f, 0.f, 0.f};
      acc = __builtin_amdgcn_mfma_f32_16x16x32_bf16(aq0, bk0, acc, 0, 0, 0);
      acc = __builtin_amdgcn_mfma_f32_16x16x32_bf16(aq1, bk1, acc, 0, 0, 0);
      int wi = col >> 6, bit = col & 63;
#pragma unroll
      for (int r = 0; r < 4; ++r) {
        int qr = q0 + g * 4 + r;
        uint64_t w = (qr < L_) ? gmb[(size_t)qr * 32 + wi] : ~0ull;
        float pv = ((w >> bit) & 1) ? 0.0f : __expf(acc[r] * SCALE_);
        if (qr < L_ && col < L_) OP[pgbase + (size_t)qr * L_ + col] = pv * invr[r];
      }
    }
  }
}

// ---------------- local scores: MFMA QK^T two-pass -> normalized pl only ----------------
__global__ __launch_bounds__(256) void attn_ls(const bf16* __restrict__ Q,
    const bf16* __restrict__ K, const uint64_t* __restrict__ WM,
    float* __restrict__ OP) {
  __shared__ float sums[64];
  int lane = threadIdx.x & 63, wave = threadIdx.x >> 6;
  int lid = lane & 15, g = lane >> 4;
  int q0 = blockIdx.x * 16;
  int bh = blockIdx.y;
  int b = bh >> 3, h = bh & 7;
  const bf16* qb = Q + (size_t)b * L_ * 1024 + (8 + h) * 64;
  const bf16* kb = K + (size_t)bh * NWP_ * 64;
  const uint64_t* wmb = WM + (size_t)b * L_ * 11;

  bf16x8 aq0 = zf8(), aq1 = zf8();
  {
    int qr = q0 + lid;
    if (qr < L_) {
      aq0 = *reinterpret_cast<const bf16x8*>(qb + (size_t)qr * 1024 + g * 8);
      aq1 = *reinterpret_cast<const bf16x8*>(qb + (size_t)qr * 1024 + 32 + g * 8);
    }
  }
  float rs[4] = {0.f, 0.f, 0.f, 0.f};
  for (int p = wave; p < 22; p += 4) {
#pragma unroll
    for (int tt = 0; tt < 2; ++tt) {
      int col = p * 32 + tt * 16 + lid;
      bf16x8 bk0 = *reinterpret_cast<const bf16x8*>(kb + (size_t)col * 64 + g * 8);
      bf16x8 bk1 = *reinterpret_cast<const bf16x8*>(kb + (size_t)col * 64 + 32 + g * 8);
      f32x4 acc = {0.f, 0.f, 0.f, 0.f};
      acc = __builtin_amdgcn_mfma_f32_16x16x32_bf16(aq0, bk0, acc, 0, 0, 0);
      acc = __builtin_amdgcn_mfma_f32_16x16x32_bf16(aq1, bk1, acc, 0, 0, 0);
      int wi = col >> 6, bit = col & 63;
#pragma unroll
      for (int r = 0; r < 4; ++r) {
        int qr = q0 + g * 4 + r;
        uint64_t w = (qr < L_) ? wmb[(size_t)qr * 11 + wi] : ~0ull;
        rs[r] += ((w >> bit) & 1) ? 0.0f : __expf(acc[r] * SCALE_);
      }
    }
  }
#pragma unroll
  for (int off = 8; off >= 1; off >>= 1)
#pragma unroll
    for (int r = 0; r < 4; ++r) rs[r] += __shfl_xor(rs[r], off, 64);
  if (lid == 0) {
#pragma unroll
    for (int r = 0; r < 4; ++r) sums[wave * 16 + g * 4 + r] = rs[r];
  }
  __syncthreads();
  float invr[4];
#pragma unroll
  for (int r = 0; r < 4; ++r) {
    int row = g * 4 + r;
    float s = sums[row] + sums[16 + row] + sums[32 + row] + sums[48 + row];
    invr[r] = (s > 0.f) ? 1.0f / s : 0.0f;
  }
  const size_t plbase = (size_t)bh * L_ * NW_;
  for (int p = wave; p < 22; p += 4) {
#pragma unroll
    for (int tt = 0; tt < 2; ++tt) {
      int col = p * 32 + tt * 16 + lid;
      bf16x8 bk0 = *reinterpret_cast<const bf16x8*>(kb + (size_t)col * 64 + g * 8);
      bf16x8 bk1 = *reinterpret_cast<const bf16x8*>(kb + (size_t)col * 64 + 32 + g * 8);
      f32x4 acc = {0.f, 0.f, 0.f, 0.f};
      acc = __builtin_amdgcn_mfma_f32_16x16x32_bf16(aq0, bk0, acc, 0, 0, 0);
      acc = __builtin_amdgcn_mfma_f32_16x16x32_bf16(aq1, bk1, acc, 0, 0, 0);
      int wi = col >> 6, bit = col & 63;
#pragma unroll
      for (int r = 0; r < 4; ++r) {
        int qr = q0 + g * 4 + r;
        uint64_t w = (qr < L_) ? wmb[(size_t)qr * 11 + wi] : ~0ull;
        float pv = ((w >> bit) & 1) ? 0.0f : __expf(acc[r] * SCALE_);
        if (qr < L_ && col < NW_) OP[plbase + (size_t)qr * NW_ + col] = pv * invr[r];
      }
    }
  }
}

// ---------------- PV from normalized P (read back from d_out), VALU ----------------
// wave = 4 q-rows, lane = d. grid (128, 16): 2048 q-rows covered.
__global__ __launch_bounds__(256) void pv_g(const float* __restrict__ P,
    const bf16* __restrict__ V, float* __restrict__ OV) {
  int lane = threadIdx.x & 63, wave = threadIdx.x >> 6;
  int bh = blockIdx.y, b = bh >> 3, h = bh & 7;
  int q0 = blockIdx.x * 16 + wave * 4;
  const bf16* Vb = V + (size_t)bh * LP_ * 64 + lane;
  const float* Pb = P + (size_t)bh * L_ * L_;
  const float* p0 = Pb + (size_t)((q0 + 0 < L_) ? q0 + 0 : L_ - 1) * L_;
  const float* p1 = Pb + (size_t)((q0 + 1 < L_) ? q0 + 1 : L_ - 1) * L_;
  const float* p2 = Pb + (size_t)((q0 + 2 < L_) ? q0 + 2 : L_ - 1) * L_;
  const float* p3 = Pb + (size_t)((q0 + 3 < L_) ? q0 + 3 : L_ - 1) * L_;
  float a0 = 0.f, a1 = 0.f, a2 = 0.f, a3 = 0.f;
#pragma unroll 2
  for (int m = 0; m < L_; ++m) {
    float v = (float)Vb[(size_t)m * 64];
    a0 = fmaf(p0[m], v, a0);
    a1 = fmaf(p1[m], v, a1);
    a2 = fmaf(p2[m], v, a2);
    a3 = fmaf(p3[m], v, a3);
  }
  float* ob = OV + (((size_t)b * 16 + h) * L_) * 64 + lane;
  if (q0 + 0 < L_) ob[(size_t)(q0 + 0) * 64] = a0;
  if (q0 + 1 < L_) ob[(size_t)(q0 + 1) * 64] = a1;
  if (q0 + 2 < L_) ob[(size_t)(q0 + 2) * 64] = a2;
  if (q0 + 3 < L_) ob[(size_t)(q0 + 3) * 64] = a3;
}

__global__ __launch_bounds__(256) void pv_l(const float* __restrict__ P,
    const bf16* __restrict__ V, float* __restrict__ OV) {
  int lane = threadIdx.x & 63, wave = threadIdx.x >> 6;
  int bh = blockIdx.y, b = bh >> 3, h = bh & 7;
  int q0 = blockIdx.x * 16 + wave * 4;
  const bf16* Vb = V + (size_t)bh * NWP_ * 64 + lane;
  const float* Pb = P + (size_t)bh * L_ * NW_;
  const float* p0 = Pb + (size_t)((q0 + 0 < L_) ? q0 + 0 : L_ - 1) * NW_;
  const float* p1 = Pb + (size_t)((q0 + 1 < L_) ? q0 + 1 : L_ - 1) * NW_;
  const float* p2 = Pb + (size_t)((q0 + 2 < L_) ? q0 + 2 : L_ - 1) * NW_;
  const float* p3 = Pb + (size_t)((q0 + 3 < L_) ? q0 + 3 : L_ - 1) * NW_;
  float a0 = 0.f, a1 = 0.f, a2 = 0.f, a3 = 0.f;
#pragma unroll 2
  for (int m = 0; m < NW_; ++m) {
    float v = (float)Vb[(size_t)m * 64];
    a0 = fmaf(p0[m], v, a0);
    a1 = fmaf(p1[m], v, a1);
    a2 = fmaf(p2[m], v, a2);
    a3 = fmaf(p3[m], v, a3);
  }
  float* ob = OV + (((size_t)b * 16 + 8 + h) * L_) * 64 + lane;
  if (q0 + 0 < L_) ob[(size_t)(q0 + 0) * 64] = a0;
  if (q0 + 1 < L_) ob[(size_t)(q0 + 1) * 64] = a1;
  if (q0 + 2 < L_) ob[(size_t)(q0 + 2) * 64] = a2;
  if (q0 + 3 < L_) ob[(size_t)(q0 + 3) * 64] = a3;
}

extern "C" void kernel_launch(void* const* d_in, const int* in_sizes, int n_in,
                              void* d_out, int out_size, void* d_ws, size_t ws_size,
                              hipStream_t stream) {
  (void)in_sizes; (void)n_in; (void)out_size; (void)ws_size;
  const float* x    = (const float*)d_in[0];
  const float* mask = (const float*)d_in[1];
  const float* Wq   = (const float*)d_in[2];
  const float* bq   = (const float*)d_in[3];
  const float* Wk   = (const float*)d_in[4];
  const float* bk   = (const float*)d_in[5];
  const float* Wv   = (const float*)d_in[6];
  const float* bv   = (const float*)d_in[7];

  char* ws = (char*)d_ws;
  bf16* qbb     = (bf16*)(ws + 0);            // 8,380,416
  bf16* kgb     = (bf16*)(ws + 8380416);      // 4,194,304
  bf16* vgb     = (bf16*)(ws + 12574720);     // 4,194,304 (row-major V)
  bf16* klb     = (bf16*)(ws + 16769024);     // 1,441,792
  bf16* vlb     = (bf16*)(ws + 18210816);     // 1,441,792
  uint64_t* gm  = (uint64_t*)(ws + 19652608); // 1,047,552
  uint64_t* wm  = (uint64_t*)(ws + 20700160); // 360,096

  float* out    = (float*)d_out;
  float* o_vall = out;                 // (2,16,2046,64)
  float* o_pg   = out + 4190208;       // (2,8,2046,2046)
  float* o_pl   = out + 71168064;      // (2,8,2046,682)

  qgemm32<<<dim3(64, 16), 256, 0, stream>>>(x, Wq, bq, qbb);
  proj_g32<<<dim3(32, 16), 256, 0, stream>>>(x, Wk, bk, Wv, bv, kgb, vgb);
  proj_l32<<<dim3(11, 16), 256, 0, stream>>>(x, Wk, bk, Wv, bv, klb, vlb);
  maskprep<<<1023, 256, 0, stream>>>(mask, gm, wm);

  attn_gs<<<dim3(128, 16), 256, 0, stream>>>(qbb, kgb, gm, o_pg);
  attn_ls<<<dim3(128, 16), 256, 0, stream>>>(qbb, klb, wm, o_pl);

  pv_g<<<dim3(128, 16), 256, 0, stream>>>(o_pg, vgb, o_vall);
  pv_l<<<dim3(128, 16), 256, 0, stream>>>(o_pl, vlb, o_vall);
}

// Round 6
// 744.994 us; speedup vs baseline: 10.0649x; 2.9493x over previous
//
#include <hip/hip_runtime.h>
#include <hip/hip_bf16.h>
#include <stdint.h>

typedef __bf16 bf16;
typedef bf16 bf16x8 __attribute__((ext_vector_type(8)));
typedef float f32x4 __attribute__((ext_vector_type(4)));

#define B_ 2
#define L_ 2046
#define H_ 16
#define NW_ 682
#define LP_ 2048
#define NWP_ 704
#define M_ (B_*L_)
#define SCALE_ 0.125f

__device__ inline bf16x8 zf8() {
  bf16x8 v;
#pragma unroll
  for (int e = 0; e < 8; ++e) v[e] = (bf16)0.0f;
  return v;
}

// ---------------- q = x @ Wq^T + bq  (f32 math, bf16 out) — R3-verified ----------------
__global__ __launch_bounds__(256) void qgemm32(const float* __restrict__ X,
                                               const float* __restrict__ W,
                                               const float* __restrict__ bq,
                                               bf16* __restrict__ Q) {
  __shared__ float xs[64][17];
  __shared__ float wsm[64][17];
  int t = threadIdx.x;
  int tx = t & 15, ty = t >> 4;
  int m0 = blockIdx.x * 64, n0 = blockIdx.y * 64;
  float acc[4][4];
#pragma unroll
  for (int i = 0; i < 4; ++i)
#pragma unroll
    for (int j = 0; j < 4; ++j) acc[i][j] = 0.f;
  for (int kt = 0; kt < 1024; kt += 16) {
    for (int i = t; i < 1024; i += 256) {
      int r = i >> 4, c = i & 15;
      int row = m0 + r;
      xs[r][c] = (row < M_) ? X[(size_t)row * 1024 + kt + c] : 0.f;
      wsm[r][c] = W[(size_t)(n0 + r) * 1024 + kt + c];
    }
    __syncthreads();
#pragma unroll
    for (int kk = 0; kk < 16; ++kk) {
      float a[4], bv[4];
#pragma unroll
      for (int i = 0; i < 4; ++i) a[i] = xs[ty * 4 + i][kk];
#pragma unroll
      for (int j = 0; j < 4; ++j) bv[j] = wsm[tx * 4 + j][kk];
#pragma unroll
      for (int i = 0; i < 4; ++i)
#pragma unroll
        for (int j = 0; j < 4; ++j) acc[i][j] = fmaf(a[i], bv[j], acc[i][j]);
    }
    __syncthreads();
  }
#pragma unroll
  for (int i = 0; i < 4; ++i) {
    int row = m0 + ty * 4 + i;
    if (row < M_) {
#pragma unroll
      for (int j = 0; j < 4; ++j) {
        int col = n0 + tx * 4 + j;
        Q[(size_t)row * 1024 + col] = (bf16)(acc[i][j] + bq[col]);
      }
    }
  }
}

// ---------------- global-head K/V projections (f32 math, bf16 row-major out) ----------------
__global__ __launch_bounds__(256) void proj_g32(const float* __restrict__ x,
    const float* __restrict__ Wk, const float* __restrict__ bk,
    const float* __restrict__ Wv, const float* __restrict__ bv,
    bf16* __restrict__ KGP, bf16* __restrict__ VGP) {
  __shared__ float xs[64][64];
  __shared__ float wks[64][65];
  __shared__ float wvs[64][65];
  int t = threadIdx.x;
  int lb = blockIdx.x, bh = blockIdx.y;
  int b = bh >> 3, h = bh & 7;
  int l0 = lb * 64;
  for (int idx = t; idx < 4096; idx += 256) {
    int r = idx >> 6, c = idx & 63;
    int l = l0 + r;
    xs[r][c] = (l < L_) ? x[((size_t)b * L_ + l) * 1024 + h * 64 + c] : 0.0f;
    wks[r][c] = Wk[(size_t)h * 4096 + idx];
    wvs[r][c] = Wv[(size_t)h * 4096 + idx];
  }
  __syncthreads();
  int o = t & 63, lg = t >> 6;
  float kbias = bk[h * 64 + o], vbias = bv[h * 64 + o];
  const size_t outb = (size_t)bh * LP_ * 64;
  for (int ls = 0; ls < 16; ++ls) {
    int l = lg * 16 + ls;
    float ka = kbias, va = vbias;
#pragma unroll
    for (int i = 0; i < 64; ++i) {
      float xv = xs[l][i];
      ka = fmaf(xv, wks[o][i], ka);
      va = fmaf(xv, wvs[o][i], va);
    }
    KGP[outb + (size_t)(l0 + l) * 64 + o] = (bf16)ka;
    VGP[outb + (size_t)(l0 + l) * 64 + o] = (bf16)va;
  }
}

// ---------------- local-head window-avg + K/V projections (f32 math, bf16 out) ----------------
__global__ __launch_bounds__(256) void proj_l32(const float* __restrict__ x,
    const float* __restrict__ Wk, const float* __restrict__ bk,
    const float* __restrict__ Wv, const float* __restrict__ bv,
    bf16* __restrict__ KLP, bf16* __restrict__ VLP) {
  __shared__ float xs[64][64];
  __shared__ float wks[64][65];
  __shared__ float wvs[64][65];
  int t = threadIdx.x;
  int nb = blockIdx.x, bh = blockIdx.y;
  int b = bh >> 3, h = bh & 7;
  int n0 = nb * 64;
  int hh = 8 + h;
  for (int idx = t; idx < 4096; idx += 256) {
    int r = idx >> 6, c = idx & 63;
    int n = n0 + r;
    float v = 0.0f;
    if (n < NW_) {
      size_t base = ((size_t)b * L_ + 3 * n) * 1024 + hh * 64 + c;
      v = (x[base] + x[base + 1024] + x[base + 2048]) * (1.0f / 3.0f);
    }
    xs[r][c] = v;
    wks[r][c] = Wk[(size_t)hh * 4096 + idx];
    wvs[r][c] = Wv[(size_t)hh * 4096 + idx];
  }
  __syncthreads();
  int o = t & 63, lg = t >> 6;
  float kbias = bk[hh * 64 + o], vbias = bv[hh * 64 + o];
  const size_t outb = (size_t)bh * NWP_ * 64;
  for (int ls = 0; ls < 16; ++ls) {
    int l = lg * 16 + ls;
    float ka = kbias, va = vbias;
#pragma unroll
    for (int i = 0; i < 64; ++i) {
      float xv = xs[l][i];
      ka = fmaf(xv, wks[o][i], ka);
      va = fmaf(xv, wvs[o][i], va);
    }
    KLP[outb + (size_t)(n0 + l) * 64 + o] = (bf16)ka;
    VLP[outb + (size_t)(n0 + l) * 64 + o] = (bf16)va;
  }
}

// ---------------- mask precompute: bit-packed (1 = masked) — R3-verified ----------------
__global__ __launch_bounds__(256) void maskprep(const float* __restrict__ mask,
                                                uint64_t* __restrict__ gm,
                                                uint64_t* __restrict__ wm) {
  int row = blockIdx.x * 4 + (threadIdx.x >> 6);  // b*L + l
  int lane = threadIdx.x & 63;
  if (row >= B_ * L_) return;
  int b = row / L_, l = row % L_;
  const float* mr = mask + (size_t)b * L_ * L_ + (size_t)l * L_;
  for (int w = 0; w < 32; ++w) {
    int m = w * 64 + lane;
    bool masked = (m >= L_) ? true : (mr[m] == 0.0f);
    uint64_t bal = __ballot(masked);
    if (lane == 0) gm[(size_t)row * 32 + w] = bal;
  }
  for (int w = 0; w < 11; ++w) {
    int n = w * 64 + lane;
    bool lmask = true;
    if (n < NW_) {
      float s = mr[3 * n] + mr[3 * n + 1] + mr[3 * n + 2];
      lmask = !(s >= 2.0f);
    }
    uint64_t bal = __ballot(lmask);
    if (lane == 0) wm[(size_t)row * 11 + w] = bal;
  }
}

// ---------------- global scores: MFMA QK^T two-pass -> normalized pg (R5-verified) ----------------
__global__ __launch_bounds__(256) void attn_gs(const bf16* __restrict__ Q,
    const bf16* __restrict__ K, const uint64_t* __restrict__ GM,
    float* __restrict__ OP) {
  __shared__ float sums[64];
  int lane = threadIdx.x & 63, wave = threadIdx.x >> 6;
  int lid = lane & 15, g = lane >> 4;
  int q0 = blockIdx.x * 16;
  int bh = blockIdx.y;
  int b = bh >> 3, h = bh & 7;
  const bf16* qb = Q + (size_t)b * L_ * 1024 + h * 64;
  const bf16* kb = K + (size_t)bh * LP_ * 64;
  const uint64_t* gmb = GM + (size_t)b * L_ * 32;

  bf16x8 aq0 = zf8(), aq1 = zf8();
  {
    int qr = q0 + lid;
    if (qr < L_) {
      aq0 = *reinterpret_cast<const bf16x8*>(qb + (size_t)qr * 1024 + g * 8);
      aq1 = *reinterpret_cast<const bf16x8*>(qb + (size_t)qr * 1024 + 32 + g * 8);
    }
  }
  // pass A: row sums
  float rs[4] = {0.f, 0.f, 0.f, 0.f};
  for (int p = wave; p < 64; p += 4) {
#pragma unroll
    for (int tt = 0; tt < 2; ++tt) {
      int col = p * 32 + tt * 16 + lid;
      bf16x8 bk0 = *reinterpret_cast<const bf16x8*>(kb + (size_t)col * 64 + g * 8);
      bf16x8 bk1 = *reinterpret_cast<const bf16x8*>(kb + (size_t)col * 64 + 32 + g * 8);
      f32x4 acc = {0.f, 0.f, 0.f, 0.f};
      acc = __builtin_amdgcn_mfma_f32_16x16x32_bf16(aq0, bk0, acc, 0, 0, 0);
      acc = __builtin_amdgcn_mfma_f32_16x16x32_bf16(aq1, bk1, acc, 0, 0, 0);
      int wi = col >> 6, bit = col & 63;
#pragma unroll
      for (int r = 0; r < 4; ++r) {
        int qr = q0 + g * 4 + r;
        uint64_t w = (qr < L_) ? gmb[(size_t)qr * 32 + wi] : ~0ull;
        rs[r] += ((w >> bit) & 1) ? 0.0f : __expf(acc[r] * SCALE_);
      }
    }
  }
#pragma unroll
  for (int off = 8; off >= 1; off >>= 1)
#pragma unroll
    for (int r = 0; r < 4; ++r) rs[r] += __shfl_xor(rs[r], off, 64);
  if (lid == 0) {
#pragma unroll
    for (int r = 0; r < 4; ++r) sums[wave * 16 + g * 4 + r] = rs[r];
  }
  __syncthreads();
  float invr[4];
#pragma unroll
  for (int r = 0; r < 4; ++r) {
    int row = g * 4 + r;
    float s = sums[row] + sums[16 + row] + sums[32 + row] + sums[48 + row];
    invr[r] = (s > 0.f) ? 1.0f / s : 0.0f;
  }
  // pass B: recompute, write normalized pg
  const size_t pgbase = (size_t)bh * L_ * L_;
  for (int p = wave; p < 64; p += 4) {
#pragma unroll
    for (int tt = 0; tt < 2; ++tt) {
      int col = p * 32 + tt * 16 + lid;
      bf16x8 bk0 = *reinterpret_cast<const bf16x8*>(kb + (size_t)col * 64 + g * 8);
      bf16x8 bk1 = *reinterpret_cast<const bf16x8*>(kb + (size_t)col * 64 + 32 + g * 8);
      f32x4 acc = {0.f, 0.f, 0.f, 0.f};
      acc = __builtin_amdgcn_mfma_f32_16x16x32_bf16(aq0, bk0, acc, 0, 0, 0);
      acc = __builtin_amdgcn_mfma_f32_16x16x32_bf16(aq1, bk1, acc, 0, 0, 0);
      int wi = col >> 6, bit = col & 63;
#pragma unroll
      for (int r = 0; r < 4; ++r) {
        int qr = q0 + g * 4 + r;
        uint64_t w = (qr < L_) ? gmb[(size_t)qr * 32 + wi] : ~0ull;
        float pv = ((w >> bit) & 1) ? 0.0f : __expf(acc[r] * SCALE_);
        if (qr < L_ && col < L_) OP[pgbase + (size_t)qr * L_ + col] = pv * invr[r];
      }
    }
  }
}

// ---------------- local scores: MFMA QK^T two-pass -> normalized pl (R5-verified) ----------------
__global__ __launch_bounds__(256) void attn_ls(const bf16* __restrict__ Q,
    const bf16* __restrict__ K, const uint64_t* __restrict__ WM,
    float* __restrict__ OP) {
  __shared__ float sums[64];
  int lane = threadIdx.x & 63, wave = threadIdx.x >> 6;
  int lid = lane & 15, g = lane >> 4;
  int q0 = blockIdx.x * 16;
  int bh = blockIdx.y;
  int b = bh >> 3, h = bh & 7;
  const bf16* qb = Q + (size_t)b * L_ * 1024 + (8 + h) * 64;
  const bf16* kb = K + (size_t)bh * NWP_ * 64;
  const uint64_t* wmb = WM + (size_t)b * L_ * 11;

  bf16x8 aq0 = zf8(), aq1 = zf8();
  {
    int qr = q0 + lid;
    if (qr < L_) {
      aq0 = *reinterpret_cast<const bf16x8*>(qb + (size_t)qr * 1024 + g * 8);
      aq1 = *reinterpret_cast<const bf16x8*>(qb + (size_t)qr * 1024 + 32 + g * 8);
    }
  }
  float rs[4] = {0.f, 0.f, 0.f, 0.f};
  for (int p = wave; p < 22; p += 4) {
#pragma unroll
    for (int tt = 0; tt < 2; ++tt) {
      int col = p * 32 + tt * 16 + lid;
      bf16x8 bk0 = *reinterpret_cast<const bf16x8*>(kb + (size_t)col * 64 + g * 8);
      bf16x8 bk1 = *reinterpret_cast<const bf16x8*>(kb + (size_t)col * 64 + 32 + g * 8);
      f32x4 acc = {0.f, 0.f, 0.f, 0.f};
      acc = __builtin_amdgcn_mfma_f32_16x16x32_bf16(aq0, bk0, acc, 0, 0, 0);
      acc = __builtin_amdgcn_mfma_f32_16x16x32_bf16(aq1, bk1, acc, 0, 0, 0);
      int wi = col >> 6, bit = col & 63;
#pragma unroll
      for (int r = 0; r < 4; ++r) {
        int qr = q0 + g * 4 + r;
        uint64_t w = (qr < L_) ? wmb[(size_t)qr * 11 + wi] : ~0ull;
        rs[r] += ((w >> bit) & 1) ? 0.0f : __expf(acc[r] * SCALE_);
      }
    }
  }
#pragma unroll
  for (int off = 8; off >= 1; off >>= 1)
#pragma unroll
    for (int r = 0; r < 4; ++r) rs[r] += __shfl_xor(rs[r], off, 64);
  if (lid == 0) {
#pragma unroll
    for (int r = 0; r < 4; ++r) sums[wave * 16 + g * 4 + r] = rs[r];
  }
  __syncthreads();
  float invr[4];
#pragma unroll
  for (int r = 0; r < 4; ++r) {
    int row = g * 4 + r;
    float s = sums[row] + sums[16 + row] + sums[32 + row] + sums[48 + row];
    invr[r] = (s > 0.f) ? 1.0f / s : 0.0f;
  }
  const size_t plbase = (size_t)bh * L_ * NW_;
  for (int p = wave; p < 22; p += 4) {
#pragma unroll
    for (int tt = 0; tt < 2; ++tt) {
      int col = p * 32 + tt * 16 + lid;
      bf16x8 bk0 = *reinterpret_cast<const bf16x8*>(kb + (size_t)col * 64 + g * 8);
      bf16x8 bk1 = *reinterpret_cast<const bf16x8*>(kb + (size_t)col * 64 + 32 + g * 8);
      f32x4 acc = {0.f, 0.f, 0.f, 0.f};
      acc = __builtin_amdgcn_mfma_f32_16x16x32_bf16(aq0, bk0, acc, 0, 0, 0);
      acc = __builtin_amdgcn_mfma_f32_16x16x32_bf16(aq1, bk1, acc, 0, 0, 0);
      int wi = col >> 6, bit = col & 63;
#pragma unroll
      for (int r = 0; r < 4; ++r) {
        int qr = q0 + g * 4 + r;
        uint64_t w = (qr < L_) ? wmb[(size_t)qr * 11 + wi] : ~0ull;
        float pv = ((w >> bit) & 1) ? 0.0f : __expf(acc[r] * SCALE_);
        if (qr < L_ && col < NW_) OP[plbase + (size_t)qr * NW_ + col] = pv * invr[r];
      }
    }
  }
}

// ---------------- PV via MFMA: O = P @ V, P read back (f32) from d_out ----------------
// grid (32, 16): block = 64 q-rows, 4 waves x 16 rows each; LDS-staged V^T per 32-key tile.
template <int MT, int ML, int VROWS>
__global__ __launch_bounds__(256) void pv_mfma(const float* __restrict__ P,
    const bf16* __restrict__ V, float* __restrict__ OV, int hbase) {
  __shared__ bf16 vt[64][40];            // vt[d][mloc], 80B row stride (16B-aligned)
  int t = threadIdx.x;
  int lane = t & 63, wave = t >> 6;
  int lid = lane & 15, g = lane >> 4;
  int bh = blockIdx.y, b = bh >> 3, h = bh & 7;
  int q0w = blockIdx.x * 64 + wave * 16;
  const float* Pb = P + (size_t)bh * L_ * ML;
  const bf16* Vb = V + (size_t)bh * VROWS * 64;
  int arow = q0w + lid; if (arow >= L_) arow = L_ - 1;   // clamp; results discarded
  const float* prow = Pb + (size_t)arow * ML;
  int sd = t & 63, mgrp = t >> 6;        // staging map: d = sd, m-group = mgrp
  f32x4 vacc[4];
  f32x4 z4 = {0.f, 0.f, 0.f, 0.f};
#pragma unroll
  for (int dg = 0; dg < 4; ++dg) vacc[dg] = z4;

  for (int mt = 0; mt < MT; ++mt) {
    int m0 = mt * 32;
    // stage V[m0..m0+32)[0..64) -> vt[d][m] (8 coalesced reads -> 1 b128 LDS write)
    bf16 stmp[8];
#pragma unroll
    for (int e = 0; e < 8; ++e)
      stmp[e] = Vb[(size_t)(m0 + mgrp * 8 + e) * 64 + sd];
    *reinterpret_cast<bf16x8*>(&vt[sd][mgrp * 8]) = *reinterpret_cast<const bf16x8*>(stmp);
    __syncthreads();
    // A-fragment: P[arow][m0 + g*8 + e], zero-padded past ML
    bf16x8 pa;
    if (m0 + 32 <= ML) {
      const float* pp = prow + m0 + g * 8;
#pragma unroll
      for (int e = 0; e < 8; ++e) pa[e] = (bf16)pp[e];
    } else {
#pragma unroll
      for (int e = 0; e < 8; ++e) {
        int m = m0 + g * 8 + e;
        pa[e] = (m < ML) ? (bf16)prow[m] : (bf16)0.0f;
      }
    }
#pragma unroll
    for (int dg = 0; dg < 4; ++dg) {
      bf16x8 bv8 = *reinterpret_cast<const bf16x8*>(&vt[dg * 16 + lid][g * 8]);
      vacc[dg] = __builtin_amdgcn_mfma_f32_16x16x32_bf16(pa, bv8, vacc[dg], 0, 0, 0);
    }
    __syncthreads();
  }
  float* ob = OV + (((size_t)b * 16 + hbase + h) * L_) * 64;
#pragma unroll
  for (int dg = 0; dg < 4; ++dg)
#pragma unroll
    for (int r = 0; r < 4; ++r) {
      int qr = q0w + g * 4 + r;
      if (qr < L_) ob[(size_t)qr * 64 + dg * 16 + lid] = vacc[dg][r];
    }
}

extern "C" void kernel_launch(void* const* d_in, const int* in_sizes, int n_in,
                              void* d_out, int out_size, void* d_ws, size_t ws_size,
                              hipStream_t stream) {
  (void)in_sizes; (void)n_in; (void)out_size; (void)ws_size;
  const float* x    = (const float*)d_in[0];
  const float* mask = (const float*)d_in[1];
  const float* Wq   = (const float*)d_in[2];
  const float* bq   = (const float*)d_in[3];
  const float* Wk   = (const float*)d_in[4];
  const float* bk   = (const float*)d_in[5];
  const float* Wv   = (const float*)d_in[6];
  const float* bv   = (const float*)d_in[7];

  char* ws = (char*)d_ws;
  bf16* qbb     = (bf16*)(ws + 0);            // 8,380,416
  bf16* kgb     = (bf16*)(ws + 8380416);      // 4,194,304
  bf16* vgb     = (bf16*)(ws + 12574720);     // 4,194,304 (row-major V)
  bf16* klb     = (bf16*)(ws + 16769024);     // 1,441,792
  bf16* vlb     = (bf16*)(ws + 18210816);     // 1,441,792
  uint64_t* gm  = (uint64_t*)(ws + 19652608); // 1,047,552
  uint64_t* wm  = (uint64_t*)(ws + 20700160); // 360,096

  float* out    = (float*)d_out;
  float* o_vall = out;                 // (2,16,2046,64)
  float* o_pg   = out + 4190208;       // (2,8,2046,2046)
  float* o_pl   = out + 71168064;      // (2,8,2046,682)

  qgemm32<<<dim3(64, 16), 256, 0, stream>>>(x, Wq, bq, qbb);
  proj_g32<<<dim3(32, 16), 256, 0, stream>>>(x, Wk, bk, Wv, bv, kgb, vgb);
  proj_l32<<<dim3(11, 16), 256, 0, stream>>>(x, Wk, bk, Wv, bv, klb, vlb);
  maskprep<<<1023, 256, 0, stream>>>(mask, gm, wm);

  attn_gs<<<dim3(128, 16), 256, 0, stream>>>(qbb, kgb, gm, o_pg);
  attn_ls<<<dim3(128, 16), 256, 0, stream>>>(qbb, klb, wm, o_pl);

  pv_mfma<64, L_, LP_><<<dim3(32, 16), 256, 0, stream>>>(o_pg, vgb, o_vall, 0);
  pv_mfma<22, NW_, NWP_><<<dim3(32, 16), 256, 0, stream>>>(o_pl, vlb, o_vall, 8);
}

// Round 7
// 612.013 us; speedup vs baseline: 12.2518x; 1.2173x over previous
//
#include <hip/hip_runtime.h>
#include <hip/hip_bf16.h>
#include <stdint.h>

typedef __bf16 bf16;
typedef bf16 bf16x8 __attribute__((ext_vector_type(8)));
typedef float f32x4 __attribute__((ext_vector_type(4)));

#define B_ 2
#define L_ 2046
#define H_ 16
#define NW_ 682
#define LP_ 2048
#define NWP_ 704
#define M_ (B_*L_)
#define SCALE_ 0.125f

__device__ inline bf16x8 zf8() {
  bf16x8 v;
#pragma unroll
  for (int e = 0; e < 8; ++e) v[e] = (bf16)0.0f;
  return v;
}

// ---------------- cast f32 -> bf16 (vectorized x4) ----------------
__global__ __launch_bounds__(256) void cast4(const float* __restrict__ in,
                                             bf16* __restrict__ out, int n) {
  int i = (blockIdx.x * 256 + threadIdx.x) * 4;
  if (i + 3 < n) {
    float4 v = *reinterpret_cast<const float4*>(in + i);
    bf16 tmp[4];
    tmp[0] = (bf16)v.x; tmp[1] = (bf16)v.y; tmp[2] = (bf16)v.z; tmp[3] = (bf16)v.w;
    *reinterpret_cast<uint64_t*>(out + i) = *reinterpret_cast<const uint64_t*>(tmp);
  } else {
    for (; i < n; ++i) out[i] = (bf16)in[i];
  }
}

// ---------------- q = x @ Wq^T + bq via MFMA (conventions R5-verified in attn_gs) ----------------
__global__ __launch_bounds__(256) void qgemm_m(const bf16* __restrict__ X,
                                               const bf16* __restrict__ W,
                                               const float* __restrict__ bq,
                                               bf16* __restrict__ Q) {
  int lane = threadIdx.x & 63, wave = threadIdx.x >> 6;
  int lid = lane & 15, g = lane >> 4;
  int m0 = blockIdx.x * 64;
  int n0 = blockIdx.y * 64 + wave * 16;
  f32x4 z4 = {0.f, 0.f, 0.f, 0.f};
  f32x4 acc[4];
#pragma unroll
  for (int rt = 0; rt < 4; ++rt) acc[rt] = z4;
  const bf16* wrow = W + (size_t)(n0 + lid) * 1024;
  for (int k = 0; k < 1024; k += 32) {
    bf16x8 bf0 = *reinterpret_cast<const bf16x8*>(wrow + k + g * 8);
#pragma unroll
    for (int rt = 0; rt < 4; ++rt) {
      int row = m0 + rt * 16 + lid;
      bf16x8 af = zf8();
      if (row < M_) af = *reinterpret_cast<const bf16x8*>(X + (size_t)row * 1024 + k + g * 8);
      acc[rt] = __builtin_amdgcn_mfma_f32_16x16x32_bf16(af, bf0, acc[rt], 0, 0, 0);
    }
  }
  int col = n0 + lid;
  float bias = bq[col];
#pragma unroll
  for (int rt = 0; rt < 4; ++rt)
#pragma unroll
    for (int r = 0; r < 4; ++r) {
      int row = m0 + rt * 16 + g * 4 + r;
      if (row < M_) Q[(size_t)row * 1024 + col] = (bf16)(acc[rt][r] + bias);
    }
}

// ---------------- global-head K/V projections (f32 math, bf16 row-major out) ----------------
__global__ __launch_bounds__(256) void proj_g32(const float* __restrict__ x,
    const float* __restrict__ Wk, const float* __restrict__ bk,
    const float* __restrict__ Wv, const float* __restrict__ bv,
    bf16* __restrict__ KGP, bf16* __restrict__ VGP) {
  __shared__ float xs[64][64];
  __shared__ float wks[64][65];
  __shared__ float wvs[64][65];
  int t = threadIdx.x;
  int lb = blockIdx.x, bh = blockIdx.y;
  int b = bh >> 3, h = bh & 7;
  int l0 = lb * 64;
  for (int idx = t; idx < 4096; idx += 256) {
    int r = idx >> 6, c = idx & 63;
    int l = l0 + r;
    xs[r][c] = (l < L_) ? x[((size_t)b * L_ + l) * 1024 + h * 64 + c] : 0.0f;
    wks[r][c] = Wk[(size_t)h * 4096 + idx];
    wvs[r][c] = Wv[(size_t)h * 4096 + idx];
  }
  __syncthreads();
  int o = t & 63, lg = t >> 6;
  float kbias = bk[h * 64 + o], vbias = bv[h * 64 + o];
  const size_t outb = (size_t)bh * LP_ * 64;
  for (int ls = 0; ls < 16; ++ls) {
    int l = lg * 16 + ls;
    float ka = kbias, va = vbias;
#pragma unroll
    for (int i = 0; i < 64; ++i) {
      float xv = xs[l][i];
      ka = fmaf(xv, wks[o][i], ka);
      va = fmaf(xv, wvs[o][i], va);
    }
    KGP[outb + (size_t)(l0 + l) * 64 + o] = (bf16)ka;
    VGP[outb + (size_t)(l0 + l) * 64 + o] = (bf16)va;
  }
}

// ---------------- local-head window-avg + K/V projections (f32 math, bf16 out) ----------------
__global__ __launch_bounds__(256) void proj_l32(const float* __restrict__ x,
    const float* __restrict__ Wk, const float* __restrict__ bk,
    const float* __restrict__ Wv, const float* __restrict__ bv,
    bf16* __restrict__ KLP, bf16* __restrict__ VLP) {
  __shared__ float xs[64][64];
  __shared__ float wks[64][65];
  __shared__ float wvs[64][65];
  int t = threadIdx.x;
  int nb = blockIdx.x, bh = blockIdx.y;
  int b = bh >> 3, h = bh & 7;
  int n0 = nb * 64;
  int hh = 8 + h;
  for (int idx = t; idx < 4096; idx += 256) {
    int r = idx >> 6, c = idx & 63;
    int n = n0 + r;
    float v = 0.0f;
    if (n < NW_) {
      size_t base = ((size_t)b * L_ + 3 * n) * 1024 + hh * 64 + c;
      v = (x[base] + x[base + 1024] + x[base + 2048]) * (1.0f / 3.0f);
    }
    xs[r][c] = v;
    wks[r][c] = Wk[(size_t)hh * 4096 + idx];
    wvs[r][c] = Wv[(size_t)hh * 4096 + idx];
  }
  __syncthreads();
  int o = t & 63, lg = t >> 6;
  float kbias = bk[hh * 64 + o], vbias = bv[hh * 64 + o];
  const size_t outb = (size_t)bh * NWP_ * 64;
  for (int ls = 0; ls < 16; ++ls) {
    int l = lg * 16 + ls;
    float ka = kbias, va = vbias;
#pragma unroll
    for (int i = 0; i < 64; ++i) {
      float xv = xs[l][i];
      ka = fmaf(xv, wks[o][i], ka);
      va = fmaf(xv, wvs[o][i], va);
    }
    KLP[outb + (size_t)(n0 + l) * 64 + o] = (bf16)ka;
    VLP[outb + (size_t)(n0 + l) * 64 + o] = (bf16)va;
  }
}

// ---------------- mask precompute: bit-packed (1 = masked) — R3-verified ----------------
__global__ __launch_bounds__(256) void maskprep(const float* __restrict__ mask,
                                                uint64_t* __restrict__ gm,
                                                uint64_t* __restrict__ wm) {
  int row = blockIdx.x * 4 + (threadIdx.x >> 6);  // b*L + l
  int lane = threadIdx.x & 63;
  if (row >= B_ * L_) return;
  int b = row / L_, l = row % L_;
  const float* mr = mask + (size_t)b * L_ * L_ + (size_t)l * L_;
  for (int w = 0; w < 32; ++w) {
    int m = w * 64 + lane;
    bool masked = (m >= L_) ? true : (mr[m] == 0.0f);
    uint64_t bal = __ballot(masked);
    if (lane == 0) gm[(size_t)row * 32 + w] = bal;
  }
  for (int w = 0; w < 11; ++w) {
    int n = w * 64 + lane;
    bool lmask = true;
    if (n < NW_) {
      float s = mr[3 * n] + mr[3 * n + 1] + mr[3 * n + 2];
      lmask = !(s >= 2.0f);
    }
    uint64_t bal = __ballot(lmask);
    if (lane == 0) wm[(size_t)row * 11 + w] = bal;
  }
}

// ---------------- global scores: MFMA QK^T two-pass -> normalized pg (R5-verified) ----------------
__global__ __launch_bounds__(256) void attn_gs(const bf16* __restrict__ Q,
    const bf16* __restrict__ K, const uint64_t* __restrict__ GM,
    float* __restrict__ OP) {
  __shared__ float sums[64];
  int lane = threadIdx.x & 63, wave = threadIdx.x >> 6;
  int lid = lane & 15, g = lane >> 4;
  int q0 = blockIdx.x * 16;
  int bh = blockIdx.y;
  int b = bh >> 3, h = bh & 7;
  const bf16* qb = Q + (size_t)b * L_ * 1024 + h * 64;
  const bf16* kb = K + (size_t)bh * LP_ * 64;
  const uint64_t* gmb = GM + (size_t)b * L_ * 32;

  bf16x8 aq0 = zf8(), aq1 = zf8();
  {
    int qr = q0 + lid;
    if (qr < L_) {
      aq0 = *reinterpret_cast<const bf16x8*>(qb + (size_t)qr * 1024 + g * 8);
      aq1 = *reinterpret_cast<const bf16x8*>(qb + (size_t)qr * 1024 + 32 + g * 8);
    }
  }
  // pass A: row sums
  float rs[4] = {0.f, 0.f, 0.f, 0.f};
  for (int p = wave; p < 64; p += 4) {
#pragma unroll
    for (int tt = 0; tt < 2; ++tt) {
      int col = p * 32 + tt * 16 + lid;
      bf16x8 bk0 = *reinterpret_cast<const bf16x8*>(kb + (size_t)col * 64 + g * 8);
      bf16x8 bk1 = *reinterpret_cast<const bf16x8*>(kb + (size_t)col * 64 + 32 + g * 8);
      f32x4 acc = {0.f, 0.f, 0.f, 0.f};
      acc = __builtin_amdgcn_mfma_f32_16x16x32_bf16(aq0, bk0, acc, 0, 0, 0);
      acc = __builtin_amdgcn_mfma_f32_16x16x32_bf16(aq1, bk1, acc, 0, 0, 0);
      int wi = col >> 6, bit = col & 63;
#pragma unroll
      for (int r = 0; r < 4; ++r) {
        int qr = q0 + g * 4 + r;
        uint64_t w = (qr < L_) ? gmb[(size_t)qr * 32 + wi] : ~0ull;
        rs[r] += ((w >> bit) & 1) ? 0.0f : __expf(acc[r] * SCALE_);
      }
    }
  }
#pragma unroll
  for (int off = 8; off >= 1; off >>= 1)
#pragma unroll
    for (int r = 0; r < 4; ++r) rs[r] += __shfl_xor(rs[r], off, 64);
  if (lid == 0) {
#pragma unroll
    for (int r = 0; r < 4; ++r) sums[wave * 16 + g * 4 + r] = rs[r];
  }
  __syncthreads();
  float invr[4];
#pragma unroll
  for (int r = 0; r < 4; ++r) {
    int row = g * 4 + r;
    float s = sums[row] + sums[16 + row] + sums[32 + row] + sums[48 + row];
    invr[r] = (s > 0.f) ? 1.0f / s : 0.0f;
  }
  // pass B: recompute, write normalized pg
  const size_t pgbase = (size_t)bh * L_ * L_;
  for (int p = wave; p < 64; p += 4) {
#pragma unroll
    for (int tt = 0; tt < 2; ++tt) {
      int col = p * 32 + tt * 16 + lid;
      bf16x8 bk0 = *reinterpret_cast<const bf16x8*>(kb + (size_t)col * 64 + g * 8);
      bf16x8 bk1 = *reinterpret_cast<const bf16x8*>(kb + (size_t)col * 64 + 32 + g * 8);
      f32x4 acc = {0.f, 0.f, 0.f, 0.f};
      acc = __builtin_amdgcn_mfma_f32_16x16x32_bf16(aq0, bk0, acc, 0, 0, 0);
      acc = __builtin_amdgcn_mfma_f32_16x16x32_bf16(aq1, bk1, acc, 0, 0, 0);
      int wi = col >> 6, bit = col & 63;
#pragma unroll
      for (int r = 0; r < 4; ++r) {
        int qr = q0 + g * 4 + r;
        uint64_t w = (qr < L_) ? gmb[(size_t)qr * 32 + wi] : ~0ull;
        float pv = ((w >> bit) & 1) ? 0.0f : __expf(acc[r] * SCALE_);
        if (qr < L_ && col < L_) OP[pgbase + (size_t)qr * L_ + col] = pv * invr[r];
      }
    }
  }
}

// ---------------- local scores: MFMA QK^T two-pass -> normalized pl (R5-verified) ----------------
__global__ __launch_bounds__(256) void attn_ls(const bf16* __restrict__ Q,
    const bf16* __restrict__ K, const uint64_t* __restrict__ WM,
    float* __restrict__ OP) {
  __shared__ float sums[64];
  int lane = threadIdx.x & 63, wave = threadIdx.x >> 6;
  int lid = lane & 15, g = lane >> 4;
  int q0 = blockIdx.x * 16;
  int bh = blockIdx.y;
  int b = bh >> 3, h = bh & 7;
  const bf16* qb = Q + (size_t)b * L_ * 1024 + (8 + h) * 64;
  const bf16* kb = K + (size_t)bh * NWP_ * 64;
  const uint64_t* wmb = WM + (size_t)b * L_ * 11;

  bf16x8 aq0 = zf8(), aq1 = zf8();
  {
    int qr = q0 + lid;
    if (qr < L_) {
      aq0 = *reinterpret_cast<const bf16x8*>(qb + (size_t)qr * 1024 + g * 8);
      aq1 = *reinterpret_cast<const bf16x8*>(qb + (size_t)qr * 1024 + 32 + g * 8);
    }
  }
  float rs[4] = {0.f, 0.f, 0.f, 0.f};
  for (int p = wave; p < 22; p += 4) {
#pragma unroll
    for (int tt = 0; tt < 2; ++tt) {
      int col = p * 32 + tt * 16 + lid;
      bf16x8 bk0 = *reinterpret_cast<const bf16x8*>(kb + (size_t)col * 64 + g * 8);
      bf16x8 bk1 = *reinterpret_cast<const bf16x8*>(kb + (size_t)col * 64 + 32 + g * 8);
      f32x4 acc = {0.f, 0.f, 0.f, 0.f};
      acc = __builtin_amdgcn_mfma_f32_16x16x32_bf16(aq0, bk0, acc, 0, 0, 0);
      acc = __builtin_amdgcn_mfma_f32_16x16x32_bf16(aq1, bk1, acc, 0, 0, 0);
      int wi = col >> 6, bit = col & 63;
#pragma unroll
      for (int r = 0; r < 4; ++r) {
        int qr = q0 + g * 4 + r;
        uint64_t w = (qr < L_) ? wmb[(size_t)qr * 11 + wi] : ~0ull;
        rs[r] += ((w >> bit) & 1) ? 0.0f : __expf(acc[r] * SCALE_);
      }
    }
  }
#pragma unroll
  for (int off = 8; off >= 1; off >>= 1)
#pragma unroll
    for (int r = 0; r < 4; ++r) rs[r] += __shfl_xor(rs[r], off, 64);
  if (lid == 0) {
#pragma unroll
    for (int r = 0; r < 4; ++r) sums[wave * 16 + g * 4 + r] = rs[r];
  }
  __syncthreads();
  float invr[4];
#pragma unroll
  for (int r = 0; r < 4; ++r) {
    int row = g * 4 + r;
    float s = sums[row] + sums[16 + row] + sums[32 + row] + sums[48 + row];
    invr[r] = (s > 0.f) ? 1.0f / s : 0.0f;
  }
  const size_t plbase = (size_t)bh * L_ * NW_;
  for (int p = wave; p < 22; p += 4) {
#pragma unroll
    for (int tt = 0; tt < 2; ++tt) {
      int col = p * 32 + tt * 16 + lid;
      bf16x8 bk0 = *reinterpret_cast<const bf16x8*>(kb + (size_t)col * 64 + g * 8);
      bf16x8 bk1 = *reinterpret_cast<const bf16x8*>(kb + (size_t)col * 64 + 32 + g * 8);
      f32x4 acc = {0.f, 0.f, 0.f, 0.f};
      acc = __builtin_amdgcn_mfma_f32_16x16x32_bf16(aq0, bk0, acc, 0, 0, 0);
      acc = __builtin_amdgcn_mfma_f32_16x16x32_bf16(aq1, bk1, acc, 0, 0, 0);
      int wi = col >> 6, bit = col & 63;
#pragma unroll
      for (int r = 0; r < 4; ++r) {
        int qr = q0 + g * 4 + r;
        uint64_t w = (qr < L_) ? wmb[(size_t)qr * 11 + wi] : ~0ull;
        float pv = ((w >> bit) & 1) ? 0.0f : __expf(acc[r] * SCALE_);
        if (qr < L_ && col < NW_) OP[plbase + (size_t)qr * NW_ + col] = pv * invr[r];
      }
    }
  }
}

// ---------------- PV via MFMA: O = P @ V (R6-verified) ----------------
template <int MT, int ML, int VROWS>
__global__ __launch_bounds__(256) void pv_mfma(const float* __restrict__ P,
    const bf16* __restrict__ V, float* __restrict__ OV, int hbase) {
  __shared__ bf16 vt[64][40];            // vt[d][mloc], 80B row stride (16B-aligned)
  int t = threadIdx.x;
  int lane = t & 63, wave = t >> 6;
  int lid = lane & 15, g = lane >> 4;
  int bh = blockIdx.y, b = bh >> 3, h = bh & 7;
  int q0w = blockIdx.x * 64 + wave * 16;
  const float* Pb = P + (size_t)bh * L_ * ML;
  const bf16* Vb = V + (size_t)bh * VROWS * 64;
  int arow = q0w + lid; if (arow >= L_) arow = L_ - 1;   // clamp; results discarded
  const float* prow = Pb + (size_t)arow * ML;
  int sd = t & 63, mgrp = t >> 6;        // staging map: d = sd, m-group = mgrp
  f32x4 vacc[4];
  f32x4 z4 = {0.f, 0.f, 0.f, 0.f};
#pragma unroll
  for (int dg = 0; dg < 4; ++dg) vacc[dg] = z4;

  for (int mt = 0; mt < MT; ++mt) {
    int m0 = mt * 32;
    bf16 stmp[8];
#pragma unroll
    for (int e = 0; e < 8; ++e)
      stmp[e] = Vb[(size_t)(m0 + mgrp * 8 + e) * 64 + sd];
    *reinterpret_cast<bf16x8*>(&vt[sd][mgrp * 8]) = *reinterpret_cast<const bf16x8*>(stmp);
    __syncthreads();
    bf16x8 pa;
    if (m0 + 32 <= ML) {
      const float* pp = prow + m0 + g * 8;
#pragma unroll
      for (int e = 0; e < 8; ++e) pa[e] = (bf16)pp[e];
    } else {
#pragma unroll
      for (int e = 0; e < 8; ++e) {
        int m = m0 + g * 8 + e;
        pa[e] = (m < ML) ? (bf16)prow[m] : (bf16)0.0f;
      }
    }
#pragma unroll
    for (int dg = 0; dg < 4; ++dg) {
      bf16x8 bv8 = *reinterpret_cast<const bf16x8*>(&vt[dg * 16 + lid][g * 8]);
      vacc[dg] = __builtin_amdgcn_mfma_f32_16x16x32_bf16(pa, bv8, vacc[dg], 0, 0, 0);
    }
    __syncthreads();
  }
  float* ob = OV + (((size_t)b * 16 + hbase + h) * L_) * 64;
#pragma unroll
  for (int dg = 0; dg < 4; ++dg)
#pragma unroll
    for (int r = 0; r < 4; ++r) {
      int qr = q0w + g * 4 + r;
      if (qr < L_) ob[(size_t)qr * 64 + dg * 16 + lid] = vacc[dg][r];
    }
}

extern "C" void kernel_launch(void* const* d_in, const int* in_sizes, int n_in,
                              void* d_out, int out_size, void* d_ws, size_t ws_size,
                              hipStream_t stream) {
  (void)in_sizes; (void)n_in; (void)out_size; (void)ws_size;
  const float* x    = (const float*)d_in[0];
  const float* mask = (const float*)d_in[1];
  const float* Wq   = (const float*)d_in[2];
  const float* bq   = (const float*)d_in[3];
  const float* Wk   = (const float*)d_in[4];
  const float* bk   = (const float*)d_in[5];
  const float* Wv   = (const float*)d_in[6];
  const float* bv   = (const float*)d_in[7];

  char* ws = (char*)d_ws;
  bf16* qbb     = (bf16*)(ws + 0);            // 8,380,416
  bf16* kgb     = (bf16*)(ws + 8380416);      // 4,194,304
  bf16* vgb     = (bf16*)(ws + 12574720);     // 4,194,304 (row-major V)
  bf16* klb     = (bf16*)(ws + 16769024);     // 1,441,792
  bf16* vlb     = (bf16*)(ws + 18210816);     // 1,441,792
  uint64_t* gm  = (uint64_t*)(ws + 19652608); // 1,047,552
  uint64_t* wm  = (uint64_t*)(ws + 20700160); // 360,096
  bf16* xbb     = (bf16*)(ws + 21060256);     // 8,380,416 (x in bf16)
  bf16* wqb     = (bf16*)(ws + 29440672);     // 2,097,152 (Wq in bf16)

  float* out    = (float*)d_out;
  float* o_vall = out;                 // (2,16,2046,64)
  float* o_pg   = out + 4190208;       // (2,8,2046,2046)
  float* o_pl   = out + 71168064;      // (2,8,2046,682)

  cast4<<<4092, 256, 0, stream>>>(x, xbb, 4190208);
  cast4<<<1024, 256, 0, stream>>>(Wq, wqb, 1048576);
  qgemm_m<<<dim3(64, 16), 256, 0, stream>>>(xbb, wqb, bq, qbb);
  proj_g32<<<dim3(32, 16), 256, 0, stream>>>(x, Wk, bk, Wv, bv, kgb, vgb);
  proj_l32<<<dim3(11, 16), 256, 0, stream>>>(x, Wk, bk, Wv, bv, klb, vlb);
  maskprep<<<1023, 256, 0, stream>>>(mask, gm, wm);

  attn_gs<<<dim3(128, 16), 256, 0, stream>>>(qbb, kgb, gm, o_pg);
  attn_ls<<<dim3(128, 16), 256, 0, stream>>>(qbb, klb, wm, o_pl);

  pv_mfma<64, L_, LP_><<<dim3(32, 16), 256, 0, stream>>>(o_pg, vgb, o_vall, 0);
  pv_mfma<22, NW_, NWP_><<<dim3(32, 16), 256, 0, stream>>>(o_pl, vlb, o_vall, 8);
}

// Round 8
// 513.725 us; speedup vs baseline: 14.5959x; 1.1913x over previous
//
#include <hip/hip_runtime.h>
#include <hip/hip_bf16.h>
#include <stdint.h>

typedef __bf16 bf16;
typedef bf16 bf16x8 __attribute__((ext_vector_type(8)));
typedef float f32x4 __attribute__((ext_vector_type(4)));

#define B_ 2
#define L_ 2046
#define H_ 16
#define NW_ 682
#define LP_ 2048
#define NWP_ 704
#define M_ (B_*L_)
#define SCALE_ 0.125f

__device__ inline bf16x8 zf8() {
  bf16x8 v;
#pragma unroll
  for (int e = 0; e < 8; ++e) v[e] = (bf16)0.0f;
  return v;
}

__device__ inline uint32_t pkbf(float a, float b) {
  uint16_t ua = __builtin_bit_cast(uint16_t, (bf16)a);
  uint16_t ub = __builtin_bit_cast(uint16_t, (bf16)b);
  return (uint32_t)ua | ((uint32_t)ub << 16);
}
__device__ inline float upk_lo(uint32_t u) { return __builtin_bit_cast(float, u << 16); }
__device__ inline float upk_hi(uint32_t u) { return __builtin_bit_cast(float, u & 0xffff0000u); }

// ---------------- cast f32 -> bf16 (vectorized x4) ----------------
__global__ __launch_bounds__(256) void cast4(const float* __restrict__ in,
                                             bf16* __restrict__ out, int n) {
  int i = (blockIdx.x * 256 + threadIdx.x) * 4;
  if (i + 3 < n) {
    float4 v = *reinterpret_cast<const float4*>(in + i);
    bf16 tmp[4];
    tmp[0] = (bf16)v.x; tmp[1] = (bf16)v.y; tmp[2] = (bf16)v.z; tmp[3] = (bf16)v.w;
    *reinterpret_cast<uint64_t*>(out + i) = *reinterpret_cast<const uint64_t*>(tmp);
  } else {
    for (; i < n; ++i) out[i] = (bf16)in[i];
  }
}

// ---------------- q = x @ Wq^T + bq via MFMA (R7-verified) ----------------
__global__ __launch_bounds__(256) void qgemm_m(const bf16* __restrict__ X,
                                               const bf16* __restrict__ W,
                                               const float* __restrict__ bq,
                                               bf16* __restrict__ Q) {
  int lane = threadIdx.x & 63, wave = threadIdx.x >> 6;
  int lid = lane & 15, g = lane >> 4;
  int m0 = blockIdx.x * 64;
  int n0 = blockIdx.y * 64 + wave * 16;
  f32x4 z4 = {0.f, 0.f, 0.f, 0.f};
  f32x4 acc[4];
#pragma unroll
  for (int rt = 0; rt < 4; ++rt) acc[rt] = z4;
  const bf16* wrow = W + (size_t)(n0 + lid) * 1024;
  for (int k = 0; k < 1024; k += 32) {
    bf16x8 bf0 = *reinterpret_cast<const bf16x8*>(wrow + k + g * 8);
#pragma unroll
    for (int rt = 0; rt < 4; ++rt) {
      int row = m0 + rt * 16 + lid;
      bf16x8 af = zf8();
      if (row < M_) af = *reinterpret_cast<const bf16x8*>(X + (size_t)row * 1024 + k + g * 8);
      acc[rt] = __builtin_amdgcn_mfma_f32_16x16x32_bf16(af, bf0, acc[rt], 0, 0, 0);
    }
  }
  int col = n0 + lid;
  float bias = bq[col];
#pragma unroll
  for (int rt = 0; rt < 4; ++rt)
#pragma unroll
    for (int r = 0; r < 4; ++r) {
      int row = m0 + rt * 16 + g * 4 + r;
      if (row < M_) Q[(size_t)row * 1024 + col] = (bf16)(acc[rt][r] + bias);
    }
}

// ---------------- global-head K/V projections (f32 math, bf16 row-major out) ----------------
__global__ __launch_bounds__(256) void proj_g32(const float* __restrict__ x,
    const float* __restrict__ Wk, const float* __restrict__ bk,
    const float* __restrict__ Wv, const float* __restrict__ bv,
    bf16* __restrict__ KGP, bf16* __restrict__ VGP) {
  __shared__ float xs[64][64];
  __shared__ float wks[64][65];
  __shared__ float wvs[64][65];
  int t = threadIdx.x;
  int lb = blockIdx.x, bh = blockIdx.y;
  int b = bh >> 3, h = bh & 7;
  int l0 = lb * 64;
  for (int idx = t; idx < 4096; idx += 256) {
    int r = idx >> 6, c = idx & 63;
    int l = l0 + r;
    xs[r][c] = (l < L_) ? x[((size_t)b * L_ + l) * 1024 + h * 64 + c] : 0.0f;
    wks[r][c] = Wk[(size_t)h * 4096 + idx];
    wvs[r][c] = Wv[(size_t)h * 4096 + idx];
  }
  __syncthreads();
  int o = t & 63, lg = t >> 6;
  float kbias = bk[h * 64 + o], vbias = bv[h * 64 + o];
  const size_t outb = (size_t)bh * LP_ * 64;
  for (int ls = 0; ls < 16; ++ls) {
    int l = lg * 16 + ls;
    float ka = kbias, va = vbias;
#pragma unroll
    for (int i = 0; i < 64; ++i) {
      float xv = xs[l][i];
      ka = fmaf(xv, wks[o][i], ka);
      va = fmaf(xv, wvs[o][i], va);
    }
    KGP[outb + (size_t)(l0 + l) * 64 + o] = (bf16)ka;
    VGP[outb + (size_t)(l0 + l) * 64 + o] = (bf16)va;
  }
}

// ---------------- local-head window-avg + K/V projections (f32 math, bf16 out) ----------------
__global__ __launch_bounds__(256) void proj_l32(const float* __restrict__ x,
    const float* __restrict__ Wk, const float* __restrict__ bk,
    const float* __restrict__ Wv, const float* __restrict__ bv,
    bf16* __restrict__ KLP, bf16* __restrict__ VLP) {
  __shared__ float xs[64][64];
  __shared__ float wks[64][65];
  __shared__ float wvs[64][65];
  int t = threadIdx.x;
  int nb = blockIdx.x, bh = blockIdx.y;
  int b = bh >> 3, h = bh & 7;
  int n0 = nb * 64;
  int hh = 8 + h;
  for (int idx = t; idx < 4096; idx += 256) {
    int r = idx >> 6, c = idx & 63;
    int n = n0 + r;
    float v = 0.0f;
    if (n < NW_) {
      size_t base = ((size_t)b * L_ + 3 * n) * 1024 + hh * 64 + c;
      v = (x[base] + x[base + 1024] + x[base + 2048]) * (1.0f / 3.0f);
    }
    xs[r][c] = v;
    wks[r][c] = Wk[(size_t)hh * 4096 + idx];
    wvs[r][c] = Wv[(size_t)hh * 4096 + idx];
  }
  __syncthreads();
  int o = t & 63, lg = t >> 6;
  float kbias = bk[hh * 64 + o], vbias = bv[hh * 64 + o];
  const size_t outb = (size_t)bh * NWP_ * 64;
  for (int ls = 0; ls < 16; ++ls) {
    int l = lg * 16 + ls;
    float ka = kbias, va = vbias;
#pragma unroll
    for (int i = 0; i < 64; ++i) {
      float xv = xs[l][i];
      ka = fmaf(xv, wks[o][i], ka);
      va = fmaf(xv, wvs[o][i], va);
    }
    KLP[outb + (size_t)(n0 + l) * 64 + o] = (bf16)ka;
    VLP[outb + (size_t)(n0 + l) * 64 + o] = (bf16)va;
  }
}

// ---------------- mask precompute: bit-packed (1 = masked) — R3-verified ----------------
__global__ __launch_bounds__(256) void maskprep(const float* __restrict__ mask,
                                                uint64_t* __restrict__ gm,
                                                uint64_t* __restrict__ wm) {
  int row = blockIdx.x * 4 + (threadIdx.x >> 6);  // b*L + l
  int lane = threadIdx.x & 63;
  if (row >= B_ * L_) return;
  int b = row / L_, l = row % L_;
  const float* mr = mask + (size_t)b * L_ * L_ + (size_t)l * L_;
  for (int w = 0; w < 32; ++w) {
    int m = w * 64 + lane;
    bool masked = (m >= L_) ? true : (mr[m] == 0.0f);
    uint64_t bal = __ballot(masked);
    if (lane == 0) gm[(size_t)row * 32 + w] = bal;
  }
  for (int w = 0; w < 11; ++w) {
    int n = w * 64 + lane;
    bool lmask = true;
    if (n < NW_) {
      float s = mr[3 * n] + mr[3 * n + 1] + mr[3 * n + 2];
      lmask = !(s >= 2.0f);
    }
    uint64_t bal = __ballot(lmask);
    if (lane == 0) wm[(size_t)row * 11 + w] = bal;
  }
}

// ---------------- global scores: SINGLE-PASS MFMA QK^T, bf16 P held in registers ----------------
__global__ __launch_bounds__(256) void attn_gs(const bf16* __restrict__ Q,
    const bf16* __restrict__ K, const uint64_t* __restrict__ GM,
    float* __restrict__ OP) {
  __shared__ float sums[64];
  int lane = threadIdx.x & 63, wave = threadIdx.x >> 6;
  int lid = lane & 15, g = lane >> 4;
  int q0 = blockIdx.x * 16;
  int bh = blockIdx.y;
  int b = bh >> 3, h = bh & 7;
  const bf16* qb = Q + (size_t)b * L_ * 1024 + h * 64;
  const bf16* kb = K + (size_t)bh * LP_ * 64;
  const uint64_t* gmb = GM + (size_t)b * L_ * 32;

  bf16x8 aq0 = zf8(), aq1 = zf8();
  {
    int qr = q0 + lid;
    if (qr < L_) {
      aq0 = *reinterpret_cast<const bf16x8*>(qb + (size_t)qr * 1024 + g * 8);
      aq1 = *reinterpret_cast<const bf16x8*>(qb + (size_t)qr * 1024 + 32 + g * 8);
    }
  }
  uint32_t preg[64];            // [it(16)][r(4)] packed (tt0, tt1) bf16 pair
  float rs[4] = {0.f, 0.f, 0.f, 0.f};
#pragma unroll
  for (int it = 0; it < 16; ++it) {
    int p = it * 4 + wave;
    int c0 = p * 32;
    int col0 = c0 + lid, col1 = c0 + 16 + lid;
    bf16x8 bka0 = *reinterpret_cast<const bf16x8*>(kb + (size_t)col0 * 64 + g * 8);
    bf16x8 bka1 = *reinterpret_cast<const bf16x8*>(kb + (size_t)col0 * 64 + 32 + g * 8);
    bf16x8 bkb0 = *reinterpret_cast<const bf16x8*>(kb + (size_t)col1 * 64 + g * 8);
    bf16x8 bkb1 = *reinterpret_cast<const bf16x8*>(kb + (size_t)col1 * 64 + 32 + g * 8);
    f32x4 acc0 = {0.f, 0.f, 0.f, 0.f}, acc1 = {0.f, 0.f, 0.f, 0.f};
    acc0 = __builtin_amdgcn_mfma_f32_16x16x32_bf16(aq0, bka0, acc0, 0, 0, 0);
    acc0 = __builtin_amdgcn_mfma_f32_16x16x32_bf16(aq1, bka1, acc0, 0, 0, 0);
    acc1 = __builtin_amdgcn_mfma_f32_16x16x32_bf16(aq0, bkb0, acc1, 0, 0, 0);
    acc1 = __builtin_amdgcn_mfma_f32_16x16x32_bf16(aq1, bkb1, acc1, 0, 0, 0);
    int wi = c0 >> 6;           // both tt halves share the same 64-col mask word
    int bit0 = c0 & 32;
#pragma unroll
    for (int r = 0; r < 4; ++r) {
      int qr = q0 + g * 4 + r;
      uint64_t w = (qr < L_) ? gmb[(size_t)qr * 32 + wi] : ~0ull;
      float pv0 = ((w >> (bit0 + lid)) & 1) ? 0.0f : __expf(acc0[r] * SCALE_);
      float pv1 = ((w >> (bit0 + 16 + lid)) & 1) ? 0.0f : __expf(acc1[r] * SCALE_);
      rs[r] += pv0 + pv1;
      preg[it * 4 + r] = pkbf(pv0, pv1);
    }
  }
#pragma unroll
  for (int off = 8; off >= 1; off >>= 1)
#pragma unroll
    for (int r = 0; r < 4; ++r) rs[r] += __shfl_xor(rs[r], off, 64);
  if (lid == 0) {
#pragma unroll
    for (int r = 0; r < 4; ++r) sums[wave * 16 + g * 4 + r] = rs[r];
  }
  __syncthreads();
  float invr[4];
#pragma unroll
  for (int r = 0; r < 4; ++r) {
    int row = g * 4 + r;
    float s = sums[row] + sums[16 + row] + sums[32 + row] + sums[48 + row];
    invr[r] = (s > 0.f) ? 1.0f / s : 0.0f;
  }
  // write normalized pg from registers
  const size_t pgbase = (size_t)bh * L_ * L_;
#pragma unroll
  for (int it = 0; it < 16; ++it) {
    int c0 = (it * 4 + wave) * 32;
    int col0 = c0 + lid, col1 = c0 + 16 + lid;
#pragma unroll
    for (int r = 0; r < 4; ++r) {
      int qr = q0 + g * 4 + r;
      if (qr < L_) {
        uint32_t u = preg[it * 4 + r];
        const size_t rowb = pgbase + (size_t)qr * L_;
        if (col0 < L_) OP[rowb + col0] = upk_lo(u) * invr[r];
        if (col1 < L_) OP[rowb + col1] = upk_hi(u) * invr[r];
      }
    }
  }
}

// ---------------- local scores: SINGLE-PASS, bf16 P in registers ----------------
__global__ __launch_bounds__(256) void attn_ls(const bf16* __restrict__ Q,
    const bf16* __restrict__ K, const uint64_t* __restrict__ WM,
    float* __restrict__ OP) {
  __shared__ float sums[64];
  int lane = threadIdx.x & 63, wave = threadIdx.x >> 6;
  int lid = lane & 15, g = lane >> 4;
  int q0 = blockIdx.x * 16;
  int bh = blockIdx.y;
  int b = bh >> 3, h = bh & 7;
  const bf16* qb = Q + (size_t)b * L_ * 1024 + (8 + h) * 64;
  const bf16* kb = K + (size_t)bh * NWP_ * 64;
  const uint64_t* wmb = WM + (size_t)b * L_ * 11;

  bf16x8 aq0 = zf8(), aq1 = zf8();
  {
    int qr = q0 + lid;
    if (qr < L_) {
      aq0 = *reinterpret_cast<const bf16x8*>(qb + (size_t)qr * 1024 + g * 8);
      aq1 = *reinterpret_cast<const bf16x8*>(qb + (size_t)qr * 1024 + 32 + g * 8);
    }
  }
  uint32_t preg[24];            // [it(6)][r(4)]
  float rs[4] = {0.f, 0.f, 0.f, 0.f};
#pragma unroll
  for (int it = 0; it < 6; ++it) {
    int p = it * 4 + wave;
    bool act = (p < 22);
    if (act) {
      int c0 = p * 32;
      int col0 = c0 + lid, col1 = c0 + 16 + lid;
      bf16x8 bka0 = *reinterpret_cast<const bf16x8*>(kb + (size_t)col0 * 64 + g * 8);
      bf16x8 bka1 = *reinterpret_cast<const bf16x8*>(kb + (size_t)col0 * 64 + 32 + g * 8);
      bf16x8 bkb0 = *reinterpret_cast<const bf16x8*>(kb + (size_t)col1 * 64 + g * 8);
      bf16x8 bkb1 = *reinterpret_cast<const bf16x8*>(kb + (size_t)col1 * 64 + 32 + g * 8);
      f32x4 acc0 = {0.f, 0.f, 0.f, 0.f}, acc1 = {0.f, 0.f, 0.f, 0.f};
      acc0 = __builtin_amdgcn_mfma_f32_16x16x32_bf16(aq0, bka0, acc0, 0, 0, 0);
      acc0 = __builtin_amdgcn_mfma_f32_16x16x32_bf16(aq1, bka1, acc0, 0, 0, 0);
      acc1 = __builtin_amdgcn_mfma_f32_16x16x32_bf16(aq0, bkb0, acc1, 0, 0, 0);
      acc1 = __builtin_amdgcn_mfma_f32_16x16x32_bf16(aq1, bkb1, acc1, 0, 0, 0);
      int wi = c0 >> 6;
      int bit0 = c0 & 32;
#pragma unroll
      for (int r = 0; r < 4; ++r) {
        int qr = q0 + g * 4 + r;
        uint64_t w = (qr < L_) ? wmb[(size_t)qr * 11 + wi] : ~0ull;
        float pv0 = ((w >> (bit0 + lid)) & 1) ? 0.0f : __expf(acc0[r] * SCALE_);
        float pv1 = ((w >> (bit0 + 16 + lid)) & 1) ? 0.0f : __expf(acc1[r] * SCALE_);
        rs[r] += pv0 + pv1;
        preg[it * 4 + r] = pkbf(pv0, pv1);
      }
    }
  }
#pragma unroll
  for (int off = 8; off >= 1; off >>= 1)
#pragma unroll
    for (int r = 0; r < 4; ++r) rs[r] += __shfl_xor(rs[r], off, 64);
  if (lid == 0) {
#pragma unroll
    for (int r = 0; r < 4; ++r) sums[wave * 16 + g * 4 + r] = rs[r];
  }
  __syncthreads();
  float invr[4];
#pragma unroll
  for (int r = 0; r < 4; ++r) {
    int row = g * 4 + r;
    float s = sums[row] + sums[16 + row] + sums[32 + row] + sums[48 + row];
    invr[r] = (s > 0.f) ? 1.0f / s : 0.0f;
  }
  const size_t plbase = (size_t)bh * L_ * NW_;
#pragma unroll
  for (int it = 0; it < 6; ++it) {
    int p = it * 4 + wave;
    if (p < 22) {
      int c0 = p * 32;
      int col0 = c0 + lid, col1 = c0 + 16 + lid;
#pragma unroll
      for (int r = 0; r < 4; ++r) {
        int qr = q0 + g * 4 + r;
        if (qr < L_) {
          uint32_t u = preg[it * 4 + r];
          const size_t rowb = plbase + (size_t)qr * NW_;
          if (col0 < NW_) OP[rowb + col0] = upk_lo(u) * invr[r];
          if (col1 < NW_) OP[rowb + col1] = upk_hi(u) * invr[r];
        }
      }
    }
  }
}

// ---------------- PV via MFMA: O = P @ V (R6-verified) ----------------
template <int MT, int ML, int VROWS>
__global__ __launch_bounds__(256) void pv_mfma(const float* __restrict__ P,
    const bf16* __restrict__ V, float* __restrict__ OV, int hbase) {
  __shared__ bf16 vt[64][40];            // vt[d][mloc], 80B row stride (16B-aligned)
  int t = threadIdx.x;
  int lane = t & 63, wave = t >> 6;
  int lid = lane & 15, g = lane >> 4;
  int bh = blockIdx.y, b = bh >> 3, h = bh & 7;
  int q0w = blockIdx.x * 64 + wave * 16;
  const float* Pb = P + (size_t)bh * L_ * ML;
  const bf16* Vb = V + (size_t)bh * VROWS * 64;
  int arow = q0w + lid; if (arow >= L_) arow = L_ - 1;   // clamp; results discarded
  const float* prow = Pb + (size_t)arow * ML;
  int sd = t & 63, mgrp = t >> 6;        // staging map: d = sd, m-group = mgrp
  f32x4 vacc[4];
  f32x4 z4 = {0.f, 0.f, 0.f, 0.f};
#pragma unroll
  for (int dg = 0; dg < 4; ++dg) vacc[dg] = z4;

  for (int mt = 0; mt < MT; ++mt) {
    int m0 = mt * 32;
    bf16 stmp[8];
#pragma unroll
    for (int e = 0; e < 8; ++e)
      stmp[e] = Vb[(size_t)(m0 + mgrp * 8 + e) * 64 + sd];
    *reinterpret_cast<bf16x8*>(&vt[sd][mgrp * 8]) = *reinterpret_cast<const bf16x8*>(stmp);
    __syncthreads();
    bf16x8 pa;
    if (m0 + 32 <= ML) {
      const float* pp = prow + m0 + g * 8;
#pragma unroll
      for (int e = 0; e < 8; ++e) pa[e] = (bf16)pp[e];
    } else {
#pragma unroll
      for (int e = 0; e < 8; ++e) {
        int m = m0 + g * 8 + e;
        pa[e] = (m < ML) ? (bf16)prow[m] : (bf16)0.0f;
      }
    }
#pragma unroll
    for (int dg = 0; dg < 4; ++dg) {
      bf16x8 bv8 = *reinterpret_cast<const bf16x8*>(&vt[dg * 16 + lid][g * 8]);
      vacc[dg] = __builtin_amdgcn_mfma_f32_16x16x32_bf16(pa, bv8, vacc[dg], 0, 0, 0);
    }
    __syncthreads();
  }
  float* ob = OV + (((size_t)b * 16 + hbase + h) * L_) * 64;
#pragma unroll
  for (int dg = 0; dg < 4; ++dg)
#pragma unroll
    for (int r = 0; r < 4; ++r) {
      int qr = q0w + g * 4 + r;
      if (qr < L_) ob[(size_t)qr * 64 + dg * 16 + lid] = vacc[dg][r];
    }
}

extern "C" void kernel_launch(void* const* d_in, const int* in_sizes, int n_in,
                              void* d_out, int out_size, void* d_ws, size_t ws_size,
                              hipStream_t stream) {
  (void)in_sizes; (void)n_in; (void)out_size; (void)ws_size;
  const float* x    = (const float*)d_in[0];
  const float* mask = (const float*)d_in[1];
  const float* Wq   = (const float*)d_in[2];
  const float* bq   = (const float*)d_in[3];
  const float* Wk   = (const float*)d_in[4];
  const float* bk   = (const float*)d_in[5];
  const float* Wv   = (const float*)d_in[6];
  const float* bv   = (const float*)d_in[7];

  char* ws = (char*)d_ws;
  bf16* qbb     = (bf16*)(ws + 0);            // 8,380,416
  bf16* kgb     = (bf16*)(ws + 8380416);      // 4,194,304
  bf16* vgb     = (bf16*)(ws + 12574720);     // 4,194,304 (row-major V)
  bf16* klb     = (bf16*)(ws + 16769024);     // 1,441,792
  bf16* vlb     = (bf16*)(ws + 18210816);     // 1,441,792
  uint64_t* gm  = (uint64_t*)(ws + 19652608); // 1,047,552
  uint64_t* wm  = (uint64_t*)(ws + 20700160); // 360,096
  bf16* xbb     = (bf16*)(ws + 21060256);     // 8,380,416 (x in bf16)
  bf16* wqb     = (bf16*)(ws + 29440672);     // 2,097,152 (Wq in bf16)

  float* out    = (float*)d_out;
  float* o_vall = out;                 // (2,16,2046,64)
  float* o_pg   = out + 4190208;       // (2,8,2046,2046)
  float* o_pl   = out + 71168064;      // (2,8,2046,682)

  cast4<<<4092, 256, 0, stream>>>(x, xbb, 4190208);
  cast4<<<1024, 256, 0, stream>>>(Wq, wqb, 1048576);
  qgemm_m<<<dim3(64, 16), 256, 0, stream>>>(xbb, wqb, bq, qbb);
  proj_g32<<<dim3(32, 16), 256, 0, stream>>>(x, Wk, bk, Wv, bv, kgb, vgb);
  proj_l32<<<dim3(11, 16), 256, 0, stream>>>(x, Wk, bk, Wv, bv, klb, vlb);
  maskprep<<<1023, 256, 0, stream>>>(mask, gm, wm);

  attn_gs<<<dim3(128, 16), 256, 0, stream>>>(qbb, kgb, gm, o_pg);
  attn_ls<<<dim3(128, 16), 256, 0, stream>>>(qbb, klb, wm, o_pl);

  pv_mfma<64, L_, LP_><<<dim3(32, 16), 256, 0, stream>>>(o_pg, vgb, o_vall, 0);
  pv_mfma<22, NW_, NWP_><<<dim3(32, 16), 256, 0, stream>>>(o_pl, vlb, o_vall, 8);
}

// Round 10
// 483.248 us; speedup vs baseline: 15.5164x; 1.0631x over previous
//
#include <hip/hip_runtime.h>
#include <hip/hip_bf16.h>
#include <stdint.h>

typedef __bf16 bf16;
typedef bf16 bf16x8 __attribute__((ext_vector_type(8)));
typedef float f32x4 __attribute__((ext_vector_type(4)));

#define B_ 2
#define L_ 2046
#define H_ 16
#define NW_ 682
#define LP_ 2048
#define NWP_ 704
#define M_ (B_*L_)
#define SCALE_ 0.125f

__device__ inline bf16x8 zf8() {
  bf16x8 v;
#pragma unroll
  for (int e = 0; e < 8; ++e) v[e] = (bf16)0.0f;
  return v;
}

__device__ inline uint32_t pkbf(float a, float b) {
  uint16_t ua = __builtin_bit_cast(uint16_t, (bf16)a);
  uint16_t ub = __builtin_bit_cast(uint16_t, (bf16)b);
  return (uint32_t)ua | ((uint32_t)ub << 16);
}
__device__ inline float upk_lo(uint32_t u) { return __builtin_bit_cast(float, u << 16); }
__device__ inline float upk_hi(uint32_t u) { return __builtin_bit_cast(float, u & 0xffff0000u); }

// ---------------- cast f32 -> bf16 (vectorized x4) ----------------
__global__ __launch_bounds__(256) void cast4(const float* __restrict__ in,
                                             bf16* __restrict__ out, int n) {
  int i = (blockIdx.x * 256 + threadIdx.x) * 4;
  if (i + 3 < n) {
    float4 v = *reinterpret_cast<const float4*>(in + i);
    bf16 tmp[4];
    tmp[0] = (bf16)v.x; tmp[1] = (bf16)v.y; tmp[2] = (bf16)v.z; tmp[3] = (bf16)v.w;
    *reinterpret_cast<uint64_t*>(out + i) = *reinterpret_cast<const uint64_t*>(tmp);
  } else {
    for (; i < n; ++i) out[i] = (bf16)in[i];
  }
}

// ---------------- q = x @ Wq^T + bq : LDS-tiled MFMA GEMM (64x128 tile, BK=32) ----------------
__global__ __launch_bounds__(256) void qgemm_t(const bf16* __restrict__ X,
                                               const bf16* __restrict__ W,
                                               const float* __restrict__ bq,
                                               bf16* __restrict__ Q) {
  __shared__ bf16 As[64 * 40];    // [row][k] rows padded to 40 bf16 (80B)
  __shared__ bf16 Bs[128 * 40];
  int t = threadIdx.x, lane = t & 63, w = t >> 6;
  int lid = lane & 15, g = lane >> 4;
  int m0 = blockIdx.x * 64, n0 = blockIdx.y * 128;
  int wm = (w >> 1) * 32, wn = (w & 1) * 64;
  f32x4 z4 = {0.f, 0.f, 0.f, 0.f};
  f32x4 acc[2][4];
#pragma unroll
  for (int mi = 0; mi < 2; ++mi)
#pragma unroll
    for (int ni = 0; ni < 4; ++ni) acc[mi][ni] = z4;
  int r1 = t >> 2, c1 = t & 3;    // staging: row = r1 (0..63), 8-elem chunk c1 (0..3)
  for (int k0 = 0; k0 < 1024; k0 += 32) {
    int ga = m0 + r1; if (ga >= M_) ga = M_ - 1;
    bf16x8 av = *reinterpret_cast<const bf16x8*>(X + (size_t)ga * 1024 + k0 + c1 * 8);
    bf16x8 bv1 = *reinterpret_cast<const bf16x8*>(W + (size_t)(n0 + r1) * 1024 + k0 + c1 * 8);
    bf16x8 bv2 = *reinterpret_cast<const bf16x8*>(W + (size_t)(n0 + 64 + r1) * 1024 + k0 + c1 * 8);
    __syncthreads();   // previous tile fully consumed
    *reinterpret_cast<bf16x8*>(As + r1 * 40 + c1 * 8) = av;
    *reinterpret_cast<bf16x8*>(Bs + r1 * 40 + c1 * 8) = bv1;
    *reinterpret_cast<bf16x8*>(Bs + (64 + r1) * 40 + c1 * 8) = bv2;
    __syncthreads();
    bf16x8 af[2], bfr[4];
#pragma unroll
    for (int mi = 0; mi < 2; ++mi)
      af[mi] = *reinterpret_cast<const bf16x8*>(As + (wm + mi * 16 + lid) * 40 + g * 8);
#pragma unroll
    for (int ni = 0; ni < 4; ++ni)
      bfr[ni] = *reinterpret_cast<const bf16x8*>(Bs + (wn + ni * 16 + lid) * 40 + g * 8);
#pragma unroll
    for (int mi = 0; mi < 2; ++mi)
#pragma unroll
      for (int ni = 0; ni < 4; ++ni)
        acc[mi][ni] = __builtin_amdgcn_mfma_f32_16x16x32_bf16(af[mi], bfr[ni], acc[mi][ni], 0, 0, 0);
  }
  float bias[4];
#pragma unroll
  for (int ni = 0; ni < 4; ++ni) bias[ni] = bq[n0 + wn + ni * 16 + lid];
#pragma unroll
  for (int mi = 0; mi < 2; ++mi)
#pragma unroll
    for (int r = 0; r < 4; ++r) {
      int row = m0 + wm + mi * 16 + g * 4 + r;
      if (row < M_) {
#pragma unroll
        for (int ni = 0; ni < 4; ++ni)
          Q[(size_t)row * 1024 + n0 + wn + ni * 16 + lid] = (bf16)(acc[mi][ni][r] + bias[ni]);
      }
    }
}

// ---------------- global-head K/V projections (f32 math, bf16 row-major out) ----------------
__global__ __launch_bounds__(256) void proj_g32(const float* __restrict__ x,
    const float* __restrict__ Wk, const float* __restrict__ bk,
    const float* __restrict__ Wv, const float* __restrict__ bv,
    bf16* __restrict__ KGP, bf16* __restrict__ VGP) {
  __shared__ float xs[64][64];
  __shared__ float wks[64][65];
  __shared__ float wvs[64][65];
  int t = threadIdx.x;
  int lb = blockIdx.x, bh = blockIdx.y;
  int b = bh >> 3, h = bh & 7;
  int l0 = lb * 64;
  for (int idx = t; idx < 4096; idx += 256) {
    int r = idx >> 6, c = idx & 63;
    int l = l0 + r;
    xs[r][c] = (l < L_) ? x[((size_t)b * L_ + l) * 1024 + h * 64 + c] : 0.0f;
    wks[r][c] = Wk[(size_t)h * 4096 + idx];
    wvs[r][c] = Wv[(size_t)h * 4096 + idx];
  }
  __syncthreads();
  int o = t & 63, lg = t >> 6;
  float kbias = bk[h * 64 + o], vbias = bv[h * 64 + o];
  const size_t outb = (size_t)bh * LP_ * 64;
  for (int ls = 0; ls < 16; ++ls) {
    int l = lg * 16 + ls;
    float ka = kbias, va = vbias;
#pragma unroll
    for (int i = 0; i < 64; ++i) {
      float xv = xs[l][i];
      ka = fmaf(xv, wks[o][i], ka);
      va = fmaf(xv, wvs[o][i], va);
    }
    KGP[outb + (size_t)(l0 + l) * 64 + o] = (bf16)ka;
    VGP[outb + (size_t)(l0 + l) * 64 + o] = (bf16)va;
  }
}

// ---------------- local-head window-avg + K/V projections (f32 math, bf16 out) ----------------
__global__ __launch_bounds__(256) void proj_l32(const float* __restrict__ x,
    const float* __restrict__ Wk, const float* __restrict__ bk,
    const float* __restrict__ Wv, const float* __restrict__ bv,
    bf16* __restrict__ KLP, bf16* __restrict__ VLP) {
  __shared__ float xs[64][64];
  __shared__ float wks[64][65];
  __shared__ float wvs[64][65];
  int t = threadIdx.x;
  int nb = blockIdx.x, bh = blockIdx.y;
  int b = bh >> 3, h = bh & 7;
  int n0 = nb * 64;
  int hh = 8 + h;
  for (int idx = t; idx < 4096; idx += 256) {
    int r = idx >> 6, c = idx & 63;
    int n = n0 + r;
    float v = 0.0f;
    if (n < NW_) {
      size_t base = ((size_t)b * L_ + 3 * n) * 1024 + hh * 64 + c;
      v = (x[base] + x[base + 1024] + x[base + 2048]) * (1.0f / 3.0f);
    }
    xs[r][c] = v;
    wks[r][c] = Wk[(size_t)hh * 4096 + idx];
    wvs[r][c] = Wv[(size_t)hh * 4096 + idx];
  }
  __syncthreads();
  int o = t & 63, lg = t >> 6;
  float kbias = bk[hh * 64 + o], vbias = bv[hh * 64 + o];
  const size_t outb = (size_t)bh * NWP_ * 64;
  for (int ls = 0; ls < 16; ++ls) {
    int l = lg * 16 + ls;
    float ka = kbias, va = vbias;
#pragma unroll
    for (int i = 0; i < 64; ++i) {
      float xv = xs[l][i];
      ka = fmaf(xv, wks[o][i], ka);
      va = fmaf(xv, wvs[o][i], va);
    }
    KLP[outb + (size_t)(n0 + l) * 64 + o] = (bf16)ka;
    VLP[outb + (size_t)(n0 + l) * 64 + o] = (bf16)va;
  }
}

// ---------------- mask precompute: bit-packed (1 = masked) — R3-verified ----------------
__global__ __launch_bounds__(256) void maskprep(const float* __restrict__ mask,
                                                uint64_t* __restrict__ gm,
                                                uint64_t* __restrict__ wm) {
  int row = blockIdx.x * 4 + (threadIdx.x >> 6);  // b*L + l
  int lane = threadIdx.x & 63;
  if (row >= B_ * L_) return;
  int b = row / L_, l = row % L_;
  const float* mr = mask + (size_t)b * L_ * L_ + (size_t)l * L_;
  for (int w = 0; w < 32; ++w) {
    int m = w * 64 + lane;
    bool masked = (m >= L_) ? true : (mr[m] == 0.0f);
    uint64_t bal = __ballot(masked);
    if (lane == 0) gm[(size_t)row * 32 + w] = bal;
  }
  for (int w = 0; w < 11; ++w) {
    int n = w * 64 + lane;
    bool lmask = true;
    if (n < NW_) {
      float s = mr[3 * n] + mr[3 * n + 1] + mr[3 * n + 2];
      lmask = !(s >= 2.0f);
    }
    uint64_t bal = __ballot(lmask);
    if (lane == 0) wm[(size_t)row * 11 + w] = bal;
  }
}

// ---------------- global scores: single-pass MFMA QK^T, coalesced LDS-bounce epilogue ----------------
__global__ __launch_bounds__(256) void attn_gs(const bf16* __restrict__ Q,
    const bf16* __restrict__ K, const uint64_t* __restrict__ GM,
    float* __restrict__ OP) {
  __shared__ float sums[64];
  __shared__ float strip[16][129];
  int t = threadIdx.x;
  int lane = t & 63, wave = t >> 6;
  int lid = lane & 15, g = lane >> 4;
  int q0 = blockIdx.x * 16;
  int bh = blockIdx.y;
  int b = bh >> 3, h = bh & 7;
  const bf16* qb = Q + (size_t)b * L_ * 1024 + h * 64;
  const bf16* kb = K + (size_t)bh * LP_ * 64;
  const uint64_t* gmb = GM + (size_t)b * L_ * 32;

  bf16x8 aq0 = zf8(), aq1 = zf8();
  {
    int qr = q0 + lid;
    if (qr < L_) {
      aq0 = *reinterpret_cast<const bf16x8*>(qb + (size_t)qr * 1024 + g * 8);
      aq1 = *reinterpret_cast<const bf16x8*>(qb + (size_t)qr * 1024 + 32 + g * 8);
    }
  }
  uint32_t preg[64];            // [it(16)][r(4)] packed (tt0, tt1) bf16 pair
  float rs[4] = {0.f, 0.f, 0.f, 0.f};
#pragma unroll
  for (int it = 0; it < 16; ++it) {
    int p = it * 4 + wave;
    int c0 = p * 32;
    int col0 = c0 + lid, col1 = c0 + 16 + lid;
    bf16x8 bka0 = *reinterpret_cast<const bf16x8*>(kb + (size_t)col0 * 64 + g * 8);
    bf16x8 bka1 = *reinterpret_cast<const bf16x8*>(kb + (size_t)col0 * 64 + 32 + g * 8);
    bf16x8 bkb0 = *reinterpret_cast<const bf16x8*>(kb + (size_t)col1 * 64 + g * 8);
    bf16x8 bkb1 = *reinterpret_cast<const bf16x8*>(kb + (size_t)col1 * 64 + 32 + g * 8);
    f32x4 acc0 = {0.f, 0.f, 0.f, 0.f}, acc1 = {0.f, 0.f, 0.f, 0.f};
    acc0 = __builtin_amdgcn_mfma_f32_16x16x32_bf16(aq0, bka0, acc0, 0, 0, 0);
    acc0 = __builtin_amdgcn_mfma_f32_16x16x32_bf16(aq1, bka1, acc0, 0, 0, 0);
    acc1 = __builtin_amdgcn_mfma_f32_16x16x32_bf16(aq0, bkb0, acc1, 0, 0, 0);
    acc1 = __builtin_amdgcn_mfma_f32_16x16x32_bf16(aq1, bkb1, acc1, 0, 0, 0);
    int wi = c0 >> 6;           // both halves share the same 64-col mask word
    int bit0 = c0 & 32;
#pragma unroll
    for (int r = 0; r < 4; ++r) {
      int qr = q0 + g * 4 + r;
      uint64_t w = (qr < L_) ? gmb[(size_t)qr * 32 + wi] : ~0ull;
      float pv0 = ((w >> (bit0 + lid)) & 1) ? 0.0f : __expf(acc0[r] * SCALE_);
      float pv1 = ((w >> (bit0 + 16 + lid)) & 1) ? 0.0f : __expf(acc1[r] * SCALE_);
      rs[r] += pv0 + pv1;
      preg[it * 4 + r] = pkbf(pv0, pv1);
    }
  }
#pragma unroll
  for (int off = 8; off >= 1; off >>= 1)
#pragma unroll
    for (int r = 0; r < 4; ++r) rs[r] += __shfl_xor(rs[r], off, 64);
  if (lid == 0) {
#pragma unroll
    for (int r = 0; r < 4; ++r) sums[wave * 16 + g * 4 + r] = rs[r];
  }
  __syncthreads();
  // coalesced write: bounce each 16x128 chunk through LDS; 8 floats/thread
  int orow = t >> 4;            // 0..15
  float sAll = sums[orow] + sums[16 + orow] + sums[32 + orow] + sums[48 + orow];
  float invT = (sAll > 0.f) ? 1.0f / sAll : 0.0f;
  int qrT = q0 + orow;
  bool rowok = (qrT < L_);
  const size_t rowb = (size_t)bh * L_ * L_ + (size_t)(rowok ? qrT : 0) * L_;
  int c8 = (t & 15) * 8;
#pragma unroll
  for (int it = 0; it < 16; ++it) {
#pragma unroll
    for (int r = 0; r < 4; ++r) {
      uint32_t u = preg[it * 4 + r];
      strip[g * 4 + r][wave * 32 + lid] = upk_lo(u);
      strip[g * 4 + r][wave * 32 + 16 + lid] = upk_hi(u);
    }
    __syncthreads();
    int col = it * 128 + c8;
    if (rowok) {
#pragma unroll
      for (int pr = 0; pr < 4; ++pr) {
        int cc = c8 + pr * 2;
        if (col + pr * 2 + 1 < L_) {
          float2 o2 = make_float2(strip[orow][cc] * invT, strip[orow][cc + 1] * invT);
          *reinterpret_cast<float2*>(OP + rowb + col + pr * 2) = o2;
        }
      }
    }
    __syncthreads();
  }
}

// ---------------- local scores: single-pass, coalesced LDS-bounce epilogue ----------------
__global__ __launch_bounds__(256) void attn_ls(const bf16* __restrict__ Q,
    const bf16* __restrict__ K, const uint64_t* __restrict__ WM,
    float* __restrict__ OP) {
  __shared__ float sums[64];
  __shared__ float strip[16][129];
  int t = threadIdx.x;
  int lane = t & 63, wave = t >> 6;
  int lid = lane & 15, g = lane >> 4;
  int q0 = blockIdx.x * 16;
  int bh = blockIdx.y;
  int b = bh >> 3, h = bh & 7;
  const bf16* qb = Q + (size_t)b * L_ * 1024 + (8 + h) * 64;
  const bf16* kb = K + (size_t)bh * NWP_ * 64;
  const uint64_t* wmb = WM + (size_t)b * L_ * 11;

  bf16x8 aq0 = zf8(), aq1 = zf8();
  {
    int qr = q0 + lid;
    if (qr < L_) {
      aq0 = *reinterpret_cast<const bf16x8*>(qb + (size_t)qr * 1024 + g * 8);
      aq1 = *reinterpret_cast<const bf16x8*>(qb + (size_t)qr * 1024 + 32 + g * 8);
    }
  }
  uint32_t preg[24];            // [it(6)][r(4)]
  float rs[4] = {0.f, 0.f, 0.f, 0.f};
#pragma unroll
  for (int it = 0; it < 6; ++it) {
    int p = it * 4 + wave;
    if (p < 22) {
      int c0 = p * 32;
      int col0 = c0 + lid, col1 = c0 + 16 + lid;
      bf16x8 bka0 = *reinterpret_cast<const bf16x8*>(kb + (size_t)col0 * 64 + g * 8);
      bf16x8 bka1 = *reinterpret_cast<const bf16x8*>(kb + (size_t)col0 * 64 + 32 + g * 8);
      bf16x8 bkb0 = *reinterpret_cast<const bf16x8*>(kb + (size_t)col1 * 64 + g * 8);
      bf16x8 bkb1 = *reinterpret_cast<const bf16x8*>(kb + (size_t)col1 * 64 + 32 + g * 8);
      f32x4 acc0 = {0.f, 0.f, 0.f, 0.f}, acc1 = {0.f, 0.f, 0.f, 0.f};
      acc0 = __builtin_amdgcn_mfma_f32_16x16x32_bf16(aq0, bka0, acc0, 0, 0, 0);
      acc0 = __builtin_amdgcn_mfma_f32_16x16x32_bf16(aq1, bka1, acc0, 0, 0, 0);
      acc1 = __builtin_amdgcn_mfma_f32_16x16x32_bf16(aq0, bkb0, acc1, 0, 0, 0);
      acc1 = __builtin_amdgcn_mfma_f32_16x16x32_bf16(aq1, bkb1, acc1, 0, 0, 0);
      int wi = c0 >> 6;
      int bit0 = c0 & 32;
#pragma unroll
      for (int r = 0; r < 4; ++r) {
        int qr = q0 + g * 4 + r;
        uint64_t w = (qr < L_) ? wmb[(size_t)qr * 11 + wi] : ~0ull;
        float pv0 = ((w >> (bit0 + lid)) & 1) ? 0.0f : __expf(acc0[r] * SCALE_);
        float pv1 = ((w >> (bit0 + 16 + lid)) & 1) ? 0.0f : __expf(acc1[r] * SCALE_);
        rs[r] += pv0 + pv1;
        preg[it * 4 + r] = pkbf(pv0, pv1);
      }
    }
  }
#pragma unroll
  for (int off = 8; off >= 1; off >>= 1)
#pragma unroll
    for (int r = 0; r < 4; ++r) rs[r] += __shfl_xor(rs[r], off, 64);
  if (lid == 0) {
#pragma unroll
    for (int r = 0; r < 4; ++r) sums[wave * 16 + g * 4 + r] = rs[r];
  }
  __syncthreads();
  int orow = t >> 4;
  float sAll = sums[orow] + sums[16 + orow] + sums[32 + orow] + sums[48 + orow];
  float invT = (sAll > 0.f) ? 1.0f / sAll : 0.0f;
  int qrT = q0 + orow;
  bool rowok = (qrT < L_);
  const size_t rowb = (size_t)bh * L_ * NW_ + (size_t)(rowok ? qrT : 0) * NW_;
  int c8 = (t & 15) * 8;
#pragma unroll
  for (int it = 0; it < 6; ++it) {
    int p = it * 4 + wave;
    if (p < 22) {
#pragma unroll
      for (int r = 0; r < 4; ++r) {
        uint32_t u = preg[it * 4 + r];
        strip[g * 4 + r][wave * 32 + lid] = upk_lo(u);
        strip[g * 4 + r][wave * 32 + 16 + lid] = upk_hi(u);
      }
    }
    __syncthreads();
    int col = it * 128 + c8;
    if (rowok) {
#pragma unroll
      for (int pr = 0; pr < 4; ++pr) {
        int cc = c8 + pr * 2;
        if (col + pr * 2 + 1 < NW_) {
          float2 o2 = make_float2(strip[orow][cc] * invT, strip[orow][cc + 1] * invT);
          *reinterpret_cast<float2*>(OP + rowb + col + pr * 2) = o2;
        }
      }
    }
    __syncthreads();
  }
}

// ---------------- PV via MFMA: O = P @ V (R6-verified) ----------------
template <int MT, int ML, int VROWS>
__global__ __launch_bounds__(256) void pv_mfma(const float* __restrict__ P,
    const bf16* __restrict__ V, float* __restrict__ OV, int hbase) {
  __shared__ bf16 vt[64][40];            // vt[d][mloc], 80B row stride (16B-aligned)
  int t = threadIdx.x;
  int lane = t & 63, wave = t >> 6;
  int lid = lane & 15, g = lane >> 4;
  int bh = blockIdx.y, b = bh >> 3, h = bh & 7;
  int q0w = blockIdx.x * 64 + wave * 16;
  const float* Pb = P + (size_t)bh * L_ * ML;
  const bf16* Vb = V + (size_t)bh * VROWS * 64;
  int arow = q0w + lid; if (arow >= L_) arow = L_ - 1;   // clamp; results discarded
  const float* prow = Pb + (size_t)arow * ML;
  int sd = t & 63, mgrp = t >> 6;        // staging map: d = sd, m-group = mgrp
  f32x4 vacc[4];
  f32x4 z4 = {0.f, 0.f, 0.f, 0.f};
#pragma unroll
  for (int dg = 0; dg < 4; ++dg) vacc[dg] = z4;

  for (int mt = 0; mt < MT; ++mt) {
    int m0 = mt * 32;
    bf16 stmp[8];
#pragma unroll
    for (int e = 0; e < 8; ++e)
      stmp[e] = Vb[(size_t)(m0 + mgrp * 8 + e) * 64 + sd];
    *reinterpret_cast<bf16x8*>(&vt[sd][mgrp * 8]) = *reinterpret_cast<const bf16x8*>(stmp);
    __syncthreads();
    bf16x8 pa;
    if (m0 + 32 <= ML) {
      const float* pp = prow + m0 + g * 8;
#pragma unroll
      for (int e = 0; e < 8; ++e) pa[e] = (bf16)pp[e];
    } else {
#pragma unroll
      for (int e = 0; e < 8; ++e) {
        int m = m0 + g * 8 + e;
        pa[e] = (m < ML) ? (bf16)prow[m] : (bf16)0.0f;
      }
    }
#pragma unroll
    for (int dg = 0; dg < 4; ++dg) {
      bf16x8 bv8 = *reinterpret_cast<const bf16x8*>(&vt[dg * 16 + lid][g * 8]);
      vacc[dg] = __builtin_amdgcn_mfma_f32_16x16x32_bf16(pa, bv8, vacc[dg], 0, 0, 0);
    }
    __syncthreads();
  }
  float* ob = OV + (((size_t)b * 16 + hbase + h) * L_) * 64;
#pragma unroll
  for (int dg = 0; dg < 4; ++dg)
#pragma unroll
    for (int r = 0; r < 4; ++r) {
      int qr = q0w + g * 4 + r;
      if (qr < L_) ob[(size_t)qr * 64 + dg * 16 + lid] = vacc[dg][r];
    }
}

extern "C" void kernel_launch(void* const* d_in, const int* in_sizes, int n_in,
                              void* d_out, int out_size, void* d_ws, size_t ws_size,
                              hipStream_t stream) {
  (void)in_sizes; (void)n_in; (void)out_size; (void)ws_size;
  const float* x    = (const float*)d_in[0];
  const float* mask = (const float*)d_in[1];
  const float* Wq   = (const float*)d_in[2];
  const float* bq   = (const float*)d_in[3];
  const float* Wk   = (const float*)d_in[4];
  const float* bk   = (const float*)d_in[5];
  const float* Wv   = (const float*)d_in[6];
  const float* bv   = (const float*)d_in[7];

  char* ws = (char*)d_ws;
  bf16* qbb     = (bf16*)(ws + 0);            // 8,380,416
  bf16* kgb     = (bf16*)(ws + 8380416);      // 4,194,304
  bf16* vgb     = (bf16*)(ws + 12574720);     // 4,194,304 (row-major V)
  bf16* klb     = (bf16*)(ws + 16769024);     // 1,441,792
  bf16* vlb     = (bf16*)(ws + 18210816);     // 1,441,792
  uint64_t* gm  = (uint64_t*)(ws + 19652608); // 1,047,552
  uint64_t* wm  = (uint64_t*)(ws + 20700160); // 360,096
  bf16* xbb     = (bf16*)(ws + 21060256);     // 8,380,416 (x in bf16)
  bf16* wqb     = (bf16*)(ws + 29440672);     // 2,097,152 (Wq in bf16)

  float* out    = (float*)d_out;
  float* o_vall = out;                 // (2,16,2046,64)
  float* o_pg   = out + 4190208;       // (2,8,2046,2046)
  float* o_pl   = out + 71168064;      // (2,8,2046,682)

  cast4<<<4092, 256, 0, stream>>>(x, xbb, 4190208);
  cast4<<<1024, 256, 0, stream>>>(Wq, wqb, 1048576);
  qgemm_t<<<dim3(64, 8), 256, 0, stream>>>(xbb, wqb, bq, qbb);
  proj_g32<<<dim3(32, 16), 256, 0, stream>>>(x, Wk, bk, Wv, bv, kgb, vgb);
  proj_l32<<<dim3(11, 16), 256, 0, stream>>>(x, Wk, bk, Wv, bv, klb, vlb);
  maskprep<<<1023, 256, 0, stream>>>(mask, gm, wm);

  attn_gs<<<dim3(128, 16), 256, 0, stream>>>(qbb, kgb, gm, o_pg);
  attn_ls<<<dim3(128, 16), 256, 0, stream>>>(qbb, klb, wm, o_pl);

  pv_mfma<64, L_, LP_><<<dim3(32, 16), 256, 0, stream>>>(o_pg, vgb, o_vall, 0);
  pv_mfma<22, NW_, NWP_><<<dim3(32, 16), 256, 0, stream>>>(o_pl, vlb, o_vall, 8);
}

// Round 11
// 456.357 us; speedup vs baseline: 16.4307x; 1.0589x over previous
//
#include <hip/hip_runtime.h>
#include <hip/hip_bf16.h>
#include <stdint.h>

typedef __bf16 bf16;
typedef bf16 bf16x8 __attribute__((ext_vector_type(8)));
typedef float f32x4 __attribute__((ext_vector_type(4)));

#define B_ 2
#define L_ 2046
#define H_ 16
#define NW_ 682
#define LP_ 2048
#define NWP_ 704
#define M_ (B_*L_)
#define SCALE_ 0.125f

__device__ inline bf16x8 zf8() {
  bf16x8 v;
#pragma unroll
  for (int e = 0; e < 8; ++e) v[e] = (bf16)0.0f;
  return v;
}

__device__ inline uint32_t pkbf(float a, float b) {
  uint16_t ua = __builtin_bit_cast(uint16_t, (bf16)a);
  uint16_t ub = __builtin_bit_cast(uint16_t, (bf16)b);
  return (uint32_t)ua | ((uint32_t)ub << 16);
}
__device__ inline float upk_lo(uint32_t u) { return __builtin_bit_cast(float, u << 16); }
__device__ inline float upk_hi(uint32_t u) { return __builtin_bit_cast(float, u & 0xffff0000u); }

// ---------------- cast f32 -> bf16 (vectorized x4) ----------------
__global__ __launch_bounds__(256) void cast4(const float* __restrict__ in,
                                             bf16* __restrict__ out, int n) {
  int i = (blockIdx.x * 256 + threadIdx.x) * 4;
  if (i + 3 < n) {
    float4 v = *reinterpret_cast<const float4*>(in + i);
    bf16 tmp[4];
    tmp[0] = (bf16)v.x; tmp[1] = (bf16)v.y; tmp[2] = (bf16)v.z; tmp[3] = (bf16)v.w;
    *reinterpret_cast<uint64_t*>(out + i) = *reinterpret_cast<const uint64_t*>(tmp);
  } else {
    for (; i < n; ++i) out[i] = (bf16)in[i];
  }
}

// ---------------- q = x @ Wq^T + bq : LDS-tiled MFMA GEMM (64x128 tile, BK=32) ----------------
__global__ __launch_bounds__(256) void qgemm_t(const bf16* __restrict__ X,
                                               const bf16* __restrict__ W,
                                               const float* __restrict__ bq,
                                               bf16* __restrict__ Q) {
  __shared__ bf16 As[64 * 40];    // [row][k] rows padded to 40 bf16 (80B)
  __shared__ bf16 Bs[128 * 40];
  int t = threadIdx.x, lane = t & 63, w = t >> 6;
  int lid = lane & 15, g = lane >> 4;
  int m0 = blockIdx.x * 64, n0 = blockIdx.y * 128;
  int wm = (w >> 1) * 32, wn = (w & 1) * 64;
  f32x4 z4 = {0.f, 0.f, 0.f, 0.f};
  f32x4 acc[2][4];
#pragma unroll
  for (int mi = 0; mi < 2; ++mi)
#pragma unroll
    for (int ni = 0; ni < 4; ++ni) acc[mi][ni] = z4;
  int r1 = t >> 2, c1 = t & 3;    // staging: row = r1 (0..63), 8-elem chunk c1 (0..3)
  for (int k0 = 0; k0 < 1024; k0 += 32) {
    int ga = m0 + r1; if (ga >= M_) ga = M_ - 1;
    bf16x8 av = *reinterpret_cast<const bf16x8*>(X + (size_t)ga * 1024 + k0 + c1 * 8);
    bf16x8 bv1 = *reinterpret_cast<const bf16x8*>(W + (size_t)(n0 + r1) * 1024 + k0 + c1 * 8);
    bf16x8 bv2 = *reinterpret_cast<const bf16x8*>(W + (size_t)(n0 + 64 + r1) * 1024 + k0 + c1 * 8);
    __syncthreads();   // previous tile fully consumed
    *reinterpret_cast<bf16x8*>(As + r1 * 40 + c1 * 8) = av;
    *reinterpret_cast<bf16x8*>(Bs + r1 * 40 + c1 * 8) = bv1;
    *reinterpret_cast<bf16x8*>(Bs + (64 + r1) * 40 + c1 * 8) = bv2;
    __syncthreads();
    bf16x8 af[2], bfr[4];
#pragma unroll
    for (int mi = 0; mi < 2; ++mi)
      af[mi] = *reinterpret_cast<const bf16x8*>(As + (wm + mi * 16 + lid) * 40 + g * 8);
#pragma unroll
    for (int ni = 0; ni < 4; ++ni)
      bfr[ni] = *reinterpret_cast<const bf16x8*>(Bs + (wn + ni * 16 + lid) * 40 + g * 8);
#pragma unroll
    for (int mi = 0; mi < 2; ++mi)
#pragma unroll
      for (int ni = 0; ni < 4; ++ni)
        acc[mi][ni] = __builtin_amdgcn_mfma_f32_16x16x32_bf16(af[mi], bfr[ni], acc[mi][ni], 0, 0, 0);
  }
  float bias[4];
#pragma unroll
  for (int ni = 0; ni < 4; ++ni) bias[ni] = bq[n0 + wn + ni * 16 + lid];
#pragma unroll
  for (int mi = 0; mi < 2; ++mi)
#pragma unroll
    for (int r = 0; r < 4; ++r) {
      int row = m0 + wm + mi * 16 + g * 4 + r;
      if (row < M_) {
#pragma unroll
        for (int ni = 0; ni < 4; ++ni)
          Q[(size_t)row * 1024 + n0 + wn + ni * 16 + lid] = (bf16)(acc[mi][ni][r] + bias[ni]);
      }
    }
}

// ---------------- global-head K/V projections (f32 math, bf16 row-major out) ----------------
__global__ __launch_bounds__(256) void proj_g32(const float* __restrict__ x,
    const float* __restrict__ Wk, const float* __restrict__ bk,
    const float* __restrict__ Wv, const float* __restrict__ bv,
    bf16* __restrict__ KGP, bf16* __restrict__ VGP) {
  __shared__ float xs[64][64];
  __shared__ float wks[64][65];
  __shared__ float wvs[64][65];
  int t = threadIdx.x;
  int lb = blockIdx.x, bh = blockIdx.y;
  int b = bh >> 3, h = bh & 7;
  int l0 = lb * 64;
  for (int idx = t; idx < 4096; idx += 256) {
    int r = idx >> 6, c = idx & 63;
    int l = l0 + r;
    xs[r][c] = (l < L_) ? x[((size_t)b * L_ + l) * 1024 + h * 64 + c] : 0.0f;
    wks[r][c] = Wk[(size_t)h * 4096 + idx];
    wvs[r][c] = Wv[(size_t)h * 4096 + idx];
  }
  __syncthreads();
  int o = t & 63, lg = t >> 6;
  float kbias = bk[h * 64 + o], vbias = bv[h * 64 + o];
  const size_t outb = (size_t)bh * LP_ * 64;
  for (int ls = 0; ls < 16; ++ls) {
    int l = lg * 16 + ls;
    float ka = kbias, va = vbias;
#pragma unroll
    for (int i = 0; i < 64; ++i) {
      float xv = xs[l][i];
      ka = fmaf(xv, wks[o][i], ka);
      va = fmaf(xv, wvs[o][i], va);
    }
    KGP[outb + (size_t)(l0 + l) * 64 + o] = (bf16)ka;
    VGP[outb + (size_t)(l0 + l) * 64 + o] = (bf16)va;
  }
}

// ---------------- local-head window-avg + K/V projections (f32 math, bf16 out) ----------------
__global__ __launch_bounds__(256) void proj_l32(const float* __restrict__ x,
    const float* __restrict__ Wk, const float* __restrict__ bk,
    const float* __restrict__ Wv, const float* __restrict__ bv,
    bf16* __restrict__ KLP, bf16* __restrict__ VLP) {
  __shared__ float xs[64][64];
  __shared__ float wks[64][65];
  __shared__ float wvs[64][65];
  int t = threadIdx.x;
  int nb = blockIdx.x, bh = blockIdx.y;
  int b = bh >> 3, h = bh & 7;
  int n0 = nb * 64;
  int hh = 8 + h;
  for (int idx = t; idx < 4096; idx += 256) {
    int r = idx >> 6, c = idx & 63;
    int n = n0 + r;
    float v = 0.0f;
    if (n < NW_) {
      size_t base = ((size_t)b * L_ + 3 * n) * 1024 + hh * 64 + c;
      v = (x[base] + x[base + 1024] + x[base + 2048]) * (1.0f / 3.0f);
    }
    xs[r][c] = v;
    wks[r][c] = Wk[(size_t)hh * 4096 + idx];
    wvs[r][c] = Wv[(size_t)hh * 4096 + idx];
  }
  __syncthreads();
  int o = t & 63, lg = t >> 6;
  float kbias = bk[hh * 64 + o], vbias = bv[hh * 64 + o];
  const size_t outb = (size_t)bh * NWP_ * 64;
  for (int ls = 0; ls < 16; ++ls) {
    int l = lg * 16 + ls;
    float ka = kbias, va = vbias;
#pragma unroll
    for (int i = 0; i < 64; ++i) {
      float xv = xs[l][i];
      ka = fmaf(xv, wks[o][i], ka);
      va = fmaf(xv, wvs[o][i], va);
    }
    KLP[outb + (size_t)(n0 + l) * 64 + o] = (bf16)ka;
    VLP[outb + (size_t)(n0 + l) * 64 + o] = (bf16)va;
  }
}

// ---------------- mask precompute: bit-packed (1 = masked) — R3-verified ----------------
__global__ __launch_bounds__(256) void maskprep(const float* __restrict__ mask,
                                                uint64_t* __restrict__ gm,
                                                uint64_t* __restrict__ wm) {
  int row = blockIdx.x * 4 + (threadIdx.x >> 6);  // b*L + l
  int lane = threadIdx.x & 63;
  if (row >= B_ * L_) return;
  int b = row / L_, l = row % L_;
  const float* mr = mask + (size_t)b * L_ * L_ + (size_t)l * L_;
  for (int w = 0; w < 32; ++w) {
    int m = w * 64 + lane;
    bool masked = (m >= L_) ? true : (mr[m] == 0.0f);
    uint64_t bal = __ballot(masked);
    if (lane == 0) gm[(size_t)row * 32 + w] = bal;
  }
  for (int w = 0; w < 11; ++w) {
    int n = w * 64 + lane;
    bool lmask = true;
    if (n < NW_) {
      float s = mr[3 * n] + mr[3 * n + 1] + mr[3 * n + 2];
      lmask = !(s >= 2.0f);
    }
    uint64_t bal = __ballot(lmask);
    if (lane == 0) wm[(size_t)row * 11 + w] = bal;
  }
}

// ---------------- FUSED global: QK^T -> softmax -> pg write + PV -> value ----------------
__global__ __launch_bounds__(256) void attn_gf(const bf16* __restrict__ Q,
    const bf16* __restrict__ K, const bf16* __restrict__ V,
    const uint64_t* __restrict__ GM,
    float* __restrict__ OP, float* __restrict__ OV) {
  __shared__ float sums[64];
  __shared__ float strip[16][129];    // normalized P chunk (16 q-rows x 128 cols)
  __shared__ bf16 vt[4][64][40];      // per-wave V^T tile: [d][m_local], 80B rows
  __shared__ float vred[4][16][64];
  int t = threadIdx.x;
  int lane = t & 63, wave = t >> 6;
  int lid = lane & 15, g = lane >> 4;
  int q0 = blockIdx.x * 16;
  int bh = blockIdx.y;
  int b = bh >> 3, h = bh & 7;
  const bf16* qb = Q + (size_t)b * L_ * 1024 + h * 64;
  const bf16* kb = K + (size_t)bh * LP_ * 64;
  const bf16* vpb = V + (size_t)bh * LP_ * 64;
  const uint64_t* gmb = GM + (size_t)b * L_ * 32;

  bf16x8 aq0 = zf8(), aq1 = zf8();
  {
    int qr = q0 + lid;
    if (qr < L_) {
      aq0 = *reinterpret_cast<const bf16x8*>(qb + (size_t)qr * 1024 + g * 8);
      aq1 = *reinterpret_cast<const bf16x8*>(qb + (size_t)qr * 1024 + 32 + g * 8);
    }
  }
  // ---- phase 1: single-pass QK^T, P in registers (R8-verified) ----
  uint32_t preg[64];            // [it(16)][r(4)] packed (tt0, tt1) bf16 pair
  float rs[4] = {0.f, 0.f, 0.f, 0.f};
#pragma unroll
  for (int it = 0; it < 16; ++it) {
    int p = it * 4 + wave;
    int c0 = p * 32;
    int col0 = c0 + lid, col1 = c0 + 16 + lid;
    bf16x8 bka0 = *reinterpret_cast<const bf16x8*>(kb + (size_t)col0 * 64 + g * 8);
    bf16x8 bka1 = *reinterpret_cast<const bf16x8*>(kb + (size_t)col0 * 64 + 32 + g * 8);
    bf16x8 bkb0 = *reinterpret_cast<const bf16x8*>(kb + (size_t)col1 * 64 + g * 8);
    bf16x8 bkb1 = *reinterpret_cast<const bf16x8*>(kb + (size_t)col1 * 64 + 32 + g * 8);
    f32x4 acc0 = {0.f, 0.f, 0.f, 0.f}, acc1 = {0.f, 0.f, 0.f, 0.f};
    acc0 = __builtin_amdgcn_mfma_f32_16x16x32_bf16(aq0, bka0, acc0, 0, 0, 0);
    acc0 = __builtin_amdgcn_mfma_f32_16x16x32_bf16(aq1, bka1, acc0, 0, 0, 0);
    acc1 = __builtin_amdgcn_mfma_f32_16x16x32_bf16(aq0, bkb0, acc1, 0, 0, 0);
    acc1 = __builtin_amdgcn_mfma_f32_16x16x32_bf16(aq1, bkb1, acc1, 0, 0, 0);
    int wi = c0 >> 6;
    int bit0 = c0 & 32;
#pragma unroll
    for (int r = 0; r < 4; ++r) {
      int qr = q0 + g * 4 + r;
      uint64_t w = (qr < L_) ? gmb[(size_t)qr * 32 + wi] : ~0ull;
      float pv0 = ((w >> (bit0 + lid)) & 1) ? 0.0f : __expf(acc0[r] * SCALE_);
      float pv1 = ((w >> (bit0 + 16 + lid)) & 1) ? 0.0f : __expf(acc1[r] * SCALE_);
      rs[r] += pv0 + pv1;
      preg[it * 4 + r] = pkbf(pv0, pv1);
    }
  }
#pragma unroll
  for (int off = 8; off >= 1; off >>= 1)
#pragma unroll
    for (int r = 0; r < 4; ++r) rs[r] += __shfl_xor(rs[r], off, 64);
  if (lid == 0) {
#pragma unroll
    for (int r = 0; r < 4; ++r) sums[wave * 16 + g * 4 + r] = rs[r];
  }
  __syncthreads();
  float invr[4];
#pragma unroll
  for (int r = 0; r < 4; ++r) {
    int row = g * 4 + r;
    float s = sums[row] + sums[16 + row] + sums[32 + row] + sums[48 + row];
    invr[r] = (s > 0.f) ? 1.0f / s : 0.0f;
  }
  // ---- phase 2: per 16x128 chunk: strip (normalized) -> pg store + fused PV ----
  int orow = t >> 4;            // 0..15
  int qrT = q0 + orow;
  bool rowok = (qrT < L_);
  const size_t rowb = (size_t)bh * L_ * L_ + (size_t)(rowok ? qrT : 0) * L_;
  int c8 = (t & 15) * 8;
  f32x4 vacc[4];
  f32x4 z4 = {0.f, 0.f, 0.f, 0.f};
#pragma unroll
  for (int dg = 0; dg < 4; ++dg) vacc[dg] = z4;
#pragma unroll
  for (int it = 0; it < 16; ++it) {
    int m0 = (it * 4 + wave) * 32;
    // normalized strip write
#pragma unroll
    for (int r = 0; r < 4; ++r) {
      uint32_t u = preg[it * 4 + r];
      strip[g * 4 + r][wave * 32 + lid] = upk_lo(u) * invr[r];
      strip[g * 4 + r][wave * 32 + 16 + lid] = upk_hi(u) * invr[r];
    }
    __syncthreads();
    // coalesced pg store (8 floats/thread)
    int col = it * 128 + c8;
    if (rowok) {
#pragma unroll
      for (int pr = 0; pr < 4; ++pr) {
        int cc = c8 + pr * 2;
        if (col + pr * 2 + 1 < L_) {
          float2 o2 = make_float2(strip[orow][cc], strip[orow][cc + 1]);
          *reinterpret_cast<float2*>(OP + rowb + col + pr * 2) = o2;
        }
      }
    }
    // stage own-wave V chunk (32 m-rows) transposed into vt[wave]
    bf16 st[4][8];
#pragma unroll
    for (int mg = 0; mg < 4; ++mg)
#pragma unroll
      for (int e = 0; e < 8; ++e)
        st[mg][e] = vpb[(size_t)(m0 + mg * 8 + e) * 64 + lane];
#pragma unroll
    for (int mg = 0; mg < 4; ++mg)
      *reinterpret_cast<bf16x8*>(&vt[wave][lane][mg * 8]) = *reinterpret_cast<const bf16x8*>(st[mg]);
    // A-fragment from own-wave strip columns (normalized P)
    bf16x8 af;
#pragma unroll
    for (int e = 0; e < 8; ++e) af[e] = (bf16)strip[lid][wave * 32 + g * 8 + e];
#pragma unroll
    for (int dg = 0; dg < 4; ++dg) {
      bf16x8 bv8 = *reinterpret_cast<const bf16x8*>(&vt[wave][dg * 16 + lid][g * 8]);
      vacc[dg] = __builtin_amdgcn_mfma_f32_16x16x32_bf16(af, bv8, vacc[dg], 0, 0, 0);
    }
    __syncthreads();
  }
  // ---- cross-wave reduce + OV write (already normalized) ----
#pragma unroll
  for (int dg = 0; dg < 4; ++dg)
#pragma unroll
    for (int r = 0; r < 4; ++r)
      vred[wave][g * 4 + r][dg * 16 + lid] = vacc[dg][r];
  __syncthreads();
  float* ob = OV + (((size_t)b * 16 + h) * L_) * 64;
  for (int idx = t; idx < 1024; idx += 256) {
    int r = idx >> 6, d = idx & 63;
    int qr = q0 + r;
    if (qr < L_)
      ob[(size_t)qr * 64 + d] = vred[0][r][d] + vred[1][r][d] + vred[2][r][d] + vred[3][r][d];
  }
}

// ---------------- FUSED local: QK^T -> softmax -> pl write + PV -> value ----------------
__global__ __launch_bounds__(256) void attn_lf(const bf16* __restrict__ Q,
    const bf16* __restrict__ K, const bf16* __restrict__ V,
    const uint64_t* __restrict__ WM,
    float* __restrict__ OP, float* __restrict__ OV) {
  __shared__ float sums[64];
  __shared__ float strip[16][129];
  __shared__ bf16 vt[4][64][40];
  __shared__ float vred[4][16][64];
  int t = threadIdx.x;
  int lane = t & 63, wave = t >> 6;
  int lid = lane & 15, g = lane >> 4;
  int q0 = blockIdx.x * 16;
  int bh = blockIdx.y;
  int b = bh >> 3, h = bh & 7;
  const bf16* qb = Q + (size_t)b * L_ * 1024 + (8 + h) * 64;
  const bf16* kb = K + (size_t)bh * NWP_ * 64;
  const bf16* vpb = V + (size_t)bh * NWP_ * 64;
  const uint64_t* wmb = WM + (size_t)b * L_ * 11;

  bf16x8 aq0 = zf8(), aq1 = zf8();
  {
    int qr = q0 + lid;
    if (qr < L_) {
      aq0 = *reinterpret_cast<const bf16x8*>(qb + (size_t)qr * 1024 + g * 8);
      aq1 = *reinterpret_cast<const bf16x8*>(qb + (size_t)qr * 1024 + 32 + g * 8);
    }
  }
  uint32_t preg[24];
  float rs[4] = {0.f, 0.f, 0.f, 0.f};
#pragma unroll
  for (int it = 0; it < 6; ++it) {
    int p = it * 4 + wave;
    if (p < 22) {
      int c0 = p * 32;
      int col0 = c0 + lid, col1 = c0 + 16 + lid;
      bf16x8 bka0 = *reinterpret_cast<const bf16x8*>(kb + (size_t)col0 * 64 + g * 8);
      bf16x8 bka1 = *reinterpret_cast<const bf16x8*>(kb + (size_t)col0 * 64 + 32 + g * 8);
      bf16x8 bkb0 = *reinterpret_cast<const bf16x8*>(kb + (size_t)col1 * 64 + g * 8);
      bf16x8 bkb1 = *reinterpret_cast<const bf16x8*>(kb + (size_t)col1 * 64 + 32 + g * 8);
      f32x4 acc0 = {0.f, 0.f, 0.f, 0.f}, acc1 = {0.f, 0.f, 0.f, 0.f};
      acc0 = __builtin_amdgcn_mfma_f32_16x16x32_bf16(aq0, bka0, acc0, 0, 0, 0);
      acc0 = __builtin_amdgcn_mfma_f32_16x16x32_bf16(aq1, bka1, acc0, 0, 0, 0);
      acc1 = __builtin_amdgcn_mfma_f32_16x16x32_bf16(aq0, bkb0, acc1, 0, 0, 0);
      acc1 = __builtin_amdgcn_mfma_f32_16x16x32_bf16(aq1, bkb1, acc1, 0, 0, 0);
      int wi = c0 >> 6;
      int bit0 = c0 & 32;
#pragma unroll
      for (int r = 0; r < 4; ++r) {
        int qr = q0 + g * 4 + r;
        uint64_t w = (qr < L_) ? wmb[(size_t)qr * 11 + wi] : ~0ull;
        float pv0 = ((w >> (bit0 + lid)) & 1) ? 0.0f : __expf(acc0[r] * SCALE_);
        float pv1 = ((w >> (bit0 + 16 + lid)) & 1) ? 0.0f : __expf(acc1[r] * SCALE_);
        rs[r] += pv0 + pv1;
        preg[it * 4 + r] = pkbf(pv0, pv1);
      }
    }
  }
#pragma unroll
  for (int off = 8; off >= 1; off >>= 1)
#pragma unroll
    for (int r = 0; r < 4; ++r) rs[r] += __shfl_xor(rs[r], off, 64);
  if (lid == 0) {
#pragma unroll
    for (int r = 0; r < 4; ++r) sums[wave * 16 + g * 4 + r] = rs[r];
  }
  __syncthreads();
  float invr[4];
#pragma unroll
  for (int r = 0; r < 4; ++r) {
    int row = g * 4 + r;
    float s = sums[row] + sums[16 + row] + sums[32 + row] + sums[48 + row];
    invr[r] = (s > 0.f) ? 1.0f / s : 0.0f;
  }
  int orow = t >> 4;
  int qrT = q0 + orow;
  bool rowok = (qrT < L_);
  const size_t rowb = (size_t)bh * L_ * NW_ + (size_t)(rowok ? qrT : 0) * NW_;
  int c8 = (t & 15) * 8;
  f32x4 vacc[4];
  f32x4 z4 = {0.f, 0.f, 0.f, 0.f};
#pragma unroll
  for (int dg = 0; dg < 4; ++dg) vacc[dg] = z4;
#pragma unroll
  for (int it = 0; it < 6; ++it) {
    int p = it * 4 + wave;
    bool act = (p < 22);
    int m0 = p * 32;
    if (act) {
#pragma unroll
      for (int r = 0; r < 4; ++r) {
        uint32_t u = preg[it * 4 + r];
        strip[g * 4 + r][wave * 32 + lid] = upk_lo(u) * invr[r];
        strip[g * 4 + r][wave * 32 + 16 + lid] = upk_hi(u) * invr[r];
      }
    }
    __syncthreads();
    int col = it * 128 + c8;
    if (rowok) {
#pragma unroll
      for (int pr = 0; pr < 4; ++pr) {
        int cc = c8 + pr * 2;
        if (col + pr * 2 + 1 < NW_) {
          float2 o2 = make_float2(strip[orow][cc], strip[orow][cc + 1]);
          *reinterpret_cast<float2*>(OP + rowb + col + pr * 2) = o2;
        }
      }
    }
    if (act) {
      bf16 st[4][8];
#pragma unroll
      for (int mg = 0; mg < 4; ++mg)
#pragma unroll
        for (int e = 0; e < 8; ++e)
          st[mg][e] = vpb[(size_t)(m0 + mg * 8 + e) * 64 + lane];
#pragma unroll
      for (int mg = 0; mg < 4; ++mg)
        *reinterpret_cast<bf16x8*>(&vt[wave][lane][mg * 8]) = *reinterpret_cast<const bf16x8*>(st[mg]);
      bf16x8 af;
#pragma unroll
      for (int e = 0; e < 8; ++e) af[e] = (bf16)strip[lid][wave * 32 + g * 8 + e];
#pragma unroll
      for (int dg = 0; dg < 4; ++dg) {
        bf16x8 bv8 = *reinterpret_cast<const bf16x8*>(&vt[wave][dg * 16 + lid][g * 8]);
        vacc[dg] = __builtin_amdgcn_mfma_f32_16x16x32_bf16(af, bv8, vacc[dg], 0, 0, 0);
      }
    }
    __syncthreads();
  }
#pragma unroll
  for (int dg = 0; dg < 4; ++dg)
#pragma unroll
    for (int r = 0; r < 4; ++r)
      vred[wave][g * 4 + r][dg * 16 + lid] = vacc[dg][r];
  __syncthreads();
  float* ob = OV + (((size_t)b * 16 + 8 + h) * L_) * 64;
  for (int idx = t; idx < 1024; idx += 256) {
    int r = idx >> 6, d = idx & 63;
    int qr = q0 + r;
    if (qr < L_)
      ob[(size_t)qr * 64 + d] = vred[0][r][d] + vred[1][r][d] + vred[2][r][d] + vred[3][r][d];
  }
}

extern "C" void kernel_launch(void* const* d_in, const int* in_sizes, int n_in,
                              void* d_out, int out_size, void* d_ws, size_t ws_size,
                              hipStream_t stream) {
  (void)in_sizes; (void)n_in; (void)out_size; (void)ws_size;
  const float* x    = (const float*)d_in[0];
  const float* mask = (const float*)d_in[1];
  const float* Wq   = (const float*)d_in[2];
  const float* bq   = (const float*)d_in[3];
  const float* Wk   = (const float*)d_in[4];
  const float* bk   = (const float*)d_in[5];
  const float* Wv   = (const float*)d_in[6];
  const float* bv   = (const float*)d_in[7];

  char* ws = (char*)d_ws;
  bf16* qbb     = (bf16*)(ws + 0);            // 8,380,416
  bf16* kgb     = (bf16*)(ws + 8380416);      // 4,194,304
  bf16* vgb     = (bf16*)(ws + 12574720);     // 4,194,304 (row-major V)
  bf16* klb     = (bf16*)(ws + 16769024);     // 1,441,792
  bf16* vlb     = (bf16*)(ws + 18210816);     // 1,441,792
  uint64_t* gm  = (uint64_t*)(ws + 19652608); // 1,047,552
  uint64_t* wm  = (uint64_t*)(ws + 20700160); // 360,096
  bf16* xbb     = (bf16*)(ws + 21060256);     // 8,380,416 (x in bf16)
  bf16* wqb     = (bf16*)(ws + 29440672);     // 2,097,152 (Wq in bf16)

  float* out    = (float*)d_out;
  float* o_vall = out;                 // (2,16,2046,64)
  float* o_pg   = out + 4190208;       // (2,8,2046,2046)
  float* o_pl   = out + 71168064;      // (2,8,2046,682)

  cast4<<<4092, 256, 0, stream>>>(x, xbb, 4190208);
  cast4<<<1024, 256, 0, stream>>>(Wq, wqb, 1048576);
  qgemm_t<<<dim3(64, 8), 256, 0, stream>>>(xbb, wqb, bq, qbb);
  proj_g32<<<dim3(32, 16), 256, 0, stream>>>(x, Wk, bk, Wv, bv, kgb, vgb);
  proj_l32<<<dim3(11, 16), 256, 0, stream>>>(x, Wk, bk, Wv, bv, klb, vlb);
  maskprep<<<1023, 256, 0, stream>>>(mask, gm, wm);

  attn_gf<<<dim3(128, 16), 256, 0, stream>>>(qbb, kgb, vgb, gm, o_pg, o_vall);
  attn_lf<<<dim3(128, 16), 256, 0, stream>>>(qbb, klb, vlb, wm, o_pl, o_vall);
}

// Round 12
// 434.843 us; speedup vs baseline: 17.2436x; 1.0495x over previous
//
#include <hip/hip_runtime.h>
#include <hip/hip_bf16.h>
#include <stdint.h>

typedef __bf16 bf16;
typedef bf16 bf16x8 __attribute__((ext_vector_type(8)));
typedef float f32x4 __attribute__((ext_vector_type(4)));

#define B_ 2
#define L_ 2046
#define H_ 16
#define NW_ 682
#define LP_ 2048
#define NWP_ 704
#define M_ (B_*L_)
#define SCALE_ 0.125f

__device__ inline bf16x8 zf8() {
  bf16x8 v;
#pragma unroll
  for (int e = 0; e < 8; ++e) v[e] = (bf16)0.0f;
  return v;
}

__device__ inline uint32_t pkbf(float a, float b) {
  uint16_t ua = __builtin_bit_cast(uint16_t, (bf16)a);
  uint16_t ub = __builtin_bit_cast(uint16_t, (bf16)b);
  return (uint32_t)ua | ((uint32_t)ub << 16);
}
__device__ inline float upk_lo(uint32_t u) { return __builtin_bit_cast(float, u << 16); }
__device__ inline float upk_hi(uint32_t u) { return __builtin_bit_cast(float, u & 0xffff0000u); }

// ---------------- cast f32 -> bf16 (vectorized x4) ----------------
__global__ __launch_bounds__(256) void cast4(const float* __restrict__ in,
                                             bf16* __restrict__ out, int n) {
  int i = (blockIdx.x * 256 + threadIdx.x) * 4;
  if (i + 3 < n) {
    float4 v = *reinterpret_cast<const float4*>(in + i);
    bf16 tmp[4];
    tmp[0] = (bf16)v.x; tmp[1] = (bf16)v.y; tmp[2] = (bf16)v.z; tmp[3] = (bf16)v.w;
    *reinterpret_cast<uint64_t*>(out + i) = *reinterpret_cast<const uint64_t*>(tmp);
  } else {
    for (; i < n; ++i) out[i] = (bf16)in[i];
  }
}

// ---------------- q = x @ Wq^T + bq : LDS-tiled MFMA GEMM (64x128 tile, BK=32) ----------------
__global__ __launch_bounds__(256) void qgemm_t(const bf16* __restrict__ X,
                                               const bf16* __restrict__ W,
                                               const float* __restrict__ bq,
                                               bf16* __restrict__ Q) {
  __shared__ bf16 As[64 * 40];    // [row][k] rows padded to 40 bf16 (80B)
  __shared__ bf16 Bs[128 * 40];
  int t = threadIdx.x, lane = t & 63, w = t >> 6;
  int lid = lane & 15, g = lane >> 4;
  int m0 = blockIdx.x * 64, n0 = blockIdx.y * 128;
  int wm = (w >> 1) * 32, wn = (w & 1) * 64;
  f32x4 z4 = {0.f, 0.f, 0.f, 0.f};
  f32x4 acc[2][4];
#pragma unroll
  for (int mi = 0; mi < 2; ++mi)
#pragma unroll
    for (int ni = 0; ni < 4; ++ni) acc[mi][ni] = z4;
  int r1 = t >> 2, c1 = t & 3;    // staging: row = r1 (0..63), 8-elem chunk c1 (0..3)
  for (int k0 = 0; k0 < 1024; k0 += 32) {
    int ga = m0 + r1; if (ga >= M_) ga = M_ - 1;
    bf16x8 av = *reinterpret_cast<const bf16x8*>(X + (size_t)ga * 1024 + k0 + c1 * 8);
    bf16x8 bv1 = *reinterpret_cast<const bf16x8*>(W + (size_t)(n0 + r1) * 1024 + k0 + c1 * 8);
    bf16x8 bv2 = *reinterpret_cast<const bf16x8*>(W + (size_t)(n0 + 64 + r1) * 1024 + k0 + c1 * 8);
    __syncthreads();   // previous tile fully consumed
    *reinterpret_cast<bf16x8*>(As + r1 * 40 + c1 * 8) = av;
    *reinterpret_cast<bf16x8*>(Bs + r1 * 40 + c1 * 8) = bv1;
    *reinterpret_cast<bf16x8*>(Bs + (64 + r1) * 40 + c1 * 8) = bv2;
    __syncthreads();
    bf16x8 af[2], bfr[4];
#pragma unroll
    for (int mi = 0; mi < 2; ++mi)
      af[mi] = *reinterpret_cast<const bf16x8*>(As + (wm + mi * 16 + lid) * 40 + g * 8);
#pragma unroll
    for (int ni = 0; ni < 4; ++ni)
      bfr[ni] = *reinterpret_cast<const bf16x8*>(Bs + (wn + ni * 16 + lid) * 40 + g * 8);
#pragma unroll
    for (int mi = 0; mi < 2; ++mi)
#pragma unroll
      for (int ni = 0; ni < 4; ++ni)
        acc[mi][ni] = __builtin_amdgcn_mfma_f32_16x16x32_bf16(af[mi], bfr[ni], acc[mi][ni], 0, 0, 0);
  }
  float bias[4];
#pragma unroll
  for (int ni = 0; ni < 4; ++ni) bias[ni] = bq[n0 + wn + ni * 16 + lid];
#pragma unroll
  for (int mi = 0; mi < 2; ++mi)
#pragma unroll
    for (int r = 0; r < 4; ++r) {
      int row = m0 + wm + mi * 16 + g * 4 + r;
      if (row < M_) {
#pragma unroll
        for (int ni = 0; ni < 4; ++ni)
          Q[(size_t)row * 1024 + n0 + wn + ni * 16 + lid] = (bf16)(acc[mi][ni][r] + bias[ni]);
      }
    }
}

// ---------------- global-head K/V projections (f32 math, bf16 row-major out) ----------------
__global__ __launch_bounds__(256) void proj_g32(const float* __restrict__ x,
    const float* __restrict__ Wk, const float* __restrict__ bk,
    const float* __restrict__ Wv, const float* __restrict__ bv,
    bf16* __restrict__ KGP, bf16* __restrict__ VGP) {
  __shared__ float xs[64][64];
  __shared__ float wks[64][65];
  __shared__ float wvs[64][65];
  int t = threadIdx.x;
  int lb = blockIdx.x, bh = blockIdx.y;
  int b = bh >> 3, h = bh & 7;
  int l0 = lb * 64;
  for (int idx = t; idx < 4096; idx += 256) {
    int r = idx >> 6, c = idx & 63;
    int l = l0 + r;
    xs[r][c] = (l < L_) ? x[((size_t)b * L_ + l) * 1024 + h * 64 + c] : 0.0f;
    wks[r][c] = Wk[(size_t)h * 4096 + idx];
    wvs[r][c] = Wv[(size_t)h * 4096 + idx];
  }
  __syncthreads();
  int o = t & 63, lg = t >> 6;
  float kbias = bk[h * 64 + o], vbias = bv[h * 64 + o];
  const size_t outb = (size_t)bh * LP_ * 64;
  for (int ls = 0; ls < 16; ++ls) {
    int l = lg * 16 + ls;
    float ka = kbias, va = vbias;
#pragma unroll
    for (int i = 0; i < 64; ++i) {
      float xv = xs[l][i];
      ka = fmaf(xv, wks[o][i], ka);
      va = fmaf(xv, wvs[o][i], va);
    }
    KGP[outb + (size_t)(l0 + l) * 64 + o] = (bf16)ka;
    VGP[outb + (size_t)(l0 + l) * 64 + o] = (bf16)va;
  }
}

// ---------------- local-head window-avg + K/V projections (f32 math, bf16 out) ----------------
__global__ __launch_bounds__(256) void proj_l32(const float* __restrict__ x,
    const float* __restrict__ Wk, const float* __restrict__ bk,
    const float* __restrict__ Wv, const float* __restrict__ bv,
    bf16* __restrict__ KLP, bf16* __restrict__ VLP) {
  __shared__ float xs[64][64];
  __shared__ float wks[64][65];
  __shared__ float wvs[64][65];
  int t = threadIdx.x;
  int nb = blockIdx.x, bh = blockIdx.y;
  int b = bh >> 3, h = bh & 7;
  int n0 = nb * 64;
  int hh = 8 + h;
  for (int idx = t; idx < 4096; idx += 256) {
    int r = idx >> 6, c = idx & 63;
    int n = n0 + r;
    float v = 0.0f;
    if (n < NW_) {
      size_t base = ((size_t)b * L_ + 3 * n) * 1024 + hh * 64 + c;
      v = (x[base] + x[base + 1024] + x[base + 2048]) * (1.0f / 3.0f);
    }
    xs[r][c] = v;
    wks[r][c] = Wk[(size_t)hh * 4096 + idx];
    wvs[r][c] = Wv[(size_t)hh * 4096 + idx];
  }
  __syncthreads();
  int o = t & 63, lg = t >> 6;
  float kbias = bk[hh * 64 + o], vbias = bv[hh * 64 + o];
  const size_t outb = (size_t)bh * NWP_ * 64;
  for (int ls = 0; ls < 16; ++ls) {
    int l = lg * 16 + ls;
    float ka = kbias, va = vbias;
#pragma unroll
    for (int i = 0; i < 64; ++i) {
      float xv = xs[l][i];
      ka = fmaf(xv, wks[o][i], ka);
      va = fmaf(xv, wvs[o][i], va);
    }
    KLP[outb + (size_t)(n0 + l) * 64 + o] = (bf16)ka;
    VLP[outb + (size_t)(n0 + l) * 64 + o] = (bf16)va;
  }
}

// ---------------- mask precompute: bit-packed (1 = masked) — R3-verified ----------------
__global__ __launch_bounds__(256) void maskprep(const float* __restrict__ mask,
                                                uint64_t* __restrict__ gm,
                                                uint64_t* __restrict__ wm) {
  int row = blockIdx.x * 4 + (threadIdx.x >> 6);  // b*L + l
  int lane = threadIdx.x & 63;
  if (row >= B_ * L_) return;
  int b = row / L_, l = row % L_;
  const float* mr = mask + (size_t)b * L_ * L_ + (size_t)l * L_;
  for (int w = 0; w < 32; ++w) {
    int m = w * 64 + lane;
    bool masked = (m >= L_) ? true : (mr[m] == 0.0f);
    uint64_t bal = __ballot(masked);
    if (lane == 0) gm[(size_t)row * 32 + w] = bal;
  }
  for (int w = 0; w < 11; ++w) {
    int n = w * 64 + lane;
    bool lmask = true;
    if (n < NW_) {
      float s = mr[3 * n] + mr[3 * n + 1] + mr[3 * n + 2];
      lmask = !(s >= 2.0f);
    }
    uint64_t bal = __ballot(lmask);
    if (lane == 0) wm[(size_t)row * 11 + w] = bal;
  }
}

// ---------------- FUSED global: QK^T -> softmax -> pg write + PV -> value ----------------
// LDS: strip 8.25K + vt 17.4K + sums 0.25K ~= 26K; OV reduce reuses strip.
__global__ __launch_bounds__(256) void attn_gf(const bf16* __restrict__ Q,
    const bf16* __restrict__ K, const bf16* __restrict__ V,
    const uint64_t* __restrict__ GM,
    float* __restrict__ OP, float* __restrict__ OV) {
  __shared__ float sums[64];
  __shared__ float strip[16][129];    // normalized P chunk (16 q-rows x 128 cols)
  __shared__ bf16 vt[64][136];        // shared V^T tile: [d][m_local 0..127]
  int t = threadIdx.x;
  int lane = t & 63, wave = t >> 6;
  int lid = lane & 15, g = lane >> 4;
  int q0 = blockIdx.x * 16;
  int bh = blockIdx.y;
  int b = bh >> 3, h = bh & 7;
  const bf16* qb = Q + (size_t)b * L_ * 1024 + h * 64;
  const bf16* kb = K + (size_t)bh * LP_ * 64;
  const bf16* vpb = V + (size_t)bh * LP_ * 64;
  const uint64_t* gmb = GM + (size_t)b * L_ * 32;

  bf16x8 aq0 = zf8(), aq1 = zf8();
  {
    int qr = q0 + lid;
    if (qr < L_) {
      aq0 = *reinterpret_cast<const bf16x8*>(qb + (size_t)qr * 1024 + g * 8);
      aq1 = *reinterpret_cast<const bf16x8*>(qb + (size_t)qr * 1024 + 32 + g * 8);
    }
  }
  // ---- phase 1: single-pass QK^T, P in registers (R8-verified) ----
  uint32_t preg[64];            // [it(16)][r(4)] packed (tt0, tt1) bf16 pair
  float rs[4] = {0.f, 0.f, 0.f, 0.f};
#pragma unroll
  for (int it = 0; it < 16; ++it) {
    int p = it * 4 + wave;
    int c0 = p * 32;
    int col0 = c0 + lid, col1 = c0 + 16 + lid;
    bf16x8 bka0 = *reinterpret_cast<const bf16x8*>(kb + (size_t)col0 * 64 + g * 8);
    bf16x8 bka1 = *reinterpret_cast<const bf16x8*>(kb + (size_t)col0 * 64 + 32 + g * 8);
    bf16x8 bkb0 = *reinterpret_cast<const bf16x8*>(kb + (size_t)col1 * 64 + g * 8);
    bf16x8 bkb1 = *reinterpret_cast<const bf16x8*>(kb + (size_t)col1 * 64 + 32 + g * 8);
    f32x4 acc0 = {0.f, 0.f, 0.f, 0.f}, acc1 = {0.f, 0.f, 0.f, 0.f};
    acc0 = __builtin_amdgcn_mfma_f32_16x16x32_bf16(aq0, bka0, acc0, 0, 0, 0);
    acc0 = __builtin_amdgcn_mfma_f32_16x16x32_bf16(aq1, bka1, acc0, 0, 0, 0);
    acc1 = __builtin_amdgcn_mfma_f32_16x16x32_bf16(aq0, bkb0, acc1, 0, 0, 0);
    acc1 = __builtin_amdgcn_mfma_f32_16x16x32_bf16(aq1, bkb1, acc1, 0, 0, 0);
    int wi = c0 >> 6;
    int bit0 = c0 & 32;
#pragma unroll
    for (int r = 0; r < 4; ++r) {
      int qr = q0 + g * 4 + r;
      uint64_t w = (qr < L_) ? gmb[(size_t)qr * 32 + wi] : ~0ull;
      float pv0 = ((w >> (bit0 + lid)) & 1) ? 0.0f : __expf(acc0[r] * SCALE_);
      float pv1 = ((w >> (bit0 + 16 + lid)) & 1) ? 0.0f : __expf(acc1[r] * SCALE_);
      rs[r] += pv0 + pv1;
      preg[it * 4 + r] = pkbf(pv0, pv1);
    }
  }
#pragma unroll
  for (int off = 8; off >= 1; off >>= 1)
#pragma unroll
    for (int r = 0; r < 4; ++r) rs[r] += __shfl_xor(rs[r], off, 64);
  if (lid == 0) {
#pragma unroll
    for (int r = 0; r < 4; ++r) sums[wave * 16 + g * 4 + r] = rs[r];
  }
  __syncthreads();
  float invr[4];
#pragma unroll
  for (int r = 0; r < 4; ++r) {
    int row = g * 4 + r;
    float s = sums[row] + sums[16 + row] + sums[32 + row] + sums[48 + row];
    invr[r] = (s > 0.f) ? 1.0f / s : 0.0f;
  }
  // ---- phase 2: per 16x128 chunk: strip -> pg store + fused PV (shared vt) ----
  int orow = t >> 4;            // 0..15
  int qrT = q0 + orow;
  bool rowok = (qrT < L_);
  const size_t rowb = (size_t)bh * L_ * L_ + (size_t)(rowok ? qrT : 0) * L_;
  int c8 = (t & 15) * 8;
  int sd = t & 63, mq = t >> 6; // staging: d = sd, row-octet mq
  f32x4 vacc[4];
  f32x4 z4 = {0.f, 0.f, 0.f, 0.f};
#pragma unroll
  for (int dg = 0; dg < 4; ++dg) vacc[dg] = z4;
#pragma unroll
  for (int it = 0; it < 16; ++it) {
    int mb0 = it * 128;
    // normalized strip write (own preg)
#pragma unroll
    for (int r = 0; r < 4; ++r) {
      uint32_t u = preg[it * 4 + r];
      strip[g * 4 + r][wave * 32 + lid] = upk_lo(u) * invr[r];
      strip[g * 4 + r][wave * 32 + 16 + lid] = upk_hi(u) * invr[r];
    }
    // cooperative V^T stage: 128 rows x 64 d
#pragma unroll
    for (int blk = 0; blk < 4; ++blk) {
      bf16 st[8];
#pragma unroll
      for (int e = 0; e < 8; ++e)
        st[e] = vpb[(size_t)(mb0 + blk * 32 + mq * 8 + e) * 64 + sd];
      *reinterpret_cast<bf16x8*>(&vt[sd][blk * 32 + mq * 8]) = *reinterpret_cast<const bf16x8*>(st);
    }
    __syncthreads();
    // coalesced pg store (8 floats/thread)
    int col = mb0 + c8;
    if (rowok) {
#pragma unroll
      for (int pr = 0; pr < 4; ++pr) {
        int cc = c8 + pr * 2;
        if (col + pr * 2 + 1 < L_) {
          float2 o2 = make_float2(strip[orow][cc], strip[orow][cc + 1]);
          *reinterpret_cast<float2*>(OP + rowb + col + pr * 2) = o2;
        }
      }
    }
    // PV: own-wave 32-col m-chunk
    bf16x8 af;
#pragma unroll
    for (int e = 0; e < 8; ++e) af[e] = (bf16)strip[lid][wave * 32 + g * 8 + e];
#pragma unroll
    for (int dg = 0; dg < 4; ++dg) {
      bf16x8 bv8 = *reinterpret_cast<const bf16x8*>(&vt[dg * 16 + lid][wave * 32 + g * 8]);
      vacc[dg] = __builtin_amdgcn_mfma_f32_16x16x32_bf16(af, bv8, vacc[dg], 0, 0, 0);
    }
    __syncthreads();
  }
  // ---- cross-wave OV reduce via strip (serialized adds) ----
#pragma unroll
  for (int wsel = 0; wsel < 4; ++wsel) {
    if (wave == wsel) {
#pragma unroll
      for (int dg = 0; dg < 4; ++dg)
#pragma unroll
        for (int r = 0; r < 4; ++r) {
          if (wsel == 0) strip[g * 4 + r][dg * 16 + lid] = vacc[dg][r];
          else           strip[g * 4 + r][dg * 16 + lid] += vacc[dg][r];
        }
    }
    __syncthreads();
  }
  float* ob = OV + (((size_t)b * 16 + h) * L_) * 64;
  for (int idx = t; idx < 1024; idx += 256) {
    int r = idx >> 6, d = idx & 63;
    int qr = q0 + r;
    if (qr < L_) ob[(size_t)qr * 64 + d] = strip[r][d];
  }
}

// ---------------- FUSED local: QK^T -> softmax -> pl write + PV -> value ----------------
__global__ __launch_bounds__(256) void attn_lf(const bf16* __restrict__ Q,
    const bf16* __restrict__ K, const bf16* __restrict__ V,
    const uint64_t* __restrict__ WM,
    float* __restrict__ OP, float* __restrict__ OV) {
  __shared__ float sums[64];
  __shared__ float strip[16][129];
  __shared__ bf16 vt[64][136];
  int t = threadIdx.x;
  int lane = t & 63, wave = t >> 6;
  int lid = lane & 15, g = lane >> 4;
  int q0 = blockIdx.x * 16;
  int bh = blockIdx.y;
  int b = bh >> 3, h = bh & 7;
  const bf16* qb = Q + (size_t)b * L_ * 1024 + (8 + h) * 64;
  const bf16* kb = K + (size_t)bh * NWP_ * 64;
  const bf16* vpb = V + (size_t)bh * NWP_ * 64;
  const uint64_t* wmb = WM + (size_t)b * L_ * 11;

  bf16x8 aq0 = zf8(), aq1 = zf8();
  {
    int qr = q0 + lid;
    if (qr < L_) {
      aq0 = *reinterpret_cast<const bf16x8*>(qb + (size_t)qr * 1024 + g * 8);
      aq1 = *reinterpret_cast<const bf16x8*>(qb + (size_t)qr * 1024 + 32 + g * 8);
    }
  }
  uint32_t preg[24];
  float rs[4] = {0.f, 0.f, 0.f, 0.f};
#pragma unroll
  for (int it = 0; it < 6; ++it) {
    int p = it * 4 + wave;
    if (p < 22) {
      int c0 = p * 32;
      int col0 = c0 + lid, col1 = c0 + 16 + lid;
      bf16x8 bka0 = *reinterpret_cast<const bf16x8*>(kb + (size_t)col0 * 64 + g * 8);
      bf16x8 bka1 = *reinterpret_cast<const bf16x8*>(kb + (size_t)col0 * 64 + 32 + g * 8);
      bf16x8 bkb0 = *reinterpret_cast<const bf16x8*>(kb + (size_t)col1 * 64 + g * 8);
      bf16x8 bkb1 = *reinterpret_cast<const bf16x8*>(kb + (size_t)col1 * 64 + 32 + g * 8);
      f32x4 acc0 = {0.f, 0.f, 0.f, 0.f}, acc1 = {0.f, 0.f, 0.f, 0.f};
      acc0 = __builtin_amdgcn_mfma_f32_16x16x32_bf16(aq0, bka0, acc0, 0, 0, 0);
      acc0 = __builtin_amdgcn_mfma_f32_16x16x32_bf16(aq1, bka1, acc0, 0, 0, 0);
      acc1 = __builtin_amdgcn_mfma_f32_16x16x32_bf16(aq0, bkb0, acc1, 0, 0, 0);
      acc1 = __builtin_amdgcn_mfma_f32_16x16x32_bf16(aq1, bkb1, acc1, 0, 0, 0);
      int wi = c0 >> 6;
      int bit0 = c0 & 32;
#pragma unroll
      for (int r = 0; r < 4; ++r) {
        int qr = q0 + g * 4 + r;
        uint64_t w = (qr < L_) ? wmb[(size_t)qr * 11 + wi] : ~0ull;
        float pv0 = ((w >> (bit0 + lid)) & 1) ? 0.0f : __expf(acc0[r] * SCALE_);
        float pv1 = ((w >> (bit0 + 16 + lid)) & 1) ? 0.0f : __expf(acc1[r] * SCALE_);
        rs[r] += pv0 + pv1;
        preg[it * 4 + r] = pkbf(pv0, pv1);
      }
    }
  }
#pragma unroll
  for (int off = 8; off >= 1; off >>= 1)
#pragma unroll
    for (int r = 0; r < 4; ++r) rs[r] += __shfl_xor(rs[r], off, 64);
  if (lid == 0) {
#pragma unroll
    for (int r = 0; r < 4; ++r) sums[wave * 16 + g * 4 + r] = rs[r];
  }
  __syncthreads();
  float invr[4];
#pragma unroll
  for (int r = 0; r < 4; ++r) {
    int row = g * 4 + r;
    float s = sums[row] + sums[16 + row] + sums[32 + row] + sums[48 + row];
    invr[r] = (s > 0.f) ? 1.0f / s : 0.0f;
  }
  int orow = t >> 4;
  int qrT = q0 + orow;
  bool rowok = (qrT < L_);
  const size_t rowb = (size_t)bh * L_ * NW_ + (size_t)(rowok ? qrT : 0) * NW_;
  int c8 = (t & 15) * 8;
  int sd = t & 63, mq = t >> 6;
  f32x4 vacc[4];
  f32x4 z4 = {0.f, 0.f, 0.f, 0.f};
#pragma unroll
  for (int dg = 0; dg < 4; ++dg) vacc[dg] = z4;
#pragma unroll
  for (int it = 0; it < 6; ++it) {
    int p = it * 4 + wave;
    bool act = (p < 22);
    int mb0 = it * 128;
    if (act) {
#pragma unroll
      for (int r = 0; r < 4; ++r) {
        uint32_t u = preg[it * 4 + r];
        strip[g * 4 + r][wave * 32 + lid] = upk_lo(u) * invr[r];
        strip[g * 4 + r][wave * 32 + 16 + lid] = upk_hi(u) * invr[r];
      }
    }
    // cooperative V^T stage (rows clamped to NWP_; masked cols have P=0)
#pragma unroll
    for (int blk = 0; blk < 4; ++blk) {
      bf16 st[8];
#pragma unroll
      for (int e = 0; e < 8; ++e) {
        int m = mb0 + blk * 32 + mq * 8 + e;
        if (m >= NWP_) m = NWP_ - 1;
        st[e] = vpb[(size_t)m * 64 + sd];
      }
      *reinterpret_cast<bf16x8*>(&vt[sd][blk * 32 + mq * 8]) = *reinterpret_cast<const bf16x8*>(st);
    }
    __syncthreads();
    int col = mb0 + c8;
    if (rowok) {
#pragma unroll
      for (int pr = 0; pr < 4; ++pr) {
        int cc = c8 + pr * 2;
        if (col + pr * 2 + 1 < NW_) {
          float2 o2 = make_float2(strip[orow][cc], strip[orow][cc + 1]);
          *reinterpret_cast<float2*>(OP + rowb + col + pr * 2) = o2;
        }
      }
    }
    if (act) {
      bf16x8 af;
#pragma unroll
      for (int e = 0; e < 8; ++e) af[e] = (bf16)strip[lid][wave * 32 + g * 8 + e];
#pragma unroll
      for (int dg = 0; dg < 4; ++dg) {
        bf16x8 bv8 = *reinterpret_cast<const bf16x8*>(&vt[dg * 16 + lid][wave * 32 + g * 8]);
        vacc[dg] = __builtin_amdgcn_mfma_f32_16x16x32_bf16(af, bv8, vacc[dg], 0, 0, 0);
      }
    }
    __syncthreads();
  }
#pragma unroll
  for (int wsel = 0; wsel < 4; ++wsel) {
    if (wave == wsel) {
#pragma unroll
      for (int dg = 0; dg < 4; ++dg)
#pragma unroll
        for (int r = 0; r < 4; ++r) {
          if (wsel == 0) strip[g * 4 + r][dg * 16 + lid] = vacc[dg][r];
          else           strip[g * 4 + r][dg * 16 + lid] += vacc[dg][r];
        }
    }
    __syncthreads();
  }
  float* ob = OV + (((size_t)b * 16 + 8 + h) * L_) * 64;
  for (int idx = t; idx < 1024; idx += 256) {
    int r = idx >> 6, d = idx & 63;
    int qr = q0 + r;
    if (qr < L_) ob[(size_t)qr * 64 + d] = strip[r][d];
  }
}

extern "C" void kernel_launch(void* const* d_in, const int* in_sizes, int n_in,
                              void* d_out, int out_size, void* d_ws, size_t ws_size,
                              hipStream_t stream) {
  (void)in_sizes; (void)n_in; (void)out_size; (void)ws_size;
  const float* x    = (const float*)d_in[0];
  const float* mask = (const float*)d_in[1];
  const float* Wq   = (const float*)d_in[2];
  const float* bq   = (const float*)d_in[3];
  const float* Wk   = (const float*)d_in[4];
  const float* bk   = (const float*)d_in[5];
  const float* Wv   = (const float*)d_in[6];
  const float* bv   = (const float*)d_in[7];

  char* ws = (char*)d_ws;
  bf16* qbb     = (bf16*)(ws + 0);            // 8,380,416
  bf16* kgb     = (bf16*)(ws + 8380416);      // 4,194,304
  bf16* vgb     = (bf16*)(ws + 12574720);     // 4,194,304 (row-major V)
  bf16* klb     = (bf16*)(ws + 16769024);     // 1,441,792
  bf16* vlb     = (bf16*)(ws + 18210816);     // 1,441,792
  uint64_t* gm  = (uint64_t*)(ws + 19652608); // 1,047,552
  uint64_t* wm  = (uint64_t*)(ws + 20700160); // 360,096
  bf16* xbb     = (bf16*)(ws + 21060256);     // 8,380,416 (x in bf16)
  bf16* wqb     = (bf16*)(ws + 29440672);     // 2,097,152 (Wq in bf16)

  float* out    = (float*)d_out;
  float* o_vall = out;                 // (2,16,2046,64)
  float* o_pg   = out + 4190208;       // (2,8,2046,2046)
  float* o_pl   = out + 71168064;      // (2,8,2046,682)

  cast4<<<4092, 256, 0, stream>>>(x, xbb, 4190208);
  cast4<<<1024, 256, 0, stream>>>(Wq, wqb, 1048576);
  qgemm_t<<<dim3(64, 8), 256, 0, stream>>>(xbb, wqb, bq, qbb);
  proj_g32<<<dim3(32, 16), 256, 0, stream>>>(x, Wk, bk, Wv, bv, kgb, vgb);
  proj_l32<<<dim3(11, 16), 256, 0, stream>>>(x, Wk, bk, Wv, bv, klb, vlb);
  maskprep<<<1023, 256, 0, stream>>>(mask, gm, wm);

  attn_gf<<<dim3(128, 16), 256, 0, stream>>>(qbb, kgb, vgb, gm, o_pg, o_vall);
  attn_lf<<<dim3(128, 16), 256, 0, stream>>>(qbb, klb, vlb, wm, o_pl, o_vall);
}

// Round 13
// 396.597 us; speedup vs baseline: 18.9065x; 1.0964x over previous
//
#include <hip/hip_runtime.h>
#include <hip/hip_bf16.h>
#include <stdint.h>

typedef __bf16 bf16;
typedef bf16 bf16x8 __attribute__((ext_vector_type(8)));
typedef float f32x4 __attribute__((ext_vector_type(4)));

#define B_ 2
#define L_ 2046
#define H_ 16
#define NW_ 682
#define LP_ 2048
#define NWP_ 704
#define M_ (B_*L_)
#define SCALE_ 0.125f
#define VTP 280   // vt row stride (bf16): 560B rows, 16B-aligned, ~2-way banks

__device__ inline bf16x8 zf8() {
  bf16x8 v;
#pragma unroll
  for (int e = 0; e < 8; ++e) v[e] = (bf16)0.0f;
  return v;
}

__device__ inline uint32_t pkbf(float a, float b) {
  uint16_t ua = __builtin_bit_cast(uint16_t, (bf16)a);
  uint16_t ub = __builtin_bit_cast(uint16_t, (bf16)b);
  return (uint32_t)ua | ((uint32_t)ub << 16);
}
__device__ inline float upk_lo(uint32_t u) { return __builtin_bit_cast(float, u << 16); }
__device__ inline float upk_hi(uint32_t u) { return __builtin_bit_cast(float, u & 0xffff0000u); }

// ---------------- cast f32 -> bf16 (vectorized x4) ----------------
__global__ __launch_bounds__(256) void cast4(const float* __restrict__ in,
                                             bf16* __restrict__ out, int n) {
  int i = (blockIdx.x * 256 + threadIdx.x) * 4;
  if (i + 3 < n) {
    float4 v = *reinterpret_cast<const float4*>(in + i);
    bf16 tmp[4];
    tmp[0] = (bf16)v.x; tmp[1] = (bf16)v.y; tmp[2] = (bf16)v.z; tmp[3] = (bf16)v.w;
    *reinterpret_cast<uint64_t*>(out + i) = *reinterpret_cast<const uint64_t*>(tmp);
  } else {
    for (; i < n; ++i) out[i] = (bf16)in[i];
  }
}

// ---------------- q = x @ Wq^T + bq : LDS-tiled MFMA GEMM (64x128 tile, BK=32) ----------------
__global__ __launch_bounds__(256) void qgemm_t(const bf16* __restrict__ X,
                                               const bf16* __restrict__ W,
                                               const float* __restrict__ bq,
                                               bf16* __restrict__ Q) {
  __shared__ bf16 As[64 * 40];    // [row][k] rows padded to 40 bf16 (80B)
  __shared__ bf16 Bs[128 * 40];
  int t = threadIdx.x, lane = t & 63, w = t >> 6;
  int lid = lane & 15, g = lane >> 4;
  int m0 = blockIdx.x * 64, n0 = blockIdx.y * 128;
  int wm = (w >> 1) * 32, wn = (w & 1) * 64;
  f32x4 z4 = {0.f, 0.f, 0.f, 0.f};
  f32x4 acc[2][4];
#pragma unroll
  for (int mi = 0; mi < 2; ++mi)
#pragma unroll
    for (int ni = 0; ni < 4; ++ni) acc[mi][ni] = z4;
  int r1 = t >> 2, c1 = t & 3;    // staging: row = r1 (0..63), 8-elem chunk c1 (0..3)
  for (int k0 = 0; k0 < 1024; k0 += 32) {
    int ga = m0 + r1; if (ga >= M_) ga = M_ - 1;
    bf16x8 av = *reinterpret_cast<const bf16x8*>(X + (size_t)ga * 1024 + k0 + c1 * 8);
    bf16x8 bv1 = *reinterpret_cast<const bf16x8*>(W + (size_t)(n0 + r1) * 1024 + k0 + c1 * 8);
    bf16x8 bv2 = *reinterpret_cast<const bf16x8*>(W + (size_t)(n0 + 64 + r1) * 1024 + k0 + c1 * 8);
    __syncthreads();   // previous tile fully consumed
    *reinterpret_cast<bf16x8*>(As + r1 * 40 + c1 * 8) = av;
    *reinterpret_cast<bf16x8*>(Bs + r1 * 40 + c1 * 8) = bv1;
    *reinterpret_cast<bf16x8*>(Bs + (64 + r1) * 40 + c1 * 8) = bv2;
    __syncthreads();
    bf16x8 af[2], bfr[4];
#pragma unroll
    for (int mi = 0; mi < 2; ++mi)
      af[mi] = *reinterpret_cast<const bf16x8*>(As + (wm + mi * 16 + lid) * 40 + g * 8);
#pragma unroll
    for (int ni = 0; ni < 4; ++ni)
      bfr[ni] = *reinterpret_cast<const bf16x8*>(Bs + (wn + ni * 16 + lid) * 40 + g * 8);
#pragma unroll
    for (int mi = 0; mi < 2; ++mi)
#pragma unroll
      for (int ni = 0; ni < 4; ++ni)
        acc[mi][ni] = __builtin_amdgcn_mfma_f32_16x16x32_bf16(af[mi], bfr[ni], acc[mi][ni], 0, 0, 0);
  }
  float bias[4];
#pragma unroll
  for (int ni = 0; ni < 4; ++ni) bias[ni] = bq[n0 + wn + ni * 16 + lid];
#pragma unroll
  for (int mi = 0; mi < 2; ++mi)
#pragma unroll
    for (int r = 0; r < 4; ++r) {
      int row = m0 + wm + mi * 16 + g * 4 + r;
      if (row < M_) {
#pragma unroll
        for (int ni = 0; ni < 4; ++ni)
          Q[(size_t)row * 1024 + n0 + wn + ni * 16 + lid] = (bf16)(acc[mi][ni][r] + bias[ni]);
      }
    }
}

// ---------------- global-head K/V projections (f32 math, bf16 row-major out) ----------------
__global__ __launch_bounds__(256) void proj_g32(const float* __restrict__ x,
    const float* __restrict__ Wk, const float* __restrict__ bk,
    const float* __restrict__ Wv, const float* __restrict__ bv,
    bf16* __restrict__ KGP, bf16* __restrict__ VGP) {
  __shared__ float xs[64][64];
  __shared__ float wks[64][65];
  __shared__ float wvs[64][65];
  int t = threadIdx.x;
  int lb = blockIdx.x, bh = blockIdx.y;
  int b = bh >> 3, h = bh & 7;
  int l0 = lb * 64;
  for (int idx = t; idx < 4096; idx += 256) {
    int r = idx >> 6, c = idx & 63;
    int l = l0 + r;
    xs[r][c] = (l < L_) ? x[((size_t)b * L_ + l) * 1024 + h * 64 + c] : 0.0f;
    wks[r][c] = Wk[(size_t)h * 4096 + idx];
    wvs[r][c] = Wv[(size_t)h * 4096 + idx];
  }
  __syncthreads();
  int o = t & 63, lg = t >> 6;
  float kbias = bk[h * 64 + o], vbias = bv[h * 64 + o];
  const size_t outb = (size_t)bh * LP_ * 64;
  for (int ls = 0; ls < 16; ++ls) {
    int l = lg * 16 + ls;
    float ka = kbias, va = vbias;
#pragma unroll
    for (int i = 0; i < 64; ++i) {
      float xv = xs[l][i];
      ka = fmaf(xv, wks[o][i], ka);
      va = fmaf(xv, wvs[o][i], va);
    }
    KGP[outb + (size_t)(l0 + l) * 64 + o] = (bf16)ka;
    VGP[outb + (size_t)(l0 + l) * 64 + o] = (bf16)va;
  }
}

// ---------------- local-head window-avg + K/V projections (f32 math, bf16 out) ----------------
__global__ __launch_bounds__(256) void proj_l32(const float* __restrict__ x,
    const float* __restrict__ Wk, const float* __restrict__ bk,
    const float* __restrict__ Wv, const float* __restrict__ bv,
    bf16* __restrict__ KLP, bf16* __restrict__ VLP) {
  __shared__ float xs[64][64];
  __shared__ float wks[64][65];
  __shared__ float wvs[64][65];
  int t = threadIdx.x;
  int nb = blockIdx.x, bh = blockIdx.y;
  int b = bh >> 3, h = bh & 7;
  int n0 = nb * 64;
  int hh = 8 + h;
  for (int idx = t; idx < 4096; idx += 256) {
    int r = idx >> 6, c = idx & 63;
    int n = n0 + r;
    float v = 0.0f;
    if (n < NW_) {
      size_t base = ((size_t)b * L_ + 3 * n) * 1024 + hh * 64 + c;
      v = (x[base] + x[base + 1024] + x[base + 2048]) * (1.0f / 3.0f);
    }
    xs[r][c] = v;
    wks[r][c] = Wk[(size_t)hh * 4096 + idx];
    wvs[r][c] = Wv[(size_t)hh * 4096 + idx];
  }
  __syncthreads();
  int o = t & 63, lg = t >> 6;
  float kbias = bk[hh * 64 + o], vbias = bv[hh * 64 + o];
  const size_t outb = (size_t)bh * NWP_ * 64;
  for (int ls = 0; ls < 16; ++ls) {
    int l = lg * 16 + ls;
    float ka = kbias, va = vbias;
#pragma unroll
    for (int i = 0; i < 64; ++i) {
      float xv = xs[l][i];
      ka = fmaf(xv, wks[o][i], ka);
      va = fmaf(xv, wvs[o][i], va);
    }
    KLP[outb + (size_t)(n0 + l) * 64 + o] = (bf16)ka;
    VLP[outb + (size_t)(n0 + l) * 64 + o] = (bf16)va;
  }
}

// ---------------- mask precompute: bit-packed (1 = masked) — R3-verified ----------------
__global__ __launch_bounds__(256) void maskprep(const float* __restrict__ mask,
                                                uint64_t* __restrict__ gm,
                                                uint64_t* __restrict__ wm) {
  int row = blockIdx.x * 4 + (threadIdx.x >> 6);  // b*L + l
  int lane = threadIdx.x & 63;
  if (row >= B_ * L_) return;
  int b = row / L_, l = row % L_;
  const float* mr = mask + (size_t)b * L_ * L_ + (size_t)l * L_;
  for (int w = 0; w < 32; ++w) {
    int m = w * 64 + lane;
    bool masked = (m >= L_) ? true : (mr[m] == 0.0f);
    uint64_t bal = __ballot(masked);
    if (lane == 0) gm[(size_t)row * 32 + w] = bal;
  }
  for (int w = 0; w < 11; ++w) {
    int n = w * 64 + lane;
    bool lmask = true;
    if (n < NW_) {
      float s = mr[3 * n] + mr[3 * n + 1] + mr[3 * n + 2];
      lmask = !(s >= 2.0f);
    }
    uint64_t bal = __ballot(lmask);
    if (lane == 0) wm[(size_t)row * 11 + w] = bal;
  }
}

// ---------------- FUSED global, 8-wave blocks: QK^T -> softmax -> pg + PV -> value ----------------
// LDS: strip 16x257 f32 (16.4K) + vt 64x280 bf16 (35.8K) + sums 0.5K ~= 53K
__global__ __launch_bounds__(512, 4) void attn_gf(const bf16* __restrict__ Q,
    const bf16* __restrict__ K, const bf16* __restrict__ V,
    const uint64_t* __restrict__ GM,
    float* __restrict__ OP, float* __restrict__ OV) {
  __shared__ float sums[128];
  __shared__ float strip[16][257];    // normalized P chunk (16 q-rows x 256 cols)
  __shared__ bf16 vt[64][VTP];        // shared V^T tile: [d][m_local 0..255]
  int t = threadIdx.x;
  int lane = t & 63, wave = t >> 6;   // 8 waves
  int lid = lane & 15, g = lane >> 4;
  int q0 = blockIdx.x * 16;
  int bh = blockIdx.y;
  int b = bh >> 3, h = bh & 7;
  const bf16* qb = Q + (size_t)b * L_ * 1024 + h * 64;
  const bf16* kb = K + (size_t)bh * LP_ * 64;
  const bf16* vpb = V + (size_t)bh * LP_ * 64;
  const uint64_t* gmb = GM + (size_t)b * L_ * 32;

  bf16x8 aq0 = zf8(), aq1 = zf8();
  {
    int qr = q0 + lid;
    if (qr < L_) {
      aq0 = *reinterpret_cast<const bf16x8*>(qb + (size_t)qr * 1024 + g * 8);
      aq1 = *reinterpret_cast<const bf16x8*>(qb + (size_t)qr * 1024 + 32 + g * 8);
    }
  }
  // ---- phase 1: single-pass QK^T, P in registers ----
  uint32_t preg[32];            // [it(8)][r(4)] packed (tt0, tt1) bf16 pair
  float rs[4] = {0.f, 0.f, 0.f, 0.f};
#pragma unroll
  for (int it = 0; it < 8; ++it) {
    int p = it * 8 + wave;
    int c0 = p * 32;
    int col0 = c0 + lid, col1 = c0 + 16 + lid;
    bf16x8 bka0 = *reinterpret_cast<const bf16x8*>(kb + (size_t)col0 * 64 + g * 8);
    bf16x8 bka1 = *reinterpret_cast<const bf16x8*>(kb + (size_t)col0 * 64 + 32 + g * 8);
    bf16x8 bkb0 = *reinterpret_cast<const bf16x8*>(kb + (size_t)col1 * 64 + g * 8);
    bf16x8 bkb1 = *reinterpret_cast<const bf16x8*>(kb + (size_t)col1 * 64 + 32 + g * 8);
    f32x4 acc0 = {0.f, 0.f, 0.f, 0.f}, acc1 = {0.f, 0.f, 0.f, 0.f};
    acc0 = __builtin_amdgcn_mfma_f32_16x16x32_bf16(aq0, bka0, acc0, 0, 0, 0);
    acc0 = __builtin_amdgcn_mfma_f32_16x16x32_bf16(aq1, bka1, acc0, 0, 0, 0);
    acc1 = __builtin_amdgcn_mfma_f32_16x16x32_bf16(aq0, bkb0, acc1, 0, 0, 0);
    acc1 = __builtin_amdgcn_mfma_f32_16x16x32_bf16(aq1, bkb1, acc1, 0, 0, 0);
    int wi = c0 >> 6;
    int bit0 = c0 & 32;
#pragma unroll
    for (int r = 0; r < 4; ++r) {
      int qr = q0 + g * 4 + r;
      uint64_t w = (qr < L_) ? gmb[(size_t)qr * 32 + wi] : ~0ull;
      float pv0 = ((w >> (bit0 + lid)) & 1) ? 0.0f : __expf(acc0[r] * SCALE_);
      float pv1 = ((w >> (bit0 + 16 + lid)) & 1) ? 0.0f : __expf(acc1[r] * SCALE_);
      rs[r] += pv0 + pv1;
      preg[it * 4 + r] = pkbf(pv0, pv1);
    }
  }
#pragma unroll
  for (int off = 8; off >= 1; off >>= 1)
#pragma unroll
    for (int r = 0; r < 4; ++r) rs[r] += __shfl_xor(rs[r], off, 64);
  if (lid == 0) {
#pragma unroll
    for (int r = 0; r < 4; ++r) sums[wave * 16 + g * 4 + r] = rs[r];
  }
  __syncthreads();
  float invr[4];
#pragma unroll
  for (int r = 0; r < 4; ++r) {
    int row = g * 4 + r;
    float s = 0.f;
#pragma unroll
    for (int ww = 0; ww < 8; ++ww) s += sums[ww * 16 + row];
    invr[r] = (s > 0.f) ? 1.0f / s : 0.0f;
  }
  // ---- phase 2: per 16x256 chunk: strip -> pg store + fused PV (shared vt) ----
  int orow = t >> 5;            // 0..15
  int qrT = q0 + orow;
  bool rowok = (qrT < L_);
  const size_t rowb = (size_t)bh * L_ * L_ + (size_t)(rowok ? qrT : 0) * L_;
  int c8 = (t & 31) * 8;
  int sd = t & 63, mq = t >> 6; // staging: d = sd, row-octet mq (0..7)
  f32x4 vacc[4];
  f32x4 z4 = {0.f, 0.f, 0.f, 0.f};
#pragma unroll
  for (int dg = 0; dg < 4; ++dg) vacc[dg] = z4;
#pragma unroll
  for (int it = 0; it < 8; ++it) {
    int mb0 = it * 256;
    // normalized strip write (own preg)
#pragma unroll
    for (int r = 0; r < 4; ++r) {
      uint32_t u = preg[it * 4 + r];
      strip[g * 4 + r][wave * 32 + lid] = upk_lo(u) * invr[r];
      strip[g * 4 + r][wave * 32 + 16 + lid] = upk_hi(u) * invr[r];
    }
    // cooperative V^T stage: 256 rows x 64 d
#pragma unroll
    for (int blk = 0; blk < 4; ++blk) {
      bf16 st[8];
#pragma unroll
      for (int e = 0; e < 8; ++e)
        st[e] = vpb[(size_t)(mb0 + blk * 64 + mq * 8 + e) * 64 + sd];
      *reinterpret_cast<bf16x8*>(&vt[sd][blk * 64 + mq * 8]) = *reinterpret_cast<const bf16x8*>(st);
    }
    __syncthreads();
    // coalesced pg store (8 floats/thread)
    int col = mb0 + c8;
    if (rowok) {
#pragma unroll
      for (int pr = 0; pr < 4; ++pr) {
        int cc = c8 + pr * 2;
        if (col + pr * 2 + 1 < L_) {
          float2 o2 = make_float2(strip[orow][cc], strip[orow][cc + 1]);
          *reinterpret_cast<float2*>(OP + rowb + col + pr * 2) = o2;
        }
      }
    }
    // PV: own-wave 32-col m-chunk
    bf16x8 af;
#pragma unroll
    for (int e = 0; e < 8; ++e) af[e] = (bf16)strip[lid][wave * 32 + g * 8 + e];
#pragma unroll
    for (int dg = 0; dg < 4; ++dg) {
      bf16x8 bv8 = *reinterpret_cast<const bf16x8*>(&vt[dg * 16 + lid][wave * 32 + g * 8]);
      vacc[dg] = __builtin_amdgcn_mfma_f32_16x16x32_bf16(af, bv8, vacc[dg], 0, 0, 0);
    }
    __syncthreads();
  }
  // ---- cross-wave OV reduce via strip (serialized adds) ----
#pragma unroll
  for (int wsel = 0; wsel < 8; ++wsel) {
    if (wave == wsel) {
#pragma unroll
      for (int dg = 0; dg < 4; ++dg)
#pragma unroll
        for (int r = 0; r < 4; ++r) {
          if (wsel == 0) strip[g * 4 + r][dg * 16 + lid] = vacc[dg][r];
          else           strip[g * 4 + r][dg * 16 + lid] += vacc[dg][r];
        }
    }
    __syncthreads();
  }
  float* ob = OV + (((size_t)b * 16 + h) * L_) * 64;
  for (int idx = t; idx < 1024; idx += 512) {
    int r = idx >> 6, d = idx & 63;
    int qr = q0 + r;
    if (qr < L_) ob[(size_t)qr * 64 + d] = strip[r][d];
  }
}

// ---------------- FUSED local, 8-wave blocks ----------------
__global__ __launch_bounds__(512, 4) void attn_lf(const bf16* __restrict__ Q,
    const bf16* __restrict__ K, const bf16* __restrict__ V,
    const uint64_t* __restrict__ WM,
    float* __restrict__ OP, float* __restrict__ OV) {
  __shared__ float sums[128];
  __shared__ float strip[16][257];
  __shared__ bf16 vt[64][VTP];
  int t = threadIdx.x;
  int lane = t & 63, wave = t >> 6;
  int lid = lane & 15, g = lane >> 4;
  int q0 = blockIdx.x * 16;
  int bh = blockIdx.y;
  int b = bh >> 3, h = bh & 7;
  const bf16* qb = Q + (size_t)b * L_ * 1024 + (8 + h) * 64;
  const bf16* kb = K + (size_t)bh * NWP_ * 64;
  const bf16* vpb = V + (size_t)bh * NWP_ * 64;
  const uint64_t* wmb = WM + (size_t)b * L_ * 11;

  bf16x8 aq0 = zf8(), aq1 = zf8();
  {
    int qr = q0 + lid;
    if (qr < L_) {
      aq0 = *reinterpret_cast<const bf16x8*>(qb + (size_t)qr * 1024 + g * 8);
      aq1 = *reinterpret_cast<const bf16x8*>(qb + (size_t)qr * 1024 + 32 + g * 8);
    }
  }
  uint32_t preg[12];
  float rs[4] = {0.f, 0.f, 0.f, 0.f};
#pragma unroll
  for (int it = 0; it < 3; ++it) {
    int p = it * 8 + wave;
    if (p < 22) {
      int c0 = p * 32;
      int col0 = c0 + lid, col1 = c0 + 16 + lid;
      bf16x8 bka0 = *reinterpret_cast<const bf16x8*>(kb + (size_t)col0 * 64 + g * 8);
      bf16x8 bka1 = *reinterpret_cast<const bf16x8*>(kb + (size_t)col0 * 64 + 32 + g * 8);
      bf16x8 bkb0 = *reinterpret_cast<const bf16x8*>(kb + (size_t)col1 * 64 + g * 8);
      bf16x8 bkb1 = *reinterpret_cast<const bf16x8*>(kb + (size_t)col1 * 64 + 32 + g * 8);
      f32x4 acc0 = {0.f, 0.f, 0.f, 0.f}, acc1 = {0.f, 0.f, 0.f, 0.f};
      acc0 = __builtin_amdgcn_mfma_f32_16x16x32_bf16(aq0, bka0, acc0, 0, 0, 0);
      acc0 = __builtin_amdgcn_mfma_f32_16x16x32_bf16(aq1, bka1, acc0, 0, 0, 0);
      acc1 = __builtin_amdgcn_mfma_f32_16x16x32_bf16(aq0, bkb0, acc1, 0, 0, 0);
      acc1 = __builtin_amdgcn_mfma_f32_16x16x32_bf16(aq1, bkb1, acc1, 0, 0, 0);
      int wi = c0 >> 6;
      int bit0 = c0 & 32;
#pragma unroll
      for (int r = 0; r < 4; ++r) {
        int qr = q0 + g * 4 + r;
        uint64_t w = (qr < L_) ? wmb[(size_t)qr * 11 + wi] : ~0ull;
        float pv0 = ((w >> (bit0 + lid)) & 1) ? 0.0f : __expf(acc0[r] * SCALE_);
        float pv1 = ((w >> (bit0 + 16 + lid)) & 1) ? 0.0f : __expf(acc1[r] * SCALE_);
        rs[r] += pv0 + pv1;
        preg[it * 4 + r] = pkbf(pv0, pv1);
      }
    }
  }
#pragma unroll
  for (int off = 8; off >= 1; off >>= 1)
#pragma unroll
    for (int r = 0; r < 4; ++r) rs[r] += __shfl_xor(rs[r], off, 64);
  if (lid == 0) {
#pragma unroll
    for (int r = 0; r < 4; ++r) sums[wave * 16 + g * 4 + r] = rs[r];
  }
  __syncthreads();
  float invr[4];
#pragma unroll
  for (int r = 0; r < 4; ++r) {
    int row = g * 4 + r;
    float s = 0.f;
#pragma unroll
    for (int ww = 0; ww < 8; ++ww) s += sums[ww * 16 + row];
    invr[r] = (s > 0.f) ? 1.0f / s : 0.0f;
  }
  int orow = t >> 5;
  int qrT = q0 + orow;
  bool rowok = (qrT < L_);
  const size_t rowb = (size_t)bh * L_ * NW_ + (size_t)(rowok ? qrT : 0) * NW_;
  int c8 = (t & 31) * 8;
  int sd = t & 63, mq = t >> 6;
  f32x4 vacc[4];
  f32x4 z4 = {0.f, 0.f, 0.f, 0.f};
#pragma unroll
  for (int dg = 0; dg < 4; ++dg) vacc[dg] = z4;
#pragma unroll
  for (int it = 0; it < 3; ++it) {
    int p = it * 8 + wave;
    bool act = (p < 22);
    int mb0 = it * 256;
    if (act) {
#pragma unroll
      for (int r = 0; r < 4; ++r) {
        uint32_t u = preg[it * 4 + r];
        strip[g * 4 + r][wave * 32 + lid] = upk_lo(u) * invr[r];
        strip[g * 4 + r][wave * 32 + 16 + lid] = upk_hi(u) * invr[r];
      }
    }
    // cooperative V^T stage (rows clamped to NWP_; masked cols have P=0)
#pragma unroll
    for (int blk = 0; blk < 4; ++blk) {
      bf16 st[8];
#pragma unroll
      for (int e = 0; e < 8; ++e) {
        int m = mb0 + blk * 64 + mq * 8 + e;
        if (m >= NWP_) m = NWP_ - 1;
        st[e] = vpb[(size_t)m * 64 + sd];
      }
      *reinterpret_cast<bf16x8*>(&vt[sd][blk * 64 + mq * 8]) = *reinterpret_cast<const bf16x8*>(st);
    }
    __syncthreads();
    int col = mb0 + c8;
    if (rowok) {
#pragma unroll
      for (int pr = 0; pr < 4; ++pr) {
        int cc = c8 + pr * 2;
        if (col + pr * 2 + 1 < NW_) {
          float2 o2 = make_float2(strip[orow][cc], strip[orow][cc + 1]);
          *reinterpret_cast<float2*>(OP + rowb + col + pr * 2) = o2;
        }
      }
    }
    if (act) {
      bf16x8 af;
#pragma unroll
      for (int e = 0; e < 8; ++e) af[e] = (bf16)strip[lid][wave * 32 + g * 8 + e];
#pragma unroll
      for (int dg = 0; dg < 4; ++dg) {
        bf16x8 bv8 = *reinterpret_cast<const bf16x8*>(&vt[dg * 16 + lid][wave * 32 + g * 8]);
        vacc[dg] = __builtin_amdgcn_mfma_f32_16x16x32_bf16(af, bv8, vacc[dg], 0, 0, 0);
      }
    }
    __syncthreads();
  }
#pragma unroll
  for (int wsel = 0; wsel < 8; ++wsel) {
    if (wave == wsel) {
#pragma unroll
      for (int dg = 0; dg < 4; ++dg)
#pragma unroll
        for (int r = 0; r < 4; ++r) {
          if (wsel == 0) strip[g * 4 + r][dg * 16 + lid] = vacc[dg][r];
          else           strip[g * 4 + r][dg * 16 + lid] += vacc[dg][r];
        }
    }
    __syncthreads();
  }
  float* ob = OV + (((size_t)b * 16 + 8 + h) * L_) * 64;
  for (int idx = t; idx < 1024; idx += 512) {
    int r = idx >> 6, d = idx & 63;
    int qr = q0 + r;
    if (qr < L_) ob[(size_t)qr * 64 + d] = strip[r][d];
  }
}

extern "C" void kernel_launch(void* const* d_in, const int* in_sizes, int n_in,
                              void* d_out, int out_size, void* d_ws, size_t ws_size,
                              hipStream_t stream) {
  (void)in_sizes; (void)n_in; (void)out_size; (void)ws_size;
  const float* x    = (const float*)d_in[0];
  const float* mask = (const float*)d_in[1];
  const float* Wq   = (const float*)d_in[2];
  const float* bq   = (const float*)d_in[3];
  const float* Wk   = (const float*)d_in[4];
  const float* bk   = (const float*)d_in[5];
  const float* Wv   = (const float*)d_in[6];
  const float* bv   = (const float*)d_in[7];

  char* ws = (char*)d_ws;
  bf16* qbb     = (bf16*)(ws + 0);            // 8,380,416
  bf16* kgb     = (bf16*)(ws + 8380416);      // 4,194,304
  bf16* vgb     = (bf16*)(ws + 12574720);     // 4,194,304 (row-major V)
  bf16* klb     = (bf16*)(ws + 16769024);     // 1,441,792
  bf16* vlb     = (bf16*)(ws + 18210816);     // 1,441,792
  uint64_t* gm  = (uint64_t*)(ws + 19652608); // 1,047,552
  uint64_t* wm  = (uint64_t*)(ws + 20700160); // 360,096
  bf16* xbb     = (bf16*)(ws + 21060256);     // 8,380,416 (x in bf16)
  bf16* wqb     = (bf16*)(ws + 29440672);     // 2,097,152 (Wq in bf16)

  float* out    = (float*)d_out;
  float* o_vall = out;                 // (2,16,2046,64)
  float* o_pg   = out + 4190208;       // (2,8,2046,2046)
  float* o_pl   = out + 71168064;      // (2,8,2046,682)

  cast4<<<4092, 256, 0, stream>>>(x, xbb, 4190208);
  cast4<<<1024, 256, 0, stream>>>(Wq, wqb, 1048576);
  qgemm_t<<<dim3(64, 8), 256, 0, stream>>>(xbb, wqb, bq, qbb);
  proj_g32<<<dim3(32, 16), 256, 0, stream>>>(x, Wk, bk, Wv, bv, kgb, vgb);
  proj_l32<<<dim3(11, 16), 256, 0, stream>>>(x, Wk, bk, Wv, bv, klb, vlb);
  maskprep<<<1023, 256, 0, stream>>>(mask, gm, wm);

  attn_gf<<<dim3(128, 16), 512, 0, stream>>>(qbb, kgb, vgb, gm, o_pg, o_vall);
  attn_lf<<<dim3(128, 16), 512, 0, stream>>>(qbb, klb, vlb, wm, o_pl, o_vall);
}